// Round 8
// baseline (1234.719 us; speedup 1.0000x reference)
//
#include <hip/hip_runtime.h>
#include <math.h>

#define NN 10000
#define NE 20000
#define FIN 128
#define NHEAD 8
#define C1 512
#define C2 256
#define NB 64
#define NOUT 10

typedef _Float16 half8v __attribute__((ext_vector_type(8)));
typedef _Float16 half4v __attribute__((ext_vector_type(4)));
typedef _Float16 half2v __attribute__((ext_vector_type(2)));
typedef float f32x4 __attribute__((ext_vector_type(4)));

template<int VEC> struct VecT;
template<> struct VecT<2> { using T = half2v; };
template<> struct VecT<4> { using T = half4v; };
template<> struct VecT<8> { using T = half8v; };

__device__ __forceinline__ unsigned enc_f(float f) {
    unsigned u = __float_as_uint(f);
    return (u & 0x80000000u) ? ~u : (u | 0x80000000u);
}
__device__ __forceinline__ float dec_f(unsigned e) {
    return (e & 0x80000000u) ? __uint_as_float(e & 0x7fffffffu) : __uint_as_float(~e);
}

// ---------------- conversion / transpose ----------------
__global__ void cvt_f16(const float* __restrict__ in, _Float16* __restrict__ out, int n) {
    int i = blockIdx.x * blockDim.x + threadIdx.x;
    if (i < n) out[i] = (_Float16)in[i];
}

// W [K,N] fp32 -> Wt [N,K] f16. block (32,8)
__global__ void transpose_cvt(const float* __restrict__ W, _Float16* __restrict__ Wt,
                              int K, int N) {
    __shared__ float tile[32][33];
    int n0 = blockIdx.x * 32, k0 = blockIdx.y * 32;
    int tx = threadIdx.x, ty = threadIdx.y;
    for (int j = ty; j < 32; j += 8) tile[j][tx] = W[(size_t)(k0 + j) * N + n0 + tx];
    __syncthreads();
    for (int j = ty; j < 32; j += 8)
        Wt[(size_t)(n0 + j) * K + k0 + tx] = (_Float16)tile[tx][j];
}

// Wv [Cin, NHEAD*Cout] fp32 -> Bt [Cout, NHEAD*Cin] f16, Bt[c, h*Cin+k] = Wv[k, h*Cout+c]
__global__ void transpose_stack(const float* __restrict__ Wv, _Float16* __restrict__ Bt,
                                int Cin, int Cout) {
    __shared__ float tile[32][33];
    int h = blockIdx.z;
    int c0 = blockIdx.x * 32, k0 = blockIdx.y * 32;
    int tx = threadIdx.x, ty = threadIdx.y;
    for (int j = ty; j < 32; j += 8)
        tile[j][tx] = Wv[(size_t)(k0 + j) * (NHEAD * Cout) + (size_t)h * Cout + c0 + tx];
    __syncthreads();
    for (int j = ty; j < 32; j += 8)
        Bt[(size_t)(c0 + j) * (NHEAD * Cin) + (size_t)h * Cin + k0 + tx] = (_Float16)tile[tx][j];
}

__global__ void bvmean_k(const float* __restrict__ bv, float* __restrict__ bvm, int C) {
    int c = blockIdx.x * blockDim.x + threadIdx.x;
    if (c >= C) return;
    float s = 0.f;
    #pragma unroll
    for (int h = 0; h < NHEAD; ++h) s += bv[h * C + c];
    bvm[c] = s * (1.0f / NHEAD);
}

// ---------------- MFMA GEMM:  C = A[M,K] @ Bt[N,K]^T (+bias | +=C) ----------------
template<bool OUT_HALF, bool ACCUM>
__global__ __launch_bounds__(256) void gemm_tn(
    const _Float16* __restrict__ A, const _Float16* __restrict__ Bt,
    const float* __restrict__ bias, void* __restrict__ Cout, int ldc,
    int M, int K)
{
    __shared__ _Float16 As[128][40];
    __shared__ _Float16 Bs[128][40];
    const int t = threadIdx.x;
    const int m0 = blockIdx.y * 128, n0 = blockIdx.x * 128;
    const int w = t >> 6, lane = t & 63;
    const int wr = w >> 1, wc = w & 1;

    f32x4 acc[4][4];
    #pragma unroll
    for (int m = 0; m < 4; ++m)
        #pragma unroll
        for (int n = 0; n < 4; ++n)
            #pragma unroll
            for (int j = 0; j < 4; ++j) acc[m][n][j] = 0.f;

    for (int k0 = 0; k0 < K; k0 += 32) {
        #pragma unroll
        for (int i = 0; i < 2; ++i) {
            int c = t + i * 256;
            int row = c >> 2, kc = c & 3;
            int gr = m0 + row; gr = gr < M ? gr : M - 1;
            float4 va = *(const float4*)(A + (size_t)gr * K + k0 + kc * 8);
            *(float4*)(&As[row][kc * 8]) = va;
            float4 vb = *(const float4*)(Bt + (size_t)(n0 + row) * K + k0 + kc * 8);
            *(float4*)(&Bs[row][kc * 8]) = vb;
        }
        __syncthreads();
        half8v af[4], bf[4];
        #pragma unroll
        for (int m = 0; m < 4; ++m)
            af[m] = *(const half8v*)(&As[wr * 64 + m * 16 + (lane & 15)][(lane >> 4) * 8]);
        #pragma unroll
        for (int n = 0; n < 4; ++n)
            bf[n] = *(const half8v*)(&Bs[wc * 64 + n * 16 + (lane & 15)][(lane >> 4) * 8]);
        #pragma unroll
        for (int m = 0; m < 4; ++m)
            #pragma unroll
            for (int n = 0; n < 4; ++n)
                acc[m][n] = __builtin_amdgcn_mfma_f32_16x16x32_f16(af[m], bf[n], acc[m][n], 0, 0, 0);
        __syncthreads();
    }
    #pragma unroll
    for (int m = 0; m < 4; ++m) {
        int r0 = m0 + wr * 64 + m * 16 + (lane >> 4) * 4;
        #pragma unroll
        for (int n = 0; n < 4; ++n) {
            int col = n0 + wc * 64 + n * 16 + (lane & 15);
            float b = 0.f;
            if (!ACCUM) b = bias[col];
            #pragma unroll
            for (int r = 0; r < 4; ++r) {
                int row = r0 + r;
                if (row < M) {
                    float v = acc[m][n][r] + b;
                    if (ACCUM) v += ((float*)Cout)[(size_t)row * ldc + col];
                    if (OUT_HALF) ((_Float16*)Cout)[(size_t)row * ldc + col] = (_Float16)v;
                    else          ((float*)Cout)[(size_t)row * ldc + col] = v;
                }
            }
        }
    }
}

// ---------------- CSR build (by dst) ----------------
__global__ void zero_i32(int* __restrict__ p, int n) {
    int i = blockIdx.x * blockDim.x + threadIdx.x;
    if (i < n) p[i] = 0;
}
__global__ void hist_dst(const int* __restrict__ dst, int* __restrict__ deg) {
    int e = blockIdx.x * blockDim.x + threadIdx.x;
    if (e < NE) atomicAdd(&deg[dst[e]], 1);
}
__global__ void scan_deg(const int* __restrict__ deg, int* __restrict__ rowptr,
                         int* __restrict__ cursor, int n) {
    __shared__ int s[256];
    __shared__ int carry;
    int t = threadIdx.x;
    if (t == 0) carry = 0;
    __syncthreads();
    for (int base = 0; base < n; base += 256) {
        int v = (base + t < n) ? deg[base + t] : 0;
        s[t] = v;
        __syncthreads();
        for (int off = 1; off < 256; off <<= 1) {
            int x = (t >= off) ? s[t - off] : 0;
            __syncthreads();
            s[t] += x;
            __syncthreads();
        }
        int excl = carry + s[t] - v;
        if (base + t < n) { rowptr[base + t] = excl; cursor[base + t] = excl; }
        __syncthreads();
        if (t == 255) carry += s[255];
        __syncthreads();
    }
    if (t == 0) rowptr[n] = carry;
}
__global__ void scatter_edges(const int* __restrict__ dst, int* __restrict__ cursor,
                              int* __restrict__ eids) {
    int e = blockIdx.x * blockDim.x + threadIdx.x;
    if (e < NE) {
        int pos = atomicAdd(&cursor[dst[e]], 1);
        eids[pos] = e;
    }
}

// ---------------- segment softmax pieces ----------------
__global__ void init_seg(unsigned* __restrict__ amax, float* __restrict__ denom, int n) {
    int i = blockIdx.x * blockDim.x + threadIdx.x;
    if (i < n) { amax[i] = 0x007FFFFFu; denom[i] = 0.f; }
}

// one wave per edge: alpha[e,h] = dot(Q[dst], K[src]) * scale
template<int C>
__global__ void edge_alpha_f(const _Float16* __restrict__ Q, const _Float16* __restrict__ Kh,
                             const int* __restrict__ src, const int* __restrict__ dst,
                             float* __restrict__ alpha, unsigned* __restrict__ amaxU,
                             float scale, int h)
{
    constexpr int VEC = C / 64;
    using vecH = typename VecT<VEC>::T;
    int gi = blockIdx.x * blockDim.x + threadIdx.x;
    int e = gi >> 6, lane = threadIdx.x & 63;
    if (e >= NE) return;
    int s = src[e], d = dst[e];
    vecH q = *(const vecH*)(Q  + (size_t)d * C + lane * VEC);
    vecH k = *(const vecH*)(Kh + (size_t)s * C + lane * VEC);
    float sum = 0.f;
    #pragma unroll
    for (int j = 0; j < VEC; ++j) sum += (float)q[j] * (float)k[j];
    #pragma unroll
    for (int off = 32; off; off >>= 1) sum += __shfl_xor(sum, off);
    if (lane == 0) {
        float al = sum * scale;
        alpha[(size_t)e * NHEAD + h] = al;
        atomicMax(&amaxU[(size_t)d * NHEAD + h], enc_f(al));
    }
}

__global__ void edge_expsum(const float* __restrict__ alpha, const int* __restrict__ dst,
                            const unsigned* __restrict__ amaxU,
                            float* __restrict__ ev, float* __restrict__ denom)
{
    int i = blockIdx.x * blockDim.x + threadIdx.x;
    if (i >= NE * NHEAD) return;
    int e = i >> 3, h = i & 7;
    int d = dst[e];
    float ex = expf(alpha[i] - dec_f(amaxU[(size_t)d * NHEAD + h]));
    ev[i] = ex;
    atomicAdd(&denom[(size_t)d * NHEAD + h], ex);
}

// conv1 z-trick: Z[n, h*FIN + c] = sum_e (a[e,h]/H) * X[src(e), c]  (X = xb, 2.56MB, L2-resident)
template<int C, int G>
__global__ void zaccum(const _Float16* __restrict__ X, const float* __restrict__ ev,
                       const float* __restrict__ denom, const int* __restrict__ rowptr,
                       const int* __restrict__ eids, const int* __restrict__ src,
                       _Float16* __restrict__ Z, int hbase)
{
    constexpr int VEC = C / 64;
    using vecH = typename VecT<VEC>::T;
    int gi = blockIdx.x * blockDim.x + threadIdx.x;
    int n = gi >> 6, lane = threadIdx.x & 63;
    if (n >= NN) return;
    int beg = rowptr[n], end = rowptr[n + 1];
    float rd[G];
    #pragma unroll
    for (int h = 0; h < G; ++h)
        rd[h] = (1.0f / NHEAD) / (denom[(size_t)n * NHEAD + hbase + h] + 1e-16f);
    float acc[G][VEC];
    #pragma unroll
    for (int h = 0; h < G; ++h)
        #pragma unroll
        for (int j = 0; j < VEC; ++j) acc[h][j] = 0.f;
    for (int i = beg; i < end; ++i) {
        int e = eids[i];
        int s = src[e];
        vecH xv = *(const vecH*)(X + (size_t)s * C + lane * VEC);
        #pragma unroll
        for (int h = 0; h < G; ++h) {
            float cf = ev[(size_t)e * NHEAD + hbase + h] * rd[h];
            #pragma unroll
            for (int j = 0; j < VEC; ++j) acc[h][j] += cf * (float)xv[j];
        }
    }
    #pragma unroll
    for (int h = 0; h < G; ++h) {
        vecH o;
        #pragma unroll
        for (int j = 0; j < VEC; ++j) o[j] = (_Float16)acc[h][j];
        *(vecH*)(Z + (size_t)n * (G * C) + (size_t)h * C + lane * VEC) = o;
    }
}

// conv2 aggregation (round-6 path): one wave per node, gather V rows (bias included in V)
template<int C>
__global__ void node_aggr(const _Float16* __restrict__ V, const float* __restrict__ ev,
                          const float* __restrict__ denom, const int* __restrict__ rowptr,
                          const int* __restrict__ eids, const int* __restrict__ src,
                          float* __restrict__ acc, int h)
{
    constexpr int VEC = C / 64;
    using vecH = typename VecT<VEC>::T;
    int gi = blockIdx.x * blockDim.x + threadIdx.x;
    int n = gi >> 6, lane = threadIdx.x & 63;
    if (n >= NN) return;
    int beg = rowptr[n], end = rowptr[n + 1];
    float a[VEC];
    #pragma unroll
    for (int j = 0; j < VEC; ++j) a[j] = 0.f;
    float rd = 1.f / (denom[(size_t)n * NHEAD + h] + 1e-16f) * (1.f / NHEAD);
    for (int i = beg; i < end; ++i) {
        int e = eids[i];
        int s = src[e];
        float coeff = ev[(size_t)e * NHEAD + h] * rd;
        vecH v = *(const vecH*)(V + (size_t)s * C + lane * VEC);
        #pragma unroll
        for (int j = 0; j < VEC; ++j) a[j] += coeff * (float)v[j];
    }
    float* ap = acc + (size_t)n * C + lane * VEC;
    #pragma unroll
    for (int j = 0; j < VEC; ++j) ap[j] += a[j];
}

__global__ void elu_k(float* __restrict__ x, int n) {
    int i = blockIdx.x * blockDim.x + threadIdx.x;
    if (i < n) { float v = x[i]; x[i] = v > 0.f ? v : expm1f(v); }
}
// conv1 epilogue: + deg-gated bv-mean, ELU, -> f16
__global__ void elu_cvt_bias(const float* __restrict__ in, _Float16* __restrict__ out,
                             const float* __restrict__ bvm, const int* __restrict__ deg,
                             int total) {
    int i = blockIdx.x * blockDim.x + threadIdx.x;
    if (i >= total) return;
    int c = i & (C1 - 1), n = i >> 9;
    float v = in[i] + (deg[n] > 0 ? bvm[c] : 0.f);
    v = v > 0.f ? v : expm1f(v);
    out[i] = (_Float16)v;
}

// ---------------- fused global-attention pooling + final fc ----------------
__global__ __launch_bounds__(256) void pool_fused(
    const float* __restrict__ H2, const float* __restrict__ Wg,
    const float* __restrict__ bg, const int* __restrict__ batch,
    const float* __restrict__ Wf, const float* __restrict__ bf,
    float* __restrict__ glogit, float* __restrict__ out)
{
    const int b = blockIdx.x;
    const int t = threadIdx.x, lane = t & 63, w = t >> 6;
    __shared__ int sbeg, send;
    __shared__ float sred[4];
    if (t == 0) {
        int lo = 0, hi = NN;
        while (lo < hi) { int mid = (lo + hi) >> 1; if (batch[mid] < b) lo = mid + 1; else hi = mid; }
        sbeg = lo;
        hi = NN;
        while (lo < hi) { int mid = (lo + hi) >> 1; if (batch[mid] < b + 1) lo = mid + 1; else hi = mid; }
        send = lo;
    }
    __syncthreads();
    const int beg = sbeg, end = send;
    const float bg0 = bg[0];

    float lmax = -INFINITY;
    for (int n = beg + w; n < end; n += 4) {
        float4 h = ((const float4*)(H2 + (size_t)n * C2))[lane];
        float4 wv = ((const float4*)Wg)[lane];
        float sum = h.x * wv.x + h.y * wv.y + h.z * wv.z + h.w * wv.w;
        #pragma unroll
        for (int off = 32; off; off >>= 1) sum += __shfl_xor(sum, off);
        sum += bg0;
        if (lane == 0) glogit[n] = sum;
        lmax = fmaxf(lmax, sum);
    }
    if (lane == 0) sred[w] = lmax;
    __syncthreads();
    float m = fmaxf(fmaxf(sred[0], sred[1]), fmaxf(sred[2], sred[3]));
    if (!isfinite(m)) m = 0.f;
    __syncthreads();

    float ls = 0.f;
    for (int n = beg + t; n < end; n += 256) {
        float e = expf(glogit[n] - m);
        glogit[n] = e;
        ls += e;
    }
    #pragma unroll
    for (int off = 32; off; off >>= 1) ls += __shfl_xor(ls, off);
    if (lane == 0) sred[w] = ls;
    __syncthreads();
    const float denom = sred[0] + sred[1] + sred[2] + sred[3] + 1e-16f;
    __syncthreads();

    float acc = 0.f;
    for (int n = beg; n < end; ++n)
        acc += glogit[n] * H2[(size_t)n * C2 + t];
    const float gc = acc / denom;

    for (int o = 0; o < NOUT; ++o) {
        float p = gc * Wf[t * NOUT + o];
        #pragma unroll
        for (int off = 32; off; off >>= 1) p += __shfl_xor(p, off);
        __syncthreads();
        if (lane == 0) sred[w] = p;
        __syncthreads();
        if (t == 0) out[b * NOUT + o] = sred[0] + sred[1] + sred[2] + sred[3] + bf[o];
    }
}

extern "C" void kernel_launch(void* const* d_in, const int* in_sizes, int n_in,
                              void* d_out, int out_size, void* d_ws, size_t ws_size,
                              hipStream_t stream) {
    (void)in_sizes; (void)n_in; (void)out_size; (void)ws_size;
    const float* x     = (const float*)d_in[0];
    const int*   ei    = (const int*)  d_in[1];
    const int*   batch = (const int*)  d_in[2];
    const float* Wq1 = (const float*)d_in[3];  const float* bq1 = (const float*)d_in[4];
    const float* Wk1 = (const float*)d_in[5];  const float* bk1 = (const float*)d_in[6];
    const float* Wv1 = (const float*)d_in[7];  const float* bv1 = (const float*)d_in[8];
    const float* Ws1 = (const float*)d_in[9];  const float* bs1 = (const float*)d_in[10];
    const float* Wq2 = (const float*)d_in[11]; const float* bq2 = (const float*)d_in[12];
    const float* Wk2 = (const float*)d_in[13]; const float* bk2 = (const float*)d_in[14];
    const float* Wv2 = (const float*)d_in[15]; const float* bv2 = (const float*)d_in[16];
    const float* Ws2 = (const float*)d_in[17]; const float* bs2 = (const float*)d_in[18];
    const float* Wg  = (const float*)d_in[19]; const float* bg  = (const float*)d_in[20];
    const float* Wf  = (const float*)d_in[21]; const float* bf  = (const float*)d_in[22];

    const int* src = ei;
    const int* dst = ei + NE;

    char* base = (char*)d_ws;
    size_t off = 0;
    auto alloc = [&](size_t bytes) -> char* {
        char* p = base + off;
        off = (off + bytes + 255) & ~(size_t)255;
        return p;
    };
    _Float16* xb   = (_Float16*)alloc((size_t)NN * FIN * 2);
    _Float16* wtq1 = (_Float16*)alloc((size_t)NHEAD * C1 * FIN * 2);
    _Float16* wtk1 = (_Float16*)alloc((size_t)NHEAD * C1 * FIN * 2);
    _Float16* bvs1 = (_Float16*)alloc((size_t)C1 * NHEAD * FIN * 2);   // [512, 1024]
    _Float16* wts1 = (_Float16*)alloc((size_t)C1 * FIN * 2);
    _Float16* wtq2 = (_Float16*)alloc((size_t)NHEAD * C2 * C1 * 2);
    _Float16* wtk2 = (_Float16*)alloc((size_t)NHEAD * C2 * C1 * 2);
    _Float16* wtv2 = (_Float16*)alloc((size_t)NHEAD * C2 * C1 * 2);
    _Float16* wts2 = (_Float16*)alloc((size_t)C2 * C1 * 2);
    float* acc1 = (float*)alloc((size_t)NN * C1 * 4);
    _Float16* h1b = (_Float16*)alloc((size_t)NN * C1 * 2);
    float* alpha = (float*)alloc((size_t)NE * NHEAD * 4);
    float* ev    = (float*)alloc((size_t)NE * NHEAD * 4);
    unsigned* amaxU = (unsigned*)alloc((size_t)NN * NHEAD * 4);
    float* denom = (float*)alloc((size_t)NN * NHEAD * 4);
    int* deg    = (int*)alloc((size_t)NN * 4);
    int* rowptr = (int*)alloc((size_t)(NN + 1) * 4);
    int* cursor = (int*)alloc((size_t)NN * 4);
    int* eids   = (int*)alloc((size_t)NE * 4);
    float* bvm1 = (float*)alloc((size_t)C1 * 4);
    size_t fixed_end = off;
    float* acc2 = acc1;  // conv1 fp32 accum dead once h1b built

    // Q/K buffers (10.25MB each); Zbuf overlays both (20.5MB); Vbuf overlays Qbuf
    _Float16* Qbuf = (_Float16*)(base + fixed_end);
    _Float16* Kbuf = (_Float16*)(base + fixed_end + (((size_t)NN * C1 * 2 + 255) & ~(size_t)255));
    _Float16* Zbuf = Qbuf;
    _Float16* Vbuf = Qbuf;

    const dim3 blk(256);
    const float sc1 = 1.0f / sqrtf((float)C1);
    const float sc2 = 1.0f / sqrtf((float)C2);
    const int edge_blocks = (NE * 64) / 256;
    const int node_blocks = (NN * 64) / 256;
    const int gy = (NN + 127) / 128;

    // ---- conversions ----
    cvt_f16<<<((size_t)NN * FIN + 255) / 256, blk, 0, stream>>>(x, xb, NN * FIN);
    {
        dim3 tb(32, 8);
        transpose_cvt<<<dim3(NHEAD * C1 / 32, FIN / 32), tb, 0, stream>>>(Wq1, wtq1, FIN, NHEAD * C1);
        transpose_cvt<<<dim3(NHEAD * C1 / 32, FIN / 32), tb, 0, stream>>>(Wk1, wtk1, FIN, NHEAD * C1);
        transpose_stack<<<dim3(C1 / 32, FIN / 32, NHEAD), tb, 0, stream>>>(Wv1, bvs1, FIN, C1);
        transpose_cvt<<<dim3(C1 / 32, FIN / 32),         tb, 0, stream>>>(Ws1, wts1, FIN, C1);
        transpose_cvt<<<dim3(NHEAD * C2 / 32, C1 / 32),  tb, 0, stream>>>(Wq2, wtq2, C1, NHEAD * C2);
        transpose_cvt<<<dim3(NHEAD * C2 / 32, C1 / 32),  tb, 0, stream>>>(Wk2, wtk2, C1, NHEAD * C2);
        transpose_cvt<<<dim3(NHEAD * C2 / 32, C1 / 32),  tb, 0, stream>>>(Wv2, wtv2, C1, NHEAD * C2);
        transpose_cvt<<<dim3(C2 / 32, C1 / 32),          tb, 0, stream>>>(Ws2, wts2, C1, C2);
    }
    bvmean_k<<<(C1 + 255) / 256, blk, 0, stream>>>(bv1, bvm1, C1);

    // ---- CSR by dst ----
    zero_i32<<<(NN + 255) / 256, blk, 0, stream>>>(deg, NN);
    hist_dst<<<(NE + 255) / 256, blk, 0, stream>>>(dst, deg);
    scan_deg<<<1, blk, 0, stream>>>(deg, rowptr, cursor, NN);
    scatter_edges<<<(NE + 255) / 256, blk, 0, stream>>>(dst, cursor, eids);

    // ================ conv1 (z-trick aggregation) ================
    gemm_tn<false, false><<<dim3(C1 / 128, gy), blk, 0, stream>>>(
        xb, wts1, bs1, acc1, C1, NN, FIN);
    init_seg<<<(NN * NHEAD + 255) / 256, blk, 0, stream>>>(amaxU, denom, NN * NHEAD);
    for (int h = 0; h < NHEAD; ++h) {
        gemm_tn<true, false><<<dim3(C1 / 128, gy), blk, 0, stream>>>(
            xb, wtq1 + (size_t)h * C1 * FIN, bq1 + h * C1, Qbuf, C1, NN, FIN);
        gemm_tn<true, false><<<dim3(C1 / 128, gy), blk, 0, stream>>>(
            xb, wtk1 + (size_t)h * C1 * FIN, bk1 + h * C1, Kbuf, C1, NN, FIN);
        edge_alpha_f<C1><<<edge_blocks, blk, 0, stream>>>(Qbuf, Kbuf, src, dst, alpha, amaxU,
                                                          sc1, h);
    }
    edge_expsum<<<(NE * NHEAD + 255) / 256, blk, 0, stream>>>(alpha, dst, amaxU, ev, denom);
    zaccum<FIN, NHEAD><<<node_blocks, blk, 0, stream>>>(xb, ev, denom, rowptr, eids, src,
                                                        Zbuf, 0);
    gemm_tn<false, true><<<dim3(C1 / 128, gy), blk, 0, stream>>>(
        Zbuf, bvs1, nullptr, acc1, C1, NN, NHEAD * FIN);
    elu_cvt_bias<<<((size_t)NN * C1 + 255) / 256, blk, 0, stream>>>(
        acc1, h1b, bvm1, deg, NN * C1);

    // ================ conv2 (round-6 V + node_aggr path) ================
    gemm_tn<false, false><<<dim3(C2 / 128, gy), blk, 0, stream>>>(
        h1b, wts2, bs2, acc2, C2, NN, C1);
    init_seg<<<(NN * NHEAD + 255) / 256, blk, 0, stream>>>(amaxU, denom, NN * NHEAD);
    for (int h = 0; h < NHEAD; ++h) {
        gemm_tn<true, false><<<dim3(C2 / 128, gy), blk, 0, stream>>>(
            h1b, wtq2 + (size_t)h * C2 * C1, bq2 + h * C2, Qbuf, C2, NN, C1);
        gemm_tn<true, false><<<dim3(C2 / 128, gy), blk, 0, stream>>>(
            h1b, wtk2 + (size_t)h * C2 * C1, bk2 + h * C2, Kbuf, C2, NN, C1);
        edge_alpha_f<C2><<<edge_blocks, blk, 0, stream>>>(Qbuf, Kbuf, src, dst, alpha, amaxU,
                                                          sc2, h);
    }
    edge_expsum<<<(NE * NHEAD + 255) / 256, blk, 0, stream>>>(alpha, dst, amaxU, ev, denom);
    for (int h = 0; h < NHEAD; ++h) {
        gemm_tn<true, false><<<dim3(C2 / 128, gy), blk, 0, stream>>>(
            h1b, wtv2 + (size_t)h * C2 * C1, bv2 + h * C2, Vbuf, C2, NN, C1);
        node_aggr<C2><<<node_blocks, blk, 0, stream>>>(Vbuf, ev, denom, rowptr, eids, src,
                                                       acc2, h);
    }
    elu_k<<<((size_t)NN * C2 + 255) / 256, blk, 0, stream>>>(acc2, NN * C2);

    // ================ fused pooling + fc ================
    pool_fused<<<NB, blk, 0, stream>>>(acc2, Wg, bg, batch, Wf, bf, alpha, (float*)d_out);
}

// Round 9
// 685.963 us; speedup vs baseline: 1.8000x; 1.8000x over previous
//
#include <hip/hip_runtime.h>
#include <math.h>

#define NN 10000
#define NE 20000
#define FIN 128
#define NHEAD 8
#define C1 512
#define C2 256
#define NB 64
#define NOUT 10

typedef _Float16 half8v __attribute__((ext_vector_type(8)));
typedef _Float16 half4v __attribute__((ext_vector_type(4)));
typedef _Float16 half2v __attribute__((ext_vector_type(2)));
typedef float f32x4 __attribute__((ext_vector_type(4)));

template<int VEC> struct VecT;
template<> struct VecT<2> { using T = half2v; };
template<> struct VecT<4> { using T = half4v; };
template<> struct VecT<8> { using T = half8v; };

__device__ __forceinline__ unsigned enc_f(float f) {
    unsigned u = __float_as_uint(f);
    return (u & 0x80000000u) ? ~u : (u | 0x80000000u);
}
__device__ __forceinline__ float dec_f(unsigned e) {
    return (e & 0x80000000u) ? __uint_as_float(e & 0x7fffffffu) : __uint_as_float(~e);
}

// ---------------- conversion / transpose ----------------
__global__ void cvt_f16(const float* __restrict__ in, _Float16* __restrict__ out, int n) {
    int i = blockIdx.x * blockDim.x + threadIdx.x;
    if (i < n) out[i] = (_Float16)in[i];
}

// W [K,N] fp32 -> Wt [N,K] f16. block (32,8)
__global__ void transpose_cvt(const float* __restrict__ W, _Float16* __restrict__ Wt,
                              int K, int N) {
    __shared__ float tile[32][33];
    int n0 = blockIdx.x * 32, k0 = blockIdx.y * 32;
    int tx = threadIdx.x, ty = threadIdx.y;
    for (int j = ty; j < 32; j += 8) tile[j][tx] = W[(size_t)(k0 + j) * N + n0 + tx];
    __syncthreads();
    for (int j = ty; j < 32; j += 8)
        Wt[(size_t)(n0 + j) * K + k0 + tx] = (_Float16)tile[tx][j];
}

// Wv [Cin, NHEAD*Cout] fp32 -> Bt [Cout, NHEAD*Cin] f16, Bt[c, h*Cin+k] = Wv[k, h*Cout+c]
__global__ void transpose_stack(const float* __restrict__ Wv, _Float16* __restrict__ Bt,
                                int Cin, int Cout) {
    __shared__ float tile[32][33];
    int h = blockIdx.z;
    int c0 = blockIdx.x * 32, k0 = blockIdx.y * 32;
    int tx = threadIdx.x, ty = threadIdx.y;
    for (int j = ty; j < 32; j += 8)
        tile[j][tx] = Wv[(size_t)(k0 + j) * (NHEAD * Cout) + (size_t)h * Cout + c0 + tx];
    __syncthreads();
    for (int j = ty; j < 32; j += 8)
        Bt[(size_t)(c0 + j) * (NHEAD * Cin) + (size_t)h * Cin + k0 + tx] = (_Float16)tile[tx][j];
}

__global__ void bvmean_k(const float* __restrict__ bv, float* __restrict__ bvm, int C) {
    int c = blockIdx.x * blockDim.x + threadIdx.x;
    if (c >= C) return;
    float s = 0.f;
    #pragma unroll
    for (int h = 0; h < NHEAD; ++h) s += bv[h * C + c];
    bvm[c] = s * (1.0f / NHEAD);
}

// ---------------- conv1 low-rank QK precompute ----------------
// Mst[(h*FIN + j)*FIN + i] = sum_c wtq1[(h*C1+c)*FIN + i] * wtk1[(h*C1+c)*FIN + j]
__global__ void mstack_k(const _Float16* __restrict__ wtq1, const _Float16* __restrict__ wtk1,
                         _Float16* __restrict__ Mst) {
    int h = blockIdx.z;
    int i = blockIdx.x * 16 + threadIdx.x;
    int j = blockIdx.y * 16 + threadIdx.y;
    float acc = 0.f;
    for (int c = 0; c < C1; ++c)
        acc += (float)wtq1[((size_t)h * C1 + c) * FIN + i] *
               (float)wtk1[((size_t)h * C1 + c) * FIN + j];
    Mst[((size_t)h * FIN + j) * FIN + i] = (_Float16)acc;
}

// u[h,i] = Wq1 row-i (head h) . bk1_h ; v[h,i] = Wk1 row-i . bq1_h ; ch[h] = bq1_h . bk1_h
__global__ void uvprep(const float* __restrict__ Wq1, const float* __restrict__ Wk1,
                       const float* __restrict__ bq1, const float* __restrict__ bk1,
                       float* __restrict__ u, float* __restrict__ v, float* __restrict__ ch) {
    int h = blockIdx.x, i = threadIdx.x;  // block 128
    float su = 0.f, sv = 0.f;
    for (int c = 0; c < C1; ++c) {
        su += Wq1[(size_t)i * (NHEAD * C1) + h * C1 + c] * bk1[h * C1 + c];
        sv += Wk1[(size_t)i * (NHEAD * C1) + h * C1 + c] * bq1[h * C1 + c];
    }
    u[h * FIN + i] = su;
    v[h * FIN + i] = sv;
    if (i == 0) {
        float s = 0.f;
        for (int c = 0; c < C1; ++c) s += bq1[h * C1 + c] * bk1[h * C1 + c];
        ch[h] = s;
    }
}

// ud[n,h] = x[n].u_h + ch[h] ; vs[n,h] = x[n].v_h
__global__ void udvs_k(const _Float16* __restrict__ xb, const float* __restrict__ u,
                       const float* __restrict__ v, const float* __restrict__ ch,
                       float* __restrict__ ud, float* __restrict__ vs) {
    int idx = blockIdx.x * blockDim.x + threadIdx.x;
    if (idx >= NN * NHEAD) return;
    int n = idx >> 3, h = idx & 7;
    float su = ch[h], sv = 0.f;
    for (int i = 0; i < FIN; ++i) {
        float xv = (float)xb[(size_t)n * FIN + i];
        su += xv * u[h * FIN + i];
        sv += xv * v[h * FIN + i];
    }
    ud[idx] = su;
    vs[idx] = sv;
}

// ---------------- MFMA GEMM:  C = A[M,K] @ Bt[N,K]^T (+bias | +=C) ----------------
template<bool OUT_HALF, bool ACCUM>
__global__ __launch_bounds__(256) void gemm_tn(
    const _Float16* __restrict__ A, const _Float16* __restrict__ Bt,
    const float* __restrict__ bias, void* __restrict__ Cout, int ldc,
    int M, int K)
{
    __shared__ _Float16 As[128][40];
    __shared__ _Float16 Bs[128][40];
    const int t = threadIdx.x;
    const int m0 = blockIdx.y * 128, n0 = blockIdx.x * 128;
    const int w = t >> 6, lane = t & 63;
    const int wr = w >> 1, wc = w & 1;

    f32x4 acc[4][4];
    #pragma unroll
    for (int m = 0; m < 4; ++m)
        #pragma unroll
        for (int n = 0; n < 4; ++n)
            #pragma unroll
            for (int j = 0; j < 4; ++j) acc[m][n][j] = 0.f;

    for (int k0 = 0; k0 < K; k0 += 32) {
        #pragma unroll
        for (int i = 0; i < 2; ++i) {
            int c = t + i * 256;
            int row = c >> 2, kc = c & 3;
            int gr = m0 + row; gr = gr < M ? gr : M - 1;
            float4 va = *(const float4*)(A + (size_t)gr * K + k0 + kc * 8);
            *(float4*)(&As[row][kc * 8]) = va;
            float4 vb = *(const float4*)(Bt + (size_t)(n0 + row) * K + k0 + kc * 8);
            *(float4*)(&Bs[row][kc * 8]) = vb;
        }
        __syncthreads();
        half8v af[4], bf[4];
        #pragma unroll
        for (int m = 0; m < 4; ++m)
            af[m] = *(const half8v*)(&As[wr * 64 + m * 16 + (lane & 15)][(lane >> 4) * 8]);
        #pragma unroll
        for (int n = 0; n < 4; ++n)
            bf[n] = *(const half8v*)(&Bs[wc * 64 + n * 16 + (lane & 15)][(lane >> 4) * 8]);
        #pragma unroll
        for (int m = 0; m < 4; ++m)
            #pragma unroll
            for (int n = 0; n < 4; ++n)
                acc[m][n] = __builtin_amdgcn_mfma_f32_16x16x32_f16(af[m], bf[n], acc[m][n], 0, 0, 0);
        __syncthreads();
    }
    #pragma unroll
    for (int m = 0; m < 4; ++m) {
        int r0 = m0 + wr * 64 + m * 16 + (lane >> 4) * 4;
        #pragma unroll
        for (int n = 0; n < 4; ++n) {
            int col = n0 + wc * 64 + n * 16 + (lane & 15);
            float b = 0.f;
            if (!ACCUM) b = bias[col];
            #pragma unroll
            for (int r = 0; r < 4; ++r) {
                int row = r0 + r;
                if (row < M) {
                    float v = acc[m][n][r] + b;
                    if (ACCUM) v += ((float*)Cout)[(size_t)row * ldc + col];
                    if (OUT_HALF) ((_Float16*)Cout)[(size_t)row * ldc + col] = (_Float16)v;
                    else          ((float*)Cout)[(size_t)row * ldc + col] = v;
                }
            }
        }
    }
}

// ---------------- CSR build (by dst) ----------------
__global__ void zero_i32(int* __restrict__ p, int n) {
    int i = blockIdx.x * blockDim.x + threadIdx.x;
    if (i < n) p[i] = 0;
}
__global__ void hist_dst(const int* __restrict__ dst, int* __restrict__ deg) {
    int e = blockIdx.x * blockDim.x + threadIdx.x;
    if (e < NE) atomicAdd(&deg[dst[e]], 1);
}
__global__ void scan_deg(const int* __restrict__ deg, int* __restrict__ rowptr,
                         int* __restrict__ cursor, int n) {
    __shared__ int s[256];
    __shared__ int carry;
    int t = threadIdx.x;
    if (t == 0) carry = 0;
    __syncthreads();
    for (int base = 0; base < n; base += 256) {
        int v = (base + t < n) ? deg[base + t] : 0;
        s[t] = v;
        __syncthreads();
        for (int off = 1; off < 256; off <<= 1) {
            int x = (t >= off) ? s[t - off] : 0;
            __syncthreads();
            s[t] += x;
            __syncthreads();
        }
        int excl = carry + s[t] - v;
        if (base + t < n) { rowptr[base + t] = excl; cursor[base + t] = excl; }
        __syncthreads();
        if (t == 255) carry += s[255];
        __syncthreads();
    }
    if (t == 0) rowptr[n] = carry;
}
__global__ void scatter_edges(const int* __restrict__ dst, int* __restrict__ cursor,
                              int* __restrict__ eids) {
    int e = blockIdx.x * blockDim.x + threadIdx.x;
    if (e < NE) {
        int pos = atomicAdd(&cursor[dst[e]], 1);
        eids[pos] = e;
    }
}

// ---------------- segment softmax pieces ----------------
__global__ void init_seg(unsigned* __restrict__ amax, float* __restrict__ denom, int n) {
    int i = blockIdx.x * blockDim.x + threadIdx.x;
    if (i < n) { amax[i] = 0x007FFFFFu; denom[i] = 0.f; }
}

// conv1 low-rank edge logits: alpha[e,h] = scale*(T[dst,h].x[src] + ud[dst,h] + vs[src,h])
__global__ void edge_alpha_lr(const _Float16* __restrict__ T, const _Float16* __restrict__ X,
                              const float* __restrict__ ud, const float* __restrict__ vs,
                              const int* __restrict__ src, const int* __restrict__ dst,
                              float* __restrict__ alpha, unsigned* __restrict__ amaxU,
                              float scale)
{
    int gi = blockIdx.x * blockDim.x + threadIdx.x;
    int e = gi >> 6, lane = threadIdx.x & 63;
    if (e >= NE) return;
    int s = src[e], d = dst[e];
    half2v xv = *(const half2v*)(X + (size_t)s * FIN + lane * 2);
    #pragma unroll
    for (int h = 0; h < NHEAD; ++h) {
        half2v tv = *(const half2v*)(T + ((size_t)d * NHEAD + h) * FIN + lane * 2);
        float sum = (float)tv[0] * (float)xv[0] + (float)tv[1] * (float)xv[1];
        #pragma unroll
        for (int off = 32; off; off >>= 1) sum += __shfl_xor(sum, off);
        if (lane == 0) {
            float al = (sum + ud[(size_t)d * NHEAD + h] + vs[(size_t)s * NHEAD + h]) * scale;
            alpha[(size_t)e * NHEAD + h] = al;
            atomicMax(&amaxU[(size_t)d * NHEAD + h], enc_f(al));
        }
    }
}

// conv2 fused-head edge logits (round-6 form)
template<int C>
__global__ void edge_alpha_f(const _Float16* __restrict__ Q, const _Float16* __restrict__ Kh,
                             const int* __restrict__ src, const int* __restrict__ dst,
                             float* __restrict__ alpha, unsigned* __restrict__ amaxU,
                             float scale, int hbase, int G)
{
    constexpr int VEC = C / 64;
    using vecH = typename VecT<VEC>::T;
    int gi = blockIdx.x * blockDim.x + threadIdx.x;
    int e = gi >> 6, lane = threadIdx.x & 63;
    if (e >= NE) return;
    int s = src[e], d = dst[e];
    const _Float16* qp = Q + (size_t)d * ((size_t)G * C) + lane * VEC;
    const _Float16* kp = Kh + (size_t)s * ((size_t)G * C) + lane * VEC;
    for (int h = 0; h < G; ++h) {
        vecH q = *(const vecH*)(qp + h * C);
        vecH k = *(const vecH*)(kp + h * C);
        float sum = 0.f;
        #pragma unroll
        for (int j = 0; j < VEC; ++j) sum += (float)q[j] * (float)k[j];
        #pragma unroll
        for (int off = 32; off; off >>= 1) sum += __shfl_xor(sum, off);
        if (lane == 0) {
            float al = sum * scale;
            alpha[(size_t)e * NHEAD + hbase + h] = al;
            atomicMax(&amaxU[(size_t)d * NHEAD + hbase + h], enc_f(al));
        }
    }
}

__global__ void edge_expsum(const float* __restrict__ alpha, const int* __restrict__ dst,
                            const unsigned* __restrict__ amaxU,
                            float* __restrict__ ev, float* __restrict__ denom)
{
    int i = blockIdx.x * blockDim.x + threadIdx.x;
    if (i >= NE * NHEAD) return;
    int e = i >> 3, h = i & 7;
    int d = dst[e];
    float ex = expf(alpha[i] - dec_f(amaxU[(size_t)d * NHEAD + h]));
    ev[i] = ex;
    atomicAdd(&denom[(size_t)d * NHEAD + h], ex);
}

// conv1 z-trick: Z[n, h*C + c] = sum_e (a[e,h]/H) * X[src(e), c]
template<int C, int G>
__global__ void zaccum(const _Float16* __restrict__ X, const float* __restrict__ ev,
                       const float* __restrict__ denom, const int* __restrict__ rowptr,
                       const int* __restrict__ eids, const int* __restrict__ src,
                       _Float16* __restrict__ Z, int hbase)
{
    constexpr int VEC = C / 64;
    using vecH = typename VecT<VEC>::T;
    int gi = blockIdx.x * blockDim.x + threadIdx.x;
    int n = gi >> 6, lane = threadIdx.x & 63;
    if (n >= NN) return;
    int beg = rowptr[n], end = rowptr[n + 1];
    float rd[G];
    #pragma unroll
    for (int h = 0; h < G; ++h)
        rd[h] = (1.0f / NHEAD) / (denom[(size_t)n * NHEAD + hbase + h] + 1e-16f);
    float acc[G][VEC];
    #pragma unroll
    for (int h = 0; h < G; ++h)
        #pragma unroll
        for (int j = 0; j < VEC; ++j) acc[h][j] = 0.f;
    for (int i = beg; i < end; ++i) {
        int e = eids[i];
        int s = src[e];
        vecH xv = *(const vecH*)(X + (size_t)s * C + lane * VEC);
        #pragma unroll
        for (int h = 0; h < G; ++h) {
            float cf = ev[(size_t)e * NHEAD + hbase + h] * rd[h];
            #pragma unroll
            for (int j = 0; j < VEC; ++j) acc[h][j] += cf * (float)xv[j];
        }
    }
    #pragma unroll
    for (int h = 0; h < G; ++h) {
        vecH o;
        #pragma unroll
        for (int j = 0; j < VEC; ++j) o[j] = (_Float16)acc[h][j];
        *(vecH*)(Z + (size_t)n * (G * C) + (size_t)h * C + lane * VEC) = o;
    }
}

// conv2 aggregation (round-6 G form): one wave per node, V gather, no atomics
template<int C>
__global__ void node_aggr(const _Float16* __restrict__ V, const float* __restrict__ ev,
                          const float* __restrict__ denom, const int* __restrict__ rowptr,
                          const int* __restrict__ eids, const int* __restrict__ src,
                          float* __restrict__ acc, int hbase, int G)
{
    constexpr int VEC = C / 64;
    using vecH = typename VecT<VEC>::T;
    int gi = blockIdx.x * blockDim.x + threadIdx.x;
    int n = gi >> 6, lane = threadIdx.x & 63;
    if (n >= NN) return;
    int beg = rowptr[n], end = rowptr[n + 1];
    float a[VEC];
    #pragma unroll
    for (int j = 0; j < VEC; ++j) a[j] = 0.f;
    for (int h = 0; h < G; ++h) {
        float rd = 1.f / (denom[(size_t)n * NHEAD + hbase + h] + 1e-16f) * (1.f / NHEAD);
        for (int i = beg; i < end; ++i) {
            int e = eids[i];
            int s = src[e];
            float coeff = ev[(size_t)e * NHEAD + hbase + h] * rd;
            vecH v = *(const vecH*)(V + (size_t)s * ((size_t)G * C) + h * C + lane * VEC);
            #pragma unroll
            for (int j = 0; j < VEC; ++j) a[j] += coeff * (float)v[j];
        }
    }
    float* ap = acc + (size_t)n * C + lane * VEC;
    #pragma unroll
    for (int j = 0; j < VEC; ++j) ap[j] += a[j];
}

__global__ void elu_k(float* __restrict__ x, int n) {
    int i = blockIdx.x * blockDim.x + threadIdx.x;
    if (i < n) { float v = x[i]; x[i] = v > 0.f ? v : expm1f(v); }
}
// conv1 epilogue: + deg-gated bv-mean, ELU, -> f16
__global__ void elu_cvt_bias(const float* __restrict__ in, _Float16* __restrict__ out,
                             const float* __restrict__ bvm, const int* __restrict__ deg,
                             int total) {
    int i = blockIdx.x * blockDim.x + threadIdx.x;
    if (i >= total) return;
    int c = i & (C1 - 1), n = i >> 9;
    float v = in[i] + (deg[n] > 0 ? bvm[c] : 0.f);
    v = v > 0.f ? v : expm1f(v);
    out[i] = (_Float16)v;
}

// ---------------- fused global-attention pooling + final fc ----------------
__global__ __launch_bounds__(256) void pool_fused(
    const float* __restrict__ H2, const float* __restrict__ Wg,
    const float* __restrict__ bg, const int* __restrict__ batch,
    const float* __restrict__ Wf, const float* __restrict__ bf,
    float* __restrict__ glogit, float* __restrict__ out)
{
    const int b = blockIdx.x;
    const int t = threadIdx.x, lane = t & 63, w = t >> 6;
    __shared__ int sbeg, send;
    __shared__ float sred[4];
    if (t == 0) {
        int lo = 0, hi = NN;
        while (lo < hi) { int mid = (lo + hi) >> 1; if (batch[mid] < b) lo = mid + 1; else hi = mid; }
        sbeg = lo;
        hi = NN;
        while (lo < hi) { int mid = (lo + hi) >> 1; if (batch[mid] < b + 1) lo = mid + 1; else hi = mid; }
        send = lo;
    }
    __syncthreads();
    const int beg = sbeg, end = send;
    const float bg0 = bg[0];

    float lmax = -INFINITY;
    for (int n = beg + w; n < end; n += 4) {
        float4 h = ((const float4*)(H2 + (size_t)n * C2))[lane];
        float4 wv = ((const float4*)Wg)[lane];
        float sum = h.x * wv.x + h.y * wv.y + h.z * wv.z + h.w * wv.w;
        #pragma unroll
        for (int off = 32; off; off >>= 1) sum += __shfl_xor(sum, off);
        sum += bg0;
        if (lane == 0) glogit[n] = sum;
        lmax = fmaxf(lmax, sum);
    }
    if (lane == 0) sred[w] = lmax;
    __syncthreads();
    float m = fmaxf(fmaxf(sred[0], sred[1]), fmaxf(sred[2], sred[3]));
    if (!isfinite(m)) m = 0.f;
    __syncthreads();

    float ls = 0.f;
    for (int n = beg + t; n < end; n += 256) {
        float e = expf(glogit[n] - m);
        glogit[n] = e;
        ls += e;
    }
    #pragma unroll
    for (int off = 32; off; off >>= 1) ls += __shfl_xor(ls, off);
    if (lane == 0) sred[w] = ls;
    __syncthreads();
    const float denom = sred[0] + sred[1] + sred[2] + sred[3] + 1e-16f;
    __syncthreads();

    float acc = 0.f;
    for (int n = beg; n < end; ++n)
        acc += glogit[n] * H2[(size_t)n * C2 + t];
    const float gc = acc / denom;

    for (int o = 0; o < NOUT; ++o) {
        float p = gc * Wf[t * NOUT + o];
        #pragma unroll
        for (int off = 32; off; off >>= 1) p += __shfl_xor(p, off);
        __syncthreads();
        if (lane == 0) sred[w] = p;
        __syncthreads();
        if (t == 0) out[b * NOUT + o] = sred[0] + sred[1] + sred[2] + sred[3] + bf[o];
    }
}

extern "C" void kernel_launch(void* const* d_in, const int* in_sizes, int n_in,
                              void* d_out, int out_size, void* d_ws, size_t ws_size,
                              hipStream_t stream) {
    (void)in_sizes; (void)n_in; (void)out_size; (void)ws_size;
    const float* x     = (const float*)d_in[0];
    const int*   ei    = (const int*)  d_in[1];
    const int*   batch = (const int*)  d_in[2];
    const float* Wq1 = (const float*)d_in[3];  const float* bq1 = (const float*)d_in[4];
    const float* Wk1 = (const float*)d_in[5];  const float* bk1 = (const float*)d_in[6];
    const float* Wv1 = (const float*)d_in[7];  const float* bv1 = (const float*)d_in[8];
    const float* Ws1 = (const float*)d_in[9];  const float* bs1 = (const float*)d_in[10];
    const float* Wq2 = (const float*)d_in[11]; const float* bq2 = (const float*)d_in[12];
    const float* Wk2 = (const float*)d_in[13]; const float* bk2 = (const float*)d_in[14];
    const float* Wv2 = (const float*)d_in[15]; const float* bv2 = (const float*)d_in[16];
    const float* Ws2 = (const float*)d_in[17]; const float* bs2 = (const float*)d_in[18];
    const float* Wg  = (const float*)d_in[19]; const float* bg  = (const float*)d_in[20];
    const float* Wf  = (const float*)d_in[21]; const float* bf  = (const float*)d_in[22];

    const int* src = ei;
    const int* dst = ei + NE;

    char* base = (char*)d_ws;
    size_t off = 0;
    auto alloc = [&](size_t bytes) -> char* {
        char* p = base + off;
        off = (off + bytes + 255) & ~(size_t)255;
        return p;
    };
    _Float16* xb   = (_Float16*)alloc((size_t)NN * FIN * 2);
    _Float16* wtq1 = (_Float16*)alloc((size_t)NHEAD * C1 * FIN * 2);
    _Float16* wtk1 = (_Float16*)alloc((size_t)NHEAD * C1 * FIN * 2);
    _Float16* bvs1 = (_Float16*)alloc((size_t)C1 * NHEAD * FIN * 2);   // [512, 1024]
    _Float16* wts1 = (_Float16*)alloc((size_t)C1 * FIN * 2);
    _Float16* wtq2 = (_Float16*)alloc((size_t)NHEAD * C2 * C1 * 2);
    _Float16* wtk2 = (_Float16*)alloc((size_t)NHEAD * C2 * C1 * 2);
    _Float16* wtv2 = (_Float16*)alloc((size_t)NHEAD * C2 * C1 * 2);
    _Float16* wts2 = (_Float16*)alloc((size_t)C2 * C1 * 2);
    _Float16* Mst  = (_Float16*)alloc((size_t)NHEAD * FIN * FIN * 2);  // [1024, 128]
    float* uvecs = (float*)alloc((size_t)NHEAD * FIN * 4);
    float* vvecs = (float*)alloc((size_t)NHEAD * FIN * 4);
    float* chd   = (float*)alloc((size_t)NHEAD * 4);
    float* ud    = (float*)alloc((size_t)NN * NHEAD * 4);
    float* vs    = (float*)alloc((size_t)NN * NHEAD * 4);
    float* zbias = (float*)alloc((size_t)NHEAD * FIN * 4);             // zeros [1024]
    float* acc1 = (float*)alloc((size_t)NN * C1 * 4);
    _Float16* h1b = (_Float16*)alloc((size_t)NN * C1 * 2);
    float* alpha = (float*)alloc((size_t)NE * NHEAD * 4);
    float* ev    = (float*)alloc((size_t)NE * NHEAD * 4);
    unsigned* amaxU = (unsigned*)alloc((size_t)NN * NHEAD * 4);
    float* denom = (float*)alloc((size_t)NN * NHEAD * 4);
    int* deg    = (int*)alloc((size_t)NN * 4);
    int* rowptr = (int*)alloc((size_t)(NN + 1) * 4);
    int* cursor = (int*)alloc((size_t)NN * 4);
    int* eids   = (int*)alloc((size_t)NE * 4);
    float* bvm1 = (float*)alloc((size_t)C1 * 4);
    // dynamic region: Tbuf (20.5MB) | Qbuf (41MB) | Kbuf (41MB); Z,V alias Qbuf
    _Float16* Tbuf = (_Float16*)alloc((size_t)NN * NHEAD * FIN * 2);
    _Float16* Qbuf = (_Float16*)alloc((size_t)NN * NHEAD * C2 * 2);
    _Float16* Kbuf = (_Float16*)alloc((size_t)NN * NHEAD * C2 * 2);
    _Float16* Zbuf = Qbuf;   // [NN, 1024] f16 = 20.5MB <= 41MB
    _Float16* Vbuf = Qbuf;
    float* acc2 = acc1;      // conv1 fp32 accum dead once h1b built

    const dim3 blk(256);
    const float sc1 = 1.0f / sqrtf((float)C1);
    const float sc2 = 1.0f / sqrtf((float)C2);
    const int edge_blocks = (NE * 64) / 256;
    const int node_blocks = (NN * 64) / 256;
    const int gy = (NN + 127) / 128;

    // ---- conversions + precompute ----
    cvt_f16<<<((size_t)NN * FIN + 255) / 256, blk, 0, stream>>>(x, xb, NN * FIN);
    {
        dim3 tb(32, 8);
        transpose_cvt<<<dim3(NHEAD * C1 / 32, FIN / 32), tb, 0, stream>>>(Wq1, wtq1, FIN, NHEAD * C1);
        transpose_cvt<<<dim3(NHEAD * C1 / 32, FIN / 32), tb, 0, stream>>>(Wk1, wtk1, FIN, NHEAD * C1);
        transpose_stack<<<dim3(C1 / 32, FIN / 32, NHEAD), tb, 0, stream>>>(Wv1, bvs1, FIN, C1);
        transpose_cvt<<<dim3(C1 / 32, FIN / 32),         tb, 0, stream>>>(Ws1, wts1, FIN, C1);
        transpose_cvt<<<dim3(NHEAD * C2 / 32, C1 / 32),  tb, 0, stream>>>(Wq2, wtq2, C1, NHEAD * C2);
        transpose_cvt<<<dim3(NHEAD * C2 / 32, C1 / 32),  tb, 0, stream>>>(Wk2, wtk2, C1, NHEAD * C2);
        transpose_cvt<<<dim3(NHEAD * C2 / 32, C1 / 32),  tb, 0, stream>>>(Wv2, wtv2, C1, NHEAD * C2);
        transpose_cvt<<<dim3(C2 / 32, C1 / 32),          tb, 0, stream>>>(Ws2, wts2, C1, C2);
    }
    bvmean_k<<<(C1 + 255) / 256, blk, 0, stream>>>(bv1, bvm1, C1);
    mstack_k<<<dim3(FIN / 16, FIN / 16, NHEAD), dim3(16, 16), 0, stream>>>(wtq1, wtk1, Mst);
    uvprep<<<NHEAD, FIN, 0, stream>>>(Wq1, Wk1, bq1, bk1, uvecs, vvecs, chd);
    udvs_k<<<(NN * NHEAD + 255) / 256, blk, 0, stream>>>(xb, uvecs, vvecs, chd, ud, vs);
    zero_i32<<<(NHEAD * FIN + 255) / 256, blk, 0, stream>>>((int*)zbias, NHEAD * FIN);

    // ---- CSR by dst ----
    zero_i32<<<(NN + 255) / 256, blk, 0, stream>>>(deg, NN);
    hist_dst<<<(NE + 255) / 256, blk, 0, stream>>>(dst, deg);
    scan_deg<<<1, blk, 0, stream>>>(deg, rowptr, cursor, NN);
    scatter_edges<<<(NE + 255) / 256, blk, 0, stream>>>(dst, cursor, eids);

    // ================ conv1 (low-rank QK + z-trick aggregation) ================
    gemm_tn<false, false><<<dim3(C1 / 128, gy), blk, 0, stream>>>(
        xb, wts1, bs1, acc1, C1, NN, FIN);                                  // skip
    gemm_tn<true, false><<<dim3(NHEAD * FIN / 128, gy), blk, 0, stream>>>(
        xb, Mst, zbias, Tbuf, NHEAD * FIN, NN, FIN);                        // T = X @ M
    init_seg<<<(NN * NHEAD + 255) / 256, blk, 0, stream>>>(amaxU, denom, NN * NHEAD);
    edge_alpha_lr<<<edge_blocks, blk, 0, stream>>>(Tbuf, xb, ud, vs, src, dst,
                                                   alpha, amaxU, sc1);
    edge_expsum<<<(NE * NHEAD + 255) / 256, blk, 0, stream>>>(alpha, dst, amaxU, ev, denom);
    zaccum<FIN, NHEAD><<<node_blocks, blk, 0, stream>>>(xb, ev, denom, rowptr, eids, src,
                                                        Zbuf, 0);
    gemm_tn<false, true><<<dim3(C1 / 128, gy), blk, 0, stream>>>(
        Zbuf, bvs1, nullptr, acc1, C1, NN, NHEAD * FIN);                    // acc1 += Z @ Wv
    elu_cvt_bias<<<((size_t)NN * C1 + 255) / 256, blk, 0, stream>>>(
        acc1, h1b, bvm1, deg, NN * C1);

    // ================ conv2 (round-6 G=8 fused path) ================
    gemm_tn<false, false><<<dim3(C2 / 128, gy), blk, 0, stream>>>(
        h1b, wts2, bs2, acc2, C2, NN, C1);                                  // skip
    init_seg<<<(NN * NHEAD + 255) / 256, blk, 0, stream>>>(amaxU, denom, NN * NHEAD);
    gemm_tn<true, false><<<dim3(NHEAD * C2 / 128, gy), blk, 0, stream>>>(
        h1b, wtq2, bq2, Qbuf, NHEAD * C2, NN, C1);                          // Q (all heads)
    gemm_tn<true, false><<<dim3(NHEAD * C2 / 128, gy), blk, 0, stream>>>(
        h1b, wtk2, bk2, Kbuf, NHEAD * C2, NN, C1);                          // K (all heads)
    edge_alpha_f<C2><<<edge_blocks, blk, 0, stream>>>(Qbuf, Kbuf, src, dst, alpha, amaxU,
                                                      sc2, 0, NHEAD);
    edge_expsum<<<(NE * NHEAD + 255) / 256, blk, 0, stream>>>(alpha, dst, amaxU, ev, denom);
    gemm_tn<true, false><<<dim3(NHEAD * C2 / 128, gy), blk, 0, stream>>>(
        h1b, wtv2, bv2, Vbuf, NHEAD * C2, NN, C1);                          // V (all heads)
    node_aggr<C2><<<node_blocks, blk, 0, stream>>>(Vbuf, ev, denom, rowptr, eids, src,
                                                   acc2, 0, NHEAD);
    elu_k<<<((size_t)NN * C2 + 255) / 256, blk, 0, stream>>>(acc2, NN * C2);

    // ================ fused pooling + fc ================
    pool_fused<<<NB, blk, 0, stream>>>(acc2, Wg, bg, batch, Wf, bf, alpha, (float*)d_out);
}

// Round 10
// 656.206 us; speedup vs baseline: 1.8816x; 1.0453x over previous
//
#include <hip/hip_runtime.h>
#include <math.h>

#define NN 10000
#define NE 20000
#define FIN 128
#define NHEAD 8
#define C1 512
#define C2 256
#define NB 64
#define NOUT 10

typedef _Float16 half8v __attribute__((ext_vector_type(8)));
typedef _Float16 half4v __attribute__((ext_vector_type(4)));
typedef _Float16 half2v __attribute__((ext_vector_type(2)));
typedef float f32x4 __attribute__((ext_vector_type(4)));

template<int VEC> struct VecT;
template<> struct VecT<2> { using T = half2v; };
template<> struct VecT<4> { using T = half4v; };
template<> struct VecT<8> { using T = half8v; };

__device__ __forceinline__ unsigned enc_f(float f) {
    unsigned u = __float_as_uint(f);
    return (u & 0x80000000u) ? ~u : (u | 0x80000000u);
}
__device__ __forceinline__ float dec_f(unsigned e) {
    return (e & 0x80000000u) ? __uint_as_float(e & 0x7fffffffu) : __uint_as_float(~e);
}

// async global->LDS, 16B per lane; LDS dest = wave-uniform base + lane*16
__device__ __forceinline__ void gload16(const _Float16* g, _Float16* l) {
    __builtin_amdgcn_global_load_lds(
        (const __attribute__((address_space(1))) unsigned int*)(const void*)g,
        (__attribute__((address_space(3))) unsigned int*)(void*)l, 16, 0, 0);
}

// ---------------- conversion / transpose ----------------
__global__ void cvt_f16(const float* __restrict__ in, _Float16* __restrict__ out, int n) {
    int i = blockIdx.x * blockDim.x + threadIdx.x;
    if (i < n) out[i] = (_Float16)in[i];
}

// W [K,N] fp32 -> Wt [N,K] f16. block (32,8)
__global__ void transpose_cvt(const float* __restrict__ W, _Float16* __restrict__ Wt,
                              int K, int N) {
    __shared__ float tile[32][33];
    int n0 = blockIdx.x * 32, k0 = blockIdx.y * 32;
    int tx = threadIdx.x, ty = threadIdx.y;
    for (int j = ty; j < 32; j += 8) tile[j][tx] = W[(size_t)(k0 + j) * N + n0 + tx];
    __syncthreads();
    for (int j = ty; j < 32; j += 8)
        Wt[(size_t)(n0 + j) * K + k0 + tx] = (_Float16)tile[tx][j];
}

// Wv [Cin, NHEAD*Cout] fp32 -> Bt [Cout, NHEAD*Cin] f16, Bt[c, h*Cin+k] = Wv[k, h*Cout+c]
__global__ void transpose_stack(const float* __restrict__ Wv, _Float16* __restrict__ Bt,
                                int Cin, int Cout) {
    __shared__ float tile[32][33];
    int h = blockIdx.z;
    int c0 = blockIdx.x * 32, k0 = blockIdx.y * 32;
    int tx = threadIdx.x, ty = threadIdx.y;
    for (int j = ty; j < 32; j += 8)
        tile[j][tx] = Wv[(size_t)(k0 + j) * (NHEAD * Cout) + (size_t)h * Cout + c0 + tx];
    __syncthreads();
    for (int j = ty; j < 32; j += 8)
        Bt[(size_t)(c0 + j) * (NHEAD * Cin) + (size_t)h * Cin + k0 + tx] = (_Float16)tile[tx][j];
}

__global__ void bvmean_k(const float* __restrict__ bv, float* __restrict__ bvm, int C) {
    int c = blockIdx.x * blockDim.x + threadIdx.x;
    if (c >= C) return;
    float s = 0.f;
    #pragma unroll
    for (int h = 0; h < NHEAD; ++h) s += bv[h * C + c];
    bvm[c] = s * (1.0f / NHEAD);
}

__global__ void concat_bias3(const float* __restrict__ a, const float* __restrict__ b,
                             const float* __restrict__ c, float* __restrict__ o) {
    int i = blockIdx.x * blockDim.x + threadIdx.x;
    const int n = NHEAD * C2;
    if (i < n) o[i] = a[i];
    else if (i < 2 * n) o[i] = b[i - n];
    else if (i < 3 * n) o[i] = c[i - 2 * n];
}

// ---------------- conv1 low-rank QK precompute ----------------
__global__ void mstack_k(const _Float16* __restrict__ wtq1, const _Float16* __restrict__ wtk1,
                         _Float16* __restrict__ Mst) {
    int h = blockIdx.z;
    int i = blockIdx.x * 16 + threadIdx.x;
    int j = blockIdx.y * 16 + threadIdx.y;
    float acc = 0.f;
    for (int c = 0; c < C1; ++c)
        acc += (float)wtq1[((size_t)h * C1 + c) * FIN + i] *
               (float)wtk1[((size_t)h * C1 + c) * FIN + j];
    Mst[((size_t)h * FIN + j) * FIN + i] = (_Float16)acc;
}

__global__ void uvprep(const float* __restrict__ Wq1, const float* __restrict__ Wk1,
                       const float* __restrict__ bq1, const float* __restrict__ bk1,
                       float* __restrict__ u, float* __restrict__ v, float* __restrict__ ch) {
    int h = blockIdx.x, i = threadIdx.x;  // block 128
    float su = 0.f, sv = 0.f;
    for (int c = 0; c < C1; ++c) {
        su += Wq1[(size_t)i * (NHEAD * C1) + h * C1 + c] * bk1[h * C1 + c];
        sv += Wk1[(size_t)i * (NHEAD * C1) + h * C1 + c] * bq1[h * C1 + c];
    }
    u[h * FIN + i] = su;
    v[h * FIN + i] = sv;
    if (i == 0) {
        float s = 0.f;
        for (int c = 0; c < C1; ++c) s += bq1[h * C1 + c] * bk1[h * C1 + c];
        ch[h] = s;
    }
}

__global__ void udvs_k(const _Float16* __restrict__ xb, const float* __restrict__ u,
                       const float* __restrict__ v, const float* __restrict__ ch,
                       float* __restrict__ ud, float* __restrict__ vs) {
    int idx = blockIdx.x * blockDim.x + threadIdx.x;
    if (idx >= NN * NHEAD) return;
    int n = idx >> 3, h = idx & 7;
    float su = ch[h], sv = 0.f;
    for (int i = 0; i < FIN; ++i) {
        float xv = (float)xb[(size_t)n * FIN + i];
        su += xv * u[h * FIN + i];
        sv += xv * v[h * FIN + i];
    }
    ud[idx] = su;
    vs[idx] = sv;
}

// ---------------- MFMA GEMM (m97 structure: global_load_lds, linear LDS [128][32]) ----------------
// C[M, Ncols] = A[M,K] @ Bt[Ncols,K]^T (+bias | +=C). Ncols%128==0, K%32==0, 16B-aligned ptrs.
template<bool OUT_HALF, bool ACCUM>
__global__ __launch_bounds__(256) void gemm_tn(
    const _Float16* __restrict__ A, const _Float16* __restrict__ Bt,
    const float* __restrict__ bias, void* __restrict__ Cout, int ldc,
    int M, int K)
{
    __shared__ _Float16 As[128 * 32];   // linear: row*32 + k (64B rows)
    __shared__ _Float16 Bs[128 * 32];
    const int t = threadIdx.x;
    const int m0 = blockIdx.y * 128, n0 = blockIdx.x * 128;
    const int w = t >> 6, lane = t & 63;
    const int wr = w >> 1, wc = w & 1;
    const int r_lo = lane >> 2, slot = lane & 3;   // staging: 16 rows/chunk, 4 lanes/row

    f32x4 acc[4][4];
    #pragma unroll
    for (int m = 0; m < 4; ++m)
        #pragma unroll
        for (int n = 0; n < 4; ++n)
            #pragma unroll
            for (int j = 0; j < 4; ++j) acc[m][n][j] = 0.f;

    for (int k0 = 0; k0 < K; k0 += 32) {
        #pragma unroll
        for (int i = 0; i < 2; ++i) {
            int chunk = 2 * w + i;            // wave-uniform
            int row = chunk * 16 + r_lo;
            int gr = m0 + row; gr = gr < M ? gr : M - 1;
            gload16(A + (size_t)gr * K + k0 + slot * 8, &As[chunk * 512]);
            gload16(Bt + (size_t)(n0 + row) * K + k0 + slot * 8, &Bs[chunk * 512]);
        }
        __syncthreads();   // vmcnt(0) drain + barrier
        half8v af[4], bf[4];
        #pragma unroll
        for (int m = 0; m < 4; ++m)
            af[m] = *(const half8v*)(&As[(wr * 64 + m * 16 + (lane & 15)) * 32 + (lane >> 4) * 8]);
        #pragma unroll
        for (int n = 0; n < 4; ++n)
            bf[n] = *(const half8v*)(&Bs[(wc * 64 + n * 16 + (lane & 15)) * 32 + (lane >> 4) * 8]);
        #pragma unroll
        for (int m = 0; m < 4; ++m)
            #pragma unroll
            for (int n = 0; n < 4; ++n)
                acc[m][n] = __builtin_amdgcn_mfma_f32_16x16x32_f16(af[m], bf[n], acc[m][n], 0, 0, 0);
        __syncthreads();
    }
    #pragma unroll
    for (int m = 0; m < 4; ++m) {
        int r0 = m0 + wr * 64 + m * 16 + (lane >> 4) * 4;
        #pragma unroll
        for (int n = 0; n < 4; ++n) {
            int col = n0 + wc * 64 + n * 16 + (lane & 15);
            float b = 0.f;
            if (!ACCUM) b = bias[col];
            #pragma unroll
            for (int r = 0; r < 4; ++r) {
                int row = r0 + r;
                if (row < M) {
                    float v = acc[m][n][r] + b;
                    if (ACCUM) v += ((float*)Cout)[(size_t)row * ldc + col];
                    if (OUT_HALF) ((_Float16*)Cout)[(size_t)row * ldc + col] = (_Float16)v;
                    else          ((float*)Cout)[(size_t)row * ldc + col] = v;
                }
            }
        }
    }
}

// ---------------- CSR build (by dst) ----------------
__global__ void zero_i32(int* __restrict__ p, int n) {
    int i = blockIdx.x * blockDim.x + threadIdx.x;
    if (i < n) p[i] = 0;
}
__global__ void hist_dst(const int* __restrict__ dst, int* __restrict__ deg) {
    int e = blockIdx.x * blockDim.x + threadIdx.x;
    if (e < NE) atomicAdd(&deg[dst[e]], 1);
}
__global__ void scan_deg(const int* __restrict__ deg, int* __restrict__ rowptr,
                         int* __restrict__ cursor, int n) {
    __shared__ int s[256];
    __shared__ int carry;
    int t = threadIdx.x;
    if (t == 0) carry = 0;
    __syncthreads();
    for (int base = 0; base < n; base += 256) {
        int v = (base + t < n) ? deg[base + t] : 0;
        s[t] = v;
        __syncthreads();
        for (int off = 1; off < 256; off <<= 1) {
            int x = (t >= off) ? s[t - off] : 0;
            __syncthreads();
            s[t] += x;
            __syncthreads();
        }
        int excl = carry + s[t] - v;
        if (base + t < n) { rowptr[base + t] = excl; cursor[base + t] = excl; }
        __syncthreads();
        if (t == 255) carry += s[255];
        __syncthreads();
    }
    if (t == 0) rowptr[n] = carry;
}
__global__ void scatter_edges(const int* __restrict__ dst, int* __restrict__ cursor,
                              int* __restrict__ eids) {
    int e = blockIdx.x * blockDim.x + threadIdx.x;
    if (e < NE) {
        int pos = atomicAdd(&cursor[dst[e]], 1);
        eids[pos] = e;
    }
}

// ---------------- segment softmax pieces ----------------
__global__ void init_seg(unsigned* __restrict__ amax, float* __restrict__ denom, int n) {
    int i = blockIdx.x * blockDim.x + threadIdx.x;
    if (i < n) { amax[i] = 0x007FFFFFu; denom[i] = 0.f; }
}

// conv1 low-rank edge logits
__global__ void edge_alpha_lr(const _Float16* __restrict__ T, const _Float16* __restrict__ X,
                              const float* __restrict__ ud, const float* __restrict__ vs,
                              const int* __restrict__ src, const int* __restrict__ dst,
                              float* __restrict__ alpha, unsigned* __restrict__ amaxU,
                              float scale)
{
    int gi = blockIdx.x * blockDim.x + threadIdx.x;
    int e = gi >> 6, lane = threadIdx.x & 63;
    if (e >= NE) return;
    int s = src[e], d = dst[e];
    half2v xv = *(const half2v*)(X + (size_t)s * FIN + lane * 2);
    #pragma unroll
    for (int h = 0; h < NHEAD; ++h) {
        half2v tv = *(const half2v*)(T + ((size_t)d * NHEAD + h) * FIN + lane * 2);
        float sum = (float)tv[0] * (float)xv[0] + (float)tv[1] * (float)xv[1];
        #pragma unroll
        for (int off = 32; off; off >>= 1) sum += __shfl_xor(sum, off);
        if (lane == 0) {
            float al = (sum + ud[(size_t)d * NHEAD + h] + vs[(size_t)s * NHEAD + h]) * scale;
            alpha[(size_t)e * NHEAD + h] = al;
            atomicMax(&amaxU[(size_t)d * NHEAD + h], enc_f(al));
        }
    }
}

// conv2 fused-head edge logits; Q,K rows have stride ldq
template<int C>
__global__ void edge_alpha_f(const _Float16* __restrict__ Q, const _Float16* __restrict__ Kh,
                             int ldq, const int* __restrict__ src, const int* __restrict__ dst,
                             float* __restrict__ alpha, unsigned* __restrict__ amaxU,
                             float scale, int hbase, int G)
{
    constexpr int VEC = C / 64;
    using vecH = typename VecT<VEC>::T;
    int gi = blockIdx.x * blockDim.x + threadIdx.x;
    int e = gi >> 6, lane = threadIdx.x & 63;
    if (e >= NE) return;
    int s = src[e], d = dst[e];
    const _Float16* qp = Q + (size_t)d * ldq + lane * VEC;
    const _Float16* kp = Kh + (size_t)s * ldq + lane * VEC;
    for (int h = 0; h < G; ++h) {
        vecH q = *(const vecH*)(qp + h * C);
        vecH k = *(const vecH*)(kp + h * C);
        float sum = 0.f;
        #pragma unroll
        for (int j = 0; j < VEC; ++j) sum += (float)q[j] * (float)k[j];
        #pragma unroll
        for (int off = 32; off; off >>= 1) sum += __shfl_xor(sum, off);
        if (lane == 0) {
            float al = sum * scale;
            alpha[(size_t)e * NHEAD + hbase + h] = al;
            atomicMax(&amaxU[(size_t)d * NHEAD + hbase + h], enc_f(al));
        }
    }
}

__global__ void edge_expsum(const float* __restrict__ alpha, const int* __restrict__ dst,
                            const unsigned* __restrict__ amaxU,
                            float* __restrict__ ev, float* __restrict__ denom)
{
    int i = blockIdx.x * blockDim.x + threadIdx.x;
    if (i >= NE * NHEAD) return;
    int e = i >> 3, h = i & 7;
    int d = dst[e];
    float ex = expf(alpha[i] - dec_f(amaxU[(size_t)d * NHEAD + h]));
    ev[i] = ex;
    atomicAdd(&denom[(size_t)d * NHEAD + h], ex);
}

// conv1 z-trick
template<int C, int G>
__global__ void zaccum(const _Float16* __restrict__ X, const float* __restrict__ ev,
                       const float* __restrict__ denom, const int* __restrict__ rowptr,
                       const int* __restrict__ eids, const int* __restrict__ src,
                       _Float16* __restrict__ Z, int hbase)
{
    constexpr int VEC = C / 64;
    using vecH = typename VecT<VEC>::T;
    int gi = blockIdx.x * blockDim.x + threadIdx.x;
    int n = gi >> 6, lane = threadIdx.x & 63;
    if (n >= NN) return;
    int beg = rowptr[n], end = rowptr[n + 1];
    float rd[G];
    #pragma unroll
    for (int h = 0; h < G; ++h)
        rd[h] = (1.0f / NHEAD) / (denom[(size_t)n * NHEAD + hbase + h] + 1e-16f);
    float acc[G][VEC];
    #pragma unroll
    for (int h = 0; h < G; ++h)
        #pragma unroll
        for (int j = 0; j < VEC; ++j) acc[h][j] = 0.f;
    for (int i = beg; i < end; ++i) {
        int e = eids[i];
        int s = src[e];
        vecH xv = *(const vecH*)(X + (size_t)s * C + lane * VEC);
        #pragma unroll
        for (int h = 0; h < G; ++h) {
            float cf = ev[(size_t)e * NHEAD + hbase + h] * rd[h];
            #pragma unroll
            for (int j = 0; j < VEC; ++j) acc[h][j] += cf * (float)xv[j];
        }
    }
    #pragma unroll
    for (int h = 0; h < G; ++h) {
        vecH o;
        #pragma unroll
        for (int j = 0; j < VEC; ++j) o[j] = (_Float16)acc[h][j];
        *(vecH*)(Z + (size_t)n * (G * C) + (size_t)h * C + lane * VEC) = o;
    }
}

// conv2 aggregation: one wave per node; V rows have stride ldv
template<int C>
__global__ void node_aggr(const _Float16* __restrict__ V, int ldv,
                          const float* __restrict__ ev, const float* __restrict__ denom,
                          const int* __restrict__ rowptr, const int* __restrict__ eids,
                          const int* __restrict__ src, float* __restrict__ acc,
                          int hbase, int G)
{
    constexpr int VEC = C / 64;
    using vecH = typename VecT<VEC>::T;
    int gi = blockIdx.x * blockDim.x + threadIdx.x;
    int n = gi >> 6, lane = threadIdx.x & 63;
    if (n >= NN) return;
    int beg = rowptr[n], end = rowptr[n + 1];
    float a[VEC];
    #pragma unroll
    for (int j = 0; j < VEC; ++j) a[j] = 0.f;
    for (int h = 0; h < G; ++h) {
        float rd = 1.f / (denom[(size_t)n * NHEAD + hbase + h] + 1e-16f) * (1.f / NHEAD);
        for (int i = beg; i < end; ++i) {
            int e = eids[i];
            int s = src[e];
            float coeff = ev[(size_t)e * NHEAD + hbase + h] * rd;
            vecH v = *(const vecH*)(V + (size_t)s * ldv + h * C + lane * VEC);
            #pragma unroll
            for (int j = 0; j < VEC; ++j) a[j] += coeff * (float)v[j];
        }
    }
    float* ap = acc + (size_t)n * C + lane * VEC;
    #pragma unroll
    for (int j = 0; j < VEC; ++j) ap[j] += a[j];
}

__global__ void elu_k(float* __restrict__ x, int n) {
    int i = blockIdx.x * blockDim.x + threadIdx.x;
    if (i < n) { float v = x[i]; x[i] = v > 0.f ? v : expm1f(v); }
}
__global__ void elu_cvt_bias(const float* __restrict__ in, _Float16* __restrict__ out,
                             const float* __restrict__ bvm, const int* __restrict__ deg,
                             int total) {
    int i = blockIdx.x * blockDim.x + threadIdx.x;
    if (i >= total) return;
    int c = i & (C1 - 1), n = i >> 9;
    float v = in[i] + (deg[n] > 0 ? bvm[c] : 0.f);
    v = v > 0.f ? v : expm1f(v);
    out[i] = (_Float16)v;
}

// ---------------- fused global-attention pooling + final fc ----------------
__global__ __launch_bounds__(256) void pool_fused(
    const float* __restrict__ H2, const float* __restrict__ Wg,
    const float* __restrict__ bg, const int* __restrict__ batch,
    const float* __restrict__ Wf, const float* __restrict__ bf,
    float* __restrict__ glogit, float* __restrict__ out)
{
    const int b = blockIdx.x;
    const int t = threadIdx.x, lane = t & 63, w = t >> 6;
    __shared__ int sbeg, send;
    __shared__ float sred[4];
    if (t == 0) {
        int lo = 0, hi = NN;
        while (lo < hi) { int mid = (lo + hi) >> 1; if (batch[mid] < b) lo = mid + 1; else hi = mid; }
        sbeg = lo;
        hi = NN;
        while (lo < hi) { int mid = (lo + hi) >> 1; if (batch[mid] < b + 1) lo = mid + 1; else hi = mid; }
        send = lo;
    }
    __syncthreads();
    const int beg = sbeg, end = send;
    const float bg0 = bg[0];

    float lmax = -INFINITY;
    for (int n = beg + w; n < end; n += 4) {
        float4 h = ((const float4*)(H2 + (size_t)n * C2))[lane];
        float4 wv = ((const float4*)Wg)[lane];
        float sum = h.x * wv.x + h.y * wv.y + h.z * wv.z + h.w * wv.w;
        #pragma unroll
        for (int off = 32; off; off >>= 1) sum += __shfl_xor(sum, off);
        sum += bg0;
        if (lane == 0) glogit[n] = sum;
        lmax = fmaxf(lmax, sum);
    }
    if (lane == 0) sred[w] = lmax;
    __syncthreads();
    float m = fmaxf(fmaxf(sred[0], sred[1]), fmaxf(sred[2], sred[3]));
    if (!isfinite(m)) m = 0.f;
    __syncthreads();

    float ls = 0.f;
    for (int n = beg + t; n < end; n += 256) {
        float e = expf(glogit[n] - m);
        glogit[n] = e;
        ls += e;
    }
    #pragma unroll
    for (int off = 32; off; off >>= 1) ls += __shfl_xor(ls, off);
    if (lane == 0) sred[w] = ls;
    __syncthreads();
    const float denom = sred[0] + sred[1] + sred[2] + sred[3] + 1e-16f;
    __syncthreads();

    float acc = 0.f;
    for (int n = beg; n < end; ++n)
        acc += glogit[n] * H2[(size_t)n * C2 + t];
    const float gc = acc / denom;

    for (int o = 0; o < NOUT; ++o) {
        float p = gc * Wf[t * NOUT + o];
        #pragma unroll
        for (int off = 32; off; off >>= 1) p += __shfl_xor(p, off);
        __syncthreads();
        if (lane == 0) sred[w] = p;
        __syncthreads();
        if (t == 0) out[b * NOUT + o] = sred[0] + sred[1] + sred[2] + sred[3] + bf[o];
    }
}

extern "C" void kernel_launch(void* const* d_in, const int* in_sizes, int n_in,
                              void* d_out, int out_size, void* d_ws, size_t ws_size,
                              hipStream_t stream) {
    (void)in_sizes; (void)n_in; (void)out_size; (void)ws_size;
    const float* x     = (const float*)d_in[0];
    const int*   ei    = (const int*)  d_in[1];
    const int*   batch = (const int*)  d_in[2];
    const float* Wq1 = (const float*)d_in[3];  const float* bq1 = (const float*)d_in[4];
    const float* Wk1 = (const float*)d_in[5];  const float* bk1 = (const float*)d_in[6];
    const float* Wv1 = (const float*)d_in[7];  const float* bv1 = (const float*)d_in[8];
    const float* Ws1 = (const float*)d_in[9];  const float* bs1 = (const float*)d_in[10];
    const float* Wq2 = (const float*)d_in[11]; const float* bq2 = (const float*)d_in[12];
    const float* Wk2 = (const float*)d_in[13]; const float* bk2 = (const float*)d_in[14];
    const float* Wv2 = (const float*)d_in[15]; const float* bv2 = (const float*)d_in[16];
    const float* Ws2 = (const float*)d_in[17]; const float* bs2 = (const float*)d_in[18];
    const float* Wg  = (const float*)d_in[19]; const float* bg  = (const float*)d_in[20];
    const float* Wf  = (const float*)d_in[21]; const float* bf  = (const float*)d_in[22];

    const int* src = ei;
    const int* dst = ei + NE;

    char* base = (char*)d_ws;
    size_t off = 0;
    auto alloc = [&](size_t bytes) -> char* {
        char* p = base + off;
        off = (off + bytes + 255) & ~(size_t)255;
        return p;
    };
    _Float16* xb    = (_Float16*)alloc((size_t)NN * FIN * 2);
    _Float16* wtq1  = (_Float16*)alloc((size_t)NHEAD * C1 * FIN * 2);
    _Float16* wtk1  = (_Float16*)alloc((size_t)NHEAD * C1 * FIN * 2);
    _Float16* bvs1  = (_Float16*)alloc((size_t)C1 * NHEAD * FIN * 2);   // [512, 1024]
    _Float16* wts1  = (_Float16*)alloc((size_t)C1 * FIN * 2);
    _Float16* wqkv2 = (_Float16*)alloc((size_t)3 * NHEAD * C2 * C1 * 2); // [6144, 512]
    _Float16* wts2  = (_Float16*)alloc((size_t)C2 * C1 * 2);
    _Float16* Mst   = (_Float16*)alloc((size_t)NHEAD * FIN * FIN * 2);  // [1024, 128]
    float* uvecs = (float*)alloc((size_t)NHEAD * FIN * 4);
    float* vvecs = (float*)alloc((size_t)NHEAD * FIN * 4);
    float* chd   = (float*)alloc((size_t)NHEAD * 4);
    float* ud    = (float*)alloc((size_t)NN * NHEAD * 4);
    float* vs    = (float*)alloc((size_t)NN * NHEAD * 4);
    float* zbias = (float*)alloc((size_t)NHEAD * FIN * 4);              // zeros [1024]
    float* bqkv2 = (float*)alloc((size_t)3 * NHEAD * C2 * 4);           // [6144]
    float* acc1  = (float*)alloc((size_t)NN * C1 * 4);
    _Float16* h1b = (_Float16*)alloc((size_t)NN * C1 * 2);
    float* alpha = (float*)alloc((size_t)NE * NHEAD * 4);
    float* ev    = (float*)alloc((size_t)NE * NHEAD * 4);
    unsigned* amaxU = (unsigned*)alloc((size_t)NN * NHEAD * 4);
    float* denom = (float*)alloc((size_t)NN * NHEAD * 4);
    int* deg    = (int*)alloc((size_t)NN * 4);
    int* rowptr = (int*)alloc((size_t)(NN + 1) * 4);
    int* cursor = (int*)alloc((size_t)NN * 4);
    int* eids   = (int*)alloc((size_t)NE * 4);
    float* bvm1 = (float*)alloc((size_t)C1 * 4);
    // dynamic: Tbuf 20.5MB | QKVbuf 123MB  (total ws ~193MB; ws>=239MB proven in r6)
    _Float16* Tbuf   = (_Float16*)alloc((size_t)NN * NHEAD * FIN * 2);
    _Float16* QKVbuf = (_Float16*)alloc((size_t)NN * 3 * NHEAD * C2 * 2);
    _Float16* Zbuf = QKVbuf;   // z-phase alias (20.5MB <= 123MB)
    float* acc2 = acc1;
    const int LDQKV = 3 * NHEAD * C2;   // 6144

    const dim3 blk(256);
    const float sc1 = 1.0f / sqrtf((float)C1);
    const float sc2 = 1.0f / sqrtf((float)C2);
    const int edge_blocks = (NE * 64) / 256;
    const int node_blocks = (NN * 64) / 256;
    const int gy = (NN + 127) / 128;

    // ---- conversions + precompute ----
    cvt_f16<<<((size_t)NN * FIN + 255) / 256, blk, 0, stream>>>(x, xb, NN * FIN);
    {
        dim3 tb(32, 8);
        transpose_cvt<<<dim3(NHEAD * C1 / 32, FIN / 32), tb, 0, stream>>>(Wq1, wtq1, FIN, NHEAD * C1);
        transpose_cvt<<<dim3(NHEAD * C1 / 32, FIN / 32), tb, 0, stream>>>(Wk1, wtk1, FIN, NHEAD * C1);
        transpose_stack<<<dim3(C1 / 32, FIN / 32, NHEAD), tb, 0, stream>>>(Wv1, bvs1, FIN, C1);
        transpose_cvt<<<dim3(C1 / 32, FIN / 32),         tb, 0, stream>>>(Ws1, wts1, FIN, C1);
        transpose_cvt<<<dim3(NHEAD * C2 / 32, C1 / 32),  tb, 0, stream>>>(Wq2, wqkv2, C1, NHEAD * C2);
        transpose_cvt<<<dim3(NHEAD * C2 / 32, C1 / 32),  tb, 0, stream>>>(
            Wk2, wqkv2 + (size_t)NHEAD * C2 * C1, C1, NHEAD * C2);
        transpose_cvt<<<dim3(NHEAD * C2 / 32, C1 / 32),  tb, 0, stream>>>(
            Wv2, wqkv2 + (size_t)2 * NHEAD * C2 * C1, C1, NHEAD * C2);
        transpose_cvt<<<dim3(C2 / 32, C1 / 32),          tb, 0, stream>>>(Ws2, wts2, C1, C2);
    }
    bvmean_k<<<(C1 + 255) / 256, blk, 0, stream>>>(bv1, bvm1, C1);
    mstack_k<<<dim3(FIN / 16, FIN / 16, NHEAD), dim3(16, 16), 0, stream>>>(wtq1, wtk1, Mst);
    uvprep<<<NHEAD, FIN, 0, stream>>>(Wq1, Wk1, bq1, bk1, uvecs, vvecs, chd);
    udvs_k<<<(NN * NHEAD + 255) / 256, blk, 0, stream>>>(xb, uvecs, vvecs, chd, ud, vs);
    zero_i32<<<(NHEAD * FIN + 255) / 256, blk, 0, stream>>>((int*)zbias, NHEAD * FIN);
    concat_bias3<<<(3 * NHEAD * C2 + 255) / 256, blk, 0, stream>>>(bq2, bk2, bv2, bqkv2);

    // ---- CSR by dst ----
    zero_i32<<<(NN + 255) / 256, blk, 0, stream>>>(deg, NN);
    hist_dst<<<(NE + 255) / 256, blk, 0, stream>>>(dst, deg);
    scan_deg<<<1, blk, 0, stream>>>(deg, rowptr, cursor, NN);
    scatter_edges<<<(NE + 255) / 256, blk, 0, stream>>>(dst, cursor, eids);

    // ================ conv1 (low-rank QK + z-trick aggregation) ================
    gemm_tn<true, false><<<dim3(NHEAD * FIN / 128, gy), blk, 0, stream>>>(
        xb, Mst, zbias, Tbuf, NHEAD * FIN, NN, FIN);                        // T = X @ M
    init_seg<<<(NN * NHEAD + 255) / 256, blk, 0, stream>>>(amaxU, denom, NN * NHEAD);
    edge_alpha_lr<<<edge_blocks, blk, 0, stream>>>(Tbuf, xb, ud, vs, src, dst,
                                                   alpha, amaxU, sc1);
    edge_expsum<<<(NE * NHEAD + 255) / 256, blk, 0, stream>>>(alpha, dst, amaxU, ev, denom);
    gemm_tn<false, false><<<dim3(C1 / 128, gy), blk, 0, stream>>>(
        xb, wts1, bs1, acc1, C1, NN, FIN);                                  // skip
    zaccum<FIN, NHEAD><<<node_blocks, blk, 0, stream>>>(xb, ev, denom, rowptr, eids, src,
                                                        Zbuf, 0);
    gemm_tn<false, true><<<dim3(C1 / 128, gy), blk, 0, stream>>>(
        Zbuf, bvs1, nullptr, acc1, C1, NN, NHEAD * FIN);                    // acc1 += Z @ Wv
    elu_cvt_bias<<<((size_t)NN * C1 + 255) / 256, blk, 0, stream>>>(
        acc1, h1b, bvm1, deg, NN * C1);

    // ================ conv2 (merged QKV GEMM, G=8 fused edge/aggr) ================
    gemm_tn<false, false><<<dim3(C2 / 128, gy), blk, 0, stream>>>(
        h1b, wts2, bs2, acc2, C2, NN, C1);                                  // skip
    init_seg<<<(NN * NHEAD + 255) / 256, blk, 0, stream>>>(amaxU, denom, NN * NHEAD);
    gemm_tn<true, false><<<dim3(LDQKV / 128, gy), blk, 0, stream>>>(
        h1b, wqkv2, bqkv2, QKVbuf, LDQKV, NN, C1);                          // Q|K|V all heads
    edge_alpha_f<C2><<<edge_blocks, blk, 0, stream>>>(
        QKVbuf, QKVbuf + NHEAD * C2, LDQKV, src, dst, alpha, amaxU, sc2, 0, NHEAD);
    edge_expsum<<<(NE * NHEAD + 255) / 256, blk, 0, stream>>>(alpha, dst, amaxU, ev, denom);
    node_aggr<C2><<<node_blocks, blk, 0, stream>>>(
        QKVbuf + 2 * NHEAD * C2, LDQKV, ev, denom, rowptr, eids, src, acc2, 0, NHEAD);
    elu_k<<<((size_t)NN * C2 + 255) / 256, blk, 0, stream>>>(acc2, NN * C2);

    // ================ fused pooling + fc ================
    pool_fused<<<NB, blk, 0, stream>>>(acc2, Wg, bg, batch, Wf, bf, alpha, (float*)d_out);
}

// Round 11
// 617.596 us; speedup vs baseline: 1.9992x; 1.0625x over previous
//
#include <hip/hip_runtime.h>
#include <math.h>

#define NN 10000
#define NE 20000
#define FIN 128
#define NHEAD 8
#define C1 512
#define C2 256
#define NB 64
#define NOUT 10

typedef _Float16 half8v __attribute__((ext_vector_type(8)));
typedef _Float16 half4v __attribute__((ext_vector_type(4)));
typedef _Float16 half2v __attribute__((ext_vector_type(2)));
typedef float f32x4 __attribute__((ext_vector_type(4)));

template<int VEC> struct VecT;
template<> struct VecT<2> { using T = half2v; };
template<> struct VecT<4> { using T = half4v; };
template<> struct VecT<8> { using T = half8v; };

__device__ __forceinline__ unsigned enc_f(float f) {
    unsigned u = __float_as_uint(f);
    return (u & 0x80000000u) ? ~u : (u | 0x80000000u);
}
__device__ __forceinline__ float dec_f(unsigned e) {
    return (e & 0x80000000u) ? __uint_as_float(e & 0x7fffffffu) : __uint_as_float(~e);
}

// async global->LDS, 16B per lane; LDS dest = wave-uniform base + lane*16
__device__ __forceinline__ void gload16(const _Float16* g, _Float16* l) {
    __builtin_amdgcn_global_load_lds(
        (const __attribute__((address_space(1))) unsigned int*)(const void*)g,
        (__attribute__((address_space(3))) unsigned int*)(void*)l, 16, 0, 0);
}

// ---------------- conversion / transpose ----------------
__global__ void cvt_f16(const float* __restrict__ in, _Float16* __restrict__ out, int n) {
    int i = blockIdx.x * blockDim.x + threadIdx.x;
    if (i < n) out[i] = (_Float16)in[i];
}

__global__ void transpose_cvt(const float* __restrict__ W, _Float16* __restrict__ Wt,
                              int K, int N) {
    __shared__ float tile[32][33];
    int n0 = blockIdx.x * 32, k0 = blockIdx.y * 32;
    int tx = threadIdx.x, ty = threadIdx.y;
    for (int j = ty; j < 32; j += 8) tile[j][tx] = W[(size_t)(k0 + j) * N + n0 + tx];
    __syncthreads();
    for (int j = ty; j < 32; j += 8)
        Wt[(size_t)(n0 + j) * K + k0 + tx] = (_Float16)tile[tx][j];
}

__global__ void transpose_stack(const float* __restrict__ Wv, _Float16* __restrict__ Bt,
                                int Cin, int Cout) {
    __shared__ float tile[32][33];
    int h = blockIdx.z;
    int c0 = blockIdx.x * 32, k0 = blockIdx.y * 32;
    int tx = threadIdx.x, ty = threadIdx.y;
    for (int j = ty; j < 32; j += 8)
        tile[j][tx] = Wv[(size_t)(k0 + j) * (NHEAD * Cout) + (size_t)h * Cout + c0 + tx];
    __syncthreads();
    for (int j = ty; j < 32; j += 8)
        Bt[(size_t)(c0 + j) * (NHEAD * Cin) + (size_t)h * Cin + k0 + tx] = (_Float16)tile[tx][j];
}

__global__ void bvmean_k(const float* __restrict__ bv, float* __restrict__ bvm, int C) {
    int c = blockIdx.x * blockDim.x + threadIdx.x;
    if (c >= C) return;
    float s = 0.f;
    #pragma unroll
    for (int h = 0; h < NHEAD; ++h) s += bv[h * C + c];
    bvm[c] = s * (1.0f / NHEAD);
}

// bias concat builders
__global__ void bcat1_k(const float* __restrict__ bs1, float* __restrict__ o) {
    int i = blockIdx.x * blockDim.x + threadIdx.x;
    if (i < NHEAD * FIN + C1) o[i] = (i < NHEAD * FIN) ? 0.f : bs1[i - NHEAD * FIN];
}
__global__ void bcat2_k(const float* __restrict__ bq2, const float* __restrict__ bk2,
                        const float* __restrict__ bv2, const float* __restrict__ bs2,
                        float* __restrict__ o) {
    int i = blockIdx.x * blockDim.x + threadIdx.x;
    const int n = NHEAD * C2;
    if (i < n) o[i] = bq2[i];
    else if (i < 2 * n) o[i] = bk2[i - n];
    else if (i < 3 * n) o[i] = bv2[i - 2 * n];
    else if (i < 3 * n + C2) o[i] = bs2[i - 3 * n];
}

// ---------------- conv1 low-rank QK precompute ----------------
__global__ void mstack_k(const _Float16* __restrict__ wtq1, const _Float16* __restrict__ wtk1,
                         _Float16* __restrict__ Mst) {
    int h = blockIdx.z;
    int i = blockIdx.x * 16 + threadIdx.x;
    int j = blockIdx.y * 16 + threadIdx.y;
    float acc = 0.f;
    for (int c = 0; c < C1; ++c)
        acc += (float)wtq1[((size_t)h * C1 + c) * FIN + i] *
               (float)wtk1[((size_t)h * C1 + c) * FIN + j];
    Mst[((size_t)h * FIN + j) * FIN + i] = (_Float16)acc;
}

__global__ void uvprep(const float* __restrict__ Wq1, const float* __restrict__ Wk1,
                       const float* __restrict__ bq1, const float* __restrict__ bk1,
                       float* __restrict__ u, float* __restrict__ v, float* __restrict__ ch) {
    int h = blockIdx.x, i = threadIdx.x;  // block 128
    float su = 0.f, sv = 0.f;
    for (int c = 0; c < C1; ++c) {
        su += Wq1[(size_t)i * (NHEAD * C1) + h * C1 + c] * bk1[h * C1 + c];
        sv += Wk1[(size_t)i * (NHEAD * C1) + h * C1 + c] * bq1[h * C1 + c];
    }
    u[h * FIN + i] = su;
    v[h * FIN + i] = sv;
    if (i == 0) {
        float s = 0.f;
        for (int c = 0; c < C1; ++c) s += bq1[h * C1 + c] * bk1[h * C1 + c];
        ch[h] = s;
    }
}

__global__ void udvs_k(const _Float16* __restrict__ xb, const float* __restrict__ u,
                       const float* __restrict__ v, const float* __restrict__ ch,
                       float* __restrict__ ud, float* __restrict__ vs) {
    int idx = blockIdx.x * blockDim.x + threadIdx.x;
    if (idx >= NN * NHEAD) return;
    int n = idx >> 3, h = idx & 7;
    float su = ch[h], sv = 0.f;
    for (int i = 0; i < FIN; ++i) {
        float xv = (float)xb[(size_t)n * FIN + i];
        su += xv * u[h * FIN + i];
        sv += xv * v[h * FIN + i];
    }
    ud[idx] = su;
    vs[idx] = sv;
}

// ---------------- MFMA GEMM core (m97 structure) ----------------
// acc compute shared by both epilogue variants
#define GEMM_BODY                                                                   \
    __shared__ _Float16 As[128 * 32];                                               \
    __shared__ _Float16 Bs[128 * 32];                                               \
    const int t = threadIdx.x;                                                      \
    const int m0 = blockIdx.y * 128, n0 = blockIdx.x * 128;                         \
    const int w = t >> 6, lane = t & 63;                                            \
    const int wr = w >> 1, wc = w & 1;                                              \
    const int r_lo = lane >> 2, slot = lane & 3;                                    \
    f32x4 acc[4][4];                                                                \
    _Pragma("unroll")                                                               \
    for (int m = 0; m < 4; ++m)                                                     \
        _Pragma("unroll")                                                           \
        for (int n = 0; n < 4; ++n)                                                 \
            _Pragma("unroll")                                                       \
            for (int j = 0; j < 4; ++j) acc[m][n][j] = 0.f;                         \
    for (int k0 = 0; k0 < K; k0 += 32) {                                            \
        _Pragma("unroll")                                                           \
        for (int i = 0; i < 2; ++i) {                                               \
            int chunk = 2 * w + i;                                                  \
            int row = chunk * 16 + r_lo;                                            \
            int gr = m0 + row; gr = gr < M ? gr : M - 1;                            \
            gload16(A + (size_t)gr * K + k0 + slot * 8, &As[chunk * 512]);          \
            gload16(Bt + (size_t)(n0 + row) * K + k0 + slot * 8, &Bs[chunk * 512]); \
        }                                                                           \
        __syncthreads();                                                            \
        half8v af[4], bf[4];                                                        \
        _Pragma("unroll")                                                           \
        for (int m = 0; m < 4; ++m)                                                 \
            af[m] = *(const half8v*)(&As[(wr * 64 + m * 16 + (lane & 15)) * 32 + (lane >> 4) * 8]); \
        _Pragma("unroll")                                                           \
        for (int n = 0; n < 4; ++n)                                                 \
            bf[n] = *(const half8v*)(&Bs[(wc * 64 + n * 16 + (lane & 15)) * 32 + (lane >> 4) * 8]); \
        _Pragma("unroll")                                                           \
        for (int m = 0; m < 4; ++m)                                                 \
            _Pragma("unroll")                                                       \
            for (int n = 0; n < 4; ++n)                                             \
                acc[m][n] = __builtin_amdgcn_mfma_f32_16x16x32_f16(af[m], bf[n], acc[m][n], 0, 0, 0); \
        __syncthreads();                                                            \
    }

// plain GEMM (+bias | +=fp32 accum)
template<bool OUT_HALF, bool ACCUM>
__global__ __launch_bounds__(256) void gemm_tn(
    const _Float16* __restrict__ A, const _Float16* __restrict__ Bt,
    const float* __restrict__ bias, void* __restrict__ Cout, int ldc,
    int M, int K)
{
    GEMM_BODY
    #pragma unroll
    for (int m = 0; m < 4; ++m) {
        int r0 = m0 + wr * 64 + m * 16 + (lane >> 4) * 4;
        #pragma unroll
        for (int n = 0; n < 4; ++n) {
            int col = n0 + wc * 64 + n * 16 + (lane & 15);
            float b = 0.f;
            if (!ACCUM) b = bias[col];
            #pragma unroll
            for (int r = 0; r < 4; ++r) {
                int row = r0 + r;
                if (row < M) {
                    float v = acc[m][n][r] + b;
                    if (ACCUM) v += ((float*)Cout)[(size_t)row * ldc + col];
                    if (OUT_HALF) ((_Float16*)Cout)[(size_t)row * ldc + col] = (_Float16)v;
                    else          ((float*)Cout)[(size_t)row * ldc + col] = v;
                }
            }
        }
    }
}

// dual-output GEMM: cols < NSPLIT -> f16 out16 (+bias); cols >= NSPLIT -> f32 out32 (+bias)
__global__ __launch_bounds__(256) void gemm_dual(
    const _Float16* __restrict__ A, const _Float16* __restrict__ Bt,
    const float* __restrict__ bias, _Float16* __restrict__ out16, int ld16,
    float* __restrict__ out32, int ld32, int NSPLIT, int M, int K)
{
    GEMM_BODY
    #pragma unroll
    for (int m = 0; m < 4; ++m) {
        int r0 = m0 + wr * 64 + m * 16 + (lane >> 4) * 4;
        #pragma unroll
        for (int n = 0; n < 4; ++n) {
            int col = n0 + wc * 64 + n * 16 + (lane & 15);
            float b = bias[col];
            #pragma unroll
            for (int r = 0; r < 4; ++r) {
                int row = r0 + r;
                if (row < M) {
                    float v = acc[m][n][r] + b;
                    if (col < NSPLIT) out16[(size_t)row * ld16 + col] = (_Float16)v;
                    else              out32[(size_t)row * ld32 + (col - NSPLIT)] = v;
                }
            }
        }
    }
}

// ---------------- CSR build (by dst) ----------------
__global__ void zero_i32(int* __restrict__ p, int n) {
    int i = blockIdx.x * blockDim.x + threadIdx.x;
    if (i < n) p[i] = 0;
}
__global__ void hist_dst(const int* __restrict__ dst, int* __restrict__ deg) {
    int e = blockIdx.x * blockDim.x + threadIdx.x;
    if (e < NE) atomicAdd(&deg[dst[e]], 1);
}
__global__ void scan_deg(const int* __restrict__ deg, int* __restrict__ rowptr,
                         int* __restrict__ cursor, int n) {
    __shared__ int s[256];
    __shared__ int carry;
    int t = threadIdx.x;
    if (t == 0) carry = 0;
    __syncthreads();
    for (int base = 0; base < n; base += 256) {
        int v = (base + t < n) ? deg[base + t] : 0;
        s[t] = v;
        __syncthreads();
        for (int off = 1; off < 256; off <<= 1) {
            int x = (t >= off) ? s[t - off] : 0;
            __syncthreads();
            s[t] += x;
            __syncthreads();
        }
        int excl = carry + s[t] - v;
        if (base + t < n) { rowptr[base + t] = excl; cursor[base + t] = excl; }
        __syncthreads();
        if (t == 255) carry += s[255];
        __syncthreads();
    }
    if (t == 0) rowptr[n] = carry;
}
__global__ void scatter_edges(const int* __restrict__ dst, int* __restrict__ cursor,
                              int* __restrict__ eids) {
    int e = blockIdx.x * blockDim.x + threadIdx.x;
    if (e < NE) {
        int pos = atomicAdd(&cursor[dst[e]], 1);
        eids[pos] = e;
    }
}

// ---------------- segment softmax pieces ----------------
__global__ void init_seg(unsigned* __restrict__ amax, float* __restrict__ denom, int n) {
    int i = blockIdx.x * blockDim.x + threadIdx.x;
    if (i < n) { amax[i] = 0x007FFFFFu; denom[i] = 0.f; }
}

// conv1 low-rank edge logits (heads unrolled)
__global__ void edge_alpha_lr(const _Float16* __restrict__ T, const _Float16* __restrict__ X,
                              const float* __restrict__ ud, const float* __restrict__ vs,
                              const int* __restrict__ src, const int* __restrict__ dst,
                              float* __restrict__ alpha, unsigned* __restrict__ amaxU,
                              float scale)
{
    int gi = blockIdx.x * blockDim.x + threadIdx.x;
    int e = gi >> 6, lane = threadIdx.x & 63;
    if (e >= NE) return;
    int s = src[e], d = dst[e];
    half2v xv = *(const half2v*)(X + (size_t)s * FIN + lane * 2);
    #pragma unroll
    for (int h = 0; h < NHEAD; ++h) {
        half2v tv = *(const half2v*)(T + ((size_t)d * NHEAD + h) * FIN + lane * 2);
        float sum = (float)tv[0] * (float)xv[0] + (float)tv[1] * (float)xv[1];
        #pragma unroll
        for (int off = 32; off; off >>= 1) sum += __shfl_xor(sum, off);
        if (lane == 0) {
            float al = (sum + ud[(size_t)d * NHEAD + h] + vs[(size_t)s * NHEAD + h]) * scale;
            alpha[(size_t)e * NHEAD + h] = al;
            atomicMax(&amaxU[(size_t)d * NHEAD + h], enc_f(al));
        }
    }
}

// conv2 fused-head edge logits: all-head loads issued up front (compile-time G unroll)
template<int C, int G>
__global__ void edge_alpha_fu(const _Float16* __restrict__ Q, const _Float16* __restrict__ Kh,
                              int ldq, const int* __restrict__ src, const int* __restrict__ dst,
                              float* __restrict__ alpha, unsigned* __restrict__ amaxU,
                              float scale)
{
    constexpr int VEC = C / 64;
    using vecH = typename VecT<VEC>::T;
    int gi = blockIdx.x * blockDim.x + threadIdx.x;
    int e = gi >> 6, lane = threadIdx.x & 63;
    if (e >= NE) return;
    int s = src[e], d = dst[e];
    const _Float16* qp = Q + (size_t)d * ldq + lane * VEC;
    const _Float16* kp = Kh + (size_t)s * ldq + lane * VEC;
    vecH q[G], k[G];
    #pragma unroll
    for (int h = 0; h < G; ++h) {
        q[h] = *(const vecH*)(qp + h * C);
        k[h] = *(const vecH*)(kp + h * C);
    }
    #pragma unroll
    for (int h = 0; h < G; ++h) {
        float sum = 0.f;
        #pragma unroll
        for (int j = 0; j < VEC; ++j) sum += (float)q[h][j] * (float)k[h][j];
        #pragma unroll
        for (int off = 32; off; off >>= 1) sum += __shfl_xor(sum, off);
        if (lane == 0) {
            float al = sum * scale;
            alpha[(size_t)e * NHEAD + h] = al;
            atomicMax(&amaxU[(size_t)d * NHEAD + h], enc_f(al));
        }
    }
}

__global__ void edge_expsum(const float* __restrict__ alpha, const int* __restrict__ dst,
                            const unsigned* __restrict__ amaxU,
                            float* __restrict__ ev, float* __restrict__ denom)
{
    int i = blockIdx.x * blockDim.x + threadIdx.x;
    if (i >= NE * NHEAD) return;
    int e = i >> 3, h = i & 7;
    int d = dst[e];
    float ex = expf(alpha[i] - dec_f(amaxU[(size_t)d * NHEAD + h]));
    ev[i] = ex;
    atomicAdd(&denom[(size_t)d * NHEAD + h], ex);
}

// conv1 z-trick (unchanged)
template<int C, int G>
__global__ void zaccum(const _Float16* __restrict__ X, const float* __restrict__ ev,
                       const float* __restrict__ denom, const int* __restrict__ rowptr,
                       const int* __restrict__ eids, const int* __restrict__ src,
                       _Float16* __restrict__ Z, int hbase)
{
    constexpr int VEC = C / 64;
    using vecH = typename VecT<VEC>::T;
    int gi = blockIdx.x * blockDim.x + threadIdx.x;
    int n = gi >> 6, lane = threadIdx.x & 63;
    if (n >= NN) return;
    int beg = rowptr[n], end = rowptr[n + 1];
    float rd[G];
    #pragma unroll
    for (int h = 0; h < G; ++h)
        rd[h] = (1.0f / NHEAD) / (denom[(size_t)n * NHEAD + hbase + h] + 1e-16f);
    float acc[G][VEC];
    #pragma unroll
    for (int h = 0; h < G; ++h)
        #pragma unroll
        for (int j = 0; j < VEC; ++j) acc[h][j] = 0.f;
    for (int i = beg; i < end; ++i) {
        int e = eids[i];
        int s = src[e];
        vecH xv = *(const vecH*)(X + (size_t)s * C + lane * VEC);
        #pragma unroll
        for (int h = 0; h < G; ++h) {
            float cf = ev[(size_t)e * NHEAD + hbase + h] * rd[h];
            #pragma unroll
            for (int j = 0; j < VEC; ++j) acc[h][j] += cf * (float)xv[j];
        }
    }
    #pragma unroll
    for (int h = 0; h < G; ++h) {
        vecH o;
        #pragma unroll
        for (int j = 0; j < VEC; ++j) o[j] = (_Float16)acc[h][j];
        *(vecH*)(Z + (size_t)n * (G * C) + (size_t)h * C + lane * VEC) = o;
    }
}

// conv2 aggregation, ILP form: edges outer, heads unrolled inner (8 independent V loads)
template<int C, int G>
__global__ void node_aggr_ilp(const _Float16* __restrict__ V, int ldv,
                              const float* __restrict__ ev, const float* __restrict__ denom,
                              const int* __restrict__ rowptr, const int* __restrict__ eids,
                              const int* __restrict__ src, float* __restrict__ acc)
{
    constexpr int VEC = C / 64;
    using vecH = typename VecT<VEC>::T;
    int gi = blockIdx.x * blockDim.x + threadIdx.x;
    int n = gi >> 6, lane = threadIdx.x & 63;
    if (n >= NN) return;
    int beg = rowptr[n], end = rowptr[n + 1];
    float rd[G];
    #pragma unroll
    for (int h = 0; h < G; ++h)
        rd[h] = (1.0f / NHEAD) / (denom[(size_t)n * NHEAD + h] + 1e-16f);
    float a[VEC];
    #pragma unroll
    for (int j = 0; j < VEC; ++j) a[j] = 0.f;
    for (int i = beg; i < end; ++i) {
        int e = eids[i];
        int s = src[e];
        float cf[G];
        #pragma unroll
        for (int h = 0; h < G; ++h) cf[h] = ev[(size_t)e * NHEAD + h] * rd[h];
        vecH v[G];
        #pragma unroll
        for (int h = 0; h < G; ++h)
            v[h] = *(const vecH*)(V + (size_t)s * ldv + h * C + lane * VEC);
        #pragma unroll
        for (int h = 0; h < G; ++h)
            #pragma unroll
            for (int j = 0; j < VEC; ++j) a[j] += cf[h] * (float)v[h][j];
    }
    float* ap = acc + (size_t)n * C + lane * VEC;
    #pragma unroll
    for (int j = 0; j < VEC; ++j) ap[j] += a[j];
}

__global__ void elu_k(float* __restrict__ x, int n) {
    int i = blockIdx.x * blockDim.x + threadIdx.x;
    if (i < n) { float v = x[i]; x[i] = v > 0.f ? v : expm1f(v); }
}
__global__ void elu_cvt_bias(const float* __restrict__ in, _Float16* __restrict__ out,
                             const float* __restrict__ bvm, const int* __restrict__ deg,
                             int total) {
    int i = blockIdx.x * blockDim.x + threadIdx.x;
    if (i >= total) return;
    int c = i & (C1 - 1), n = i >> 9;
    float v = in[i] + (deg[n] > 0 ? bvm[c] : 0.f);
    v = v > 0.f ? v : expm1f(v);
    out[i] = (_Float16)v;
}

// ---------------- fused global-attention pooling + final fc ----------------
__global__ __launch_bounds__(256) void pool_fused(
    const float* __restrict__ H2, const float* __restrict__ Wg,
    const float* __restrict__ bg, const int* __restrict__ batch,
    const float* __restrict__ Wf, const float* __restrict__ bf,
    float* __restrict__ glogit, float* __restrict__ out)
{
    const int b = blockIdx.x;
    const int t = threadIdx.x, lane = t & 63, w = t >> 6;
    __shared__ int sbeg, send;
    __shared__ float sred[4];
    if (t == 0) {
        int lo = 0, hi = NN;
        while (lo < hi) { int mid = (lo + hi) >> 1; if (batch[mid] < b) lo = mid + 1; else hi = mid; }
        sbeg = lo;
        hi = NN;
        while (lo < hi) { int mid = (lo + hi) >> 1; if (batch[mid] < b + 1) lo = mid + 1; else hi = mid; }
        send = lo;
    }
    __syncthreads();
    const int beg = sbeg, end = send;
    const float bg0 = bg[0];

    float lmax = -INFINITY;
    for (int n = beg + w; n < end; n += 4) {
        float4 h = ((const float4*)(H2 + (size_t)n * C2))[lane];
        float4 wv = ((const float4*)Wg)[lane];
        float sum = h.x * wv.x + h.y * wv.y + h.z * wv.z + h.w * wv.w;
        #pragma unroll
        for (int off = 32; off; off >>= 1) sum += __shfl_xor(sum, off);
        sum += bg0;
        if (lane == 0) glogit[n] = sum;
        lmax = fmaxf(lmax, sum);
    }
    if (lane == 0) sred[w] = lmax;
    __syncthreads();
    float m = fmaxf(fmaxf(sred[0], sred[1]), fmaxf(sred[2], sred[3]));
    if (!isfinite(m)) m = 0.f;
    __syncthreads();

    float ls = 0.f;
    for (int n = beg + t; n < end; n += 256) {
        float e = expf(glogit[n] - m);
        glogit[n] = e;
        ls += e;
    }
    #pragma unroll
    for (int off = 32; off; off >>= 1) ls += __shfl_xor(ls, off);
    if (lane == 0) sred[w] = ls;
    __syncthreads();
    const float denom = sred[0] + sred[1] + sred[2] + sred[3] + 1e-16f;
    __syncthreads();

    float acc = 0.f;
    for (int n = beg; n < end; ++n)
        acc += glogit[n] * H2[(size_t)n * C2 + t];
    const float gc = acc / denom;

    for (int o = 0; o < NOUT; ++o) {
        float p = gc * Wf[t * NOUT + o];
        #pragma unroll
        for (int off = 32; off; off >>= 1) p += __shfl_xor(p, off);
        __syncthreads();
        if (lane == 0) sred[w] = p;
        __syncthreads();
        if (t == 0) out[b * NOUT + o] = sred[0] + sred[1] + sred[2] + sred[3] + bf[o];
    }
}

extern "C" void kernel_launch(void* const* d_in, const int* in_sizes, int n_in,
                              void* d_out, int out_size, void* d_ws, size_t ws_size,
                              hipStream_t stream) {
    (void)in_sizes; (void)n_in; (void)out_size; (void)ws_size;
    const float* x     = (const float*)d_in[0];
    const int*   ei    = (const int*)  d_in[1];
    const int*   batch = (const int*)  d_in[2];
    const float* Wq1 = (const float*)d_in[3];  const float* bq1 = (const float*)d_in[4];
    const float* Wk1 = (const float*)d_in[5];  const float* bk1 = (const float*)d_in[6];
    const float* Wv1 = (const float*)d_in[7];  const float* bv1 = (const float*)d_in[8];
    const float* Ws1 = (const float*)d_in[9];  const float* bs1 = (const float*)d_in[10];
    const float* Wq2 = (const float*)d_in[11]; const float* bq2 = (const float*)d_in[12];
    const float* Wk2 = (const float*)d_in[13]; const float* bk2 = (const float*)d_in[14];
    const float* Wv2 = (const float*)d_in[15]; const float* bv2 = (const float*)d_in[16];
    const float* Ws2 = (const float*)d_in[17]; const float* bs2 = (const float*)d_in[18];
    const float* Wg  = (const float*)d_in[19]; const float* bg  = (const float*)d_in[20];
    const float* Wf  = (const float*)d_in[21]; const float* bf  = (const float*)d_in[22];

    const int* src = ei;
    const int* dst = ei + NE;

    char* base = (char*)d_ws;
    size_t off = 0;
    auto alloc = [&](size_t bytes) -> char* {
        char* p = base + off;
        off = (off + bytes + 255) & ~(size_t)255;
        return p;
    };
    _Float16* xb    = (_Float16*)alloc((size_t)NN * FIN * 2);
    _Float16* wtq1  = (_Float16*)alloc((size_t)NHEAD * C1 * FIN * 2);
    _Float16* wtk1  = (_Float16*)alloc((size_t)NHEAD * C1 * FIN * 2);
    _Float16* bvs1  = (_Float16*)alloc((size_t)C1 * NHEAD * FIN * 2);
    _Float16* wcat1 = (_Float16*)alloc((size_t)(NHEAD * FIN + C1) * FIN * 2);   // [1536,128] = Mst | wts1
    _Float16* wcat2 = (_Float16*)alloc((size_t)(3 * NHEAD * C2 + C2) * C1 * 2); // [6400,512] = Wq|Wk|Wv|Ws
    float* uvecs = (float*)alloc((size_t)NHEAD * FIN * 4);
    float* vvecs = (float*)alloc((size_t)NHEAD * FIN * 4);
    float* chd   = (float*)alloc((size_t)NHEAD * 4);
    float* ud    = (float*)alloc((size_t)NN * NHEAD * 4);
    float* vs    = (float*)alloc((size_t)NN * NHEAD * 4);
    float* bcat1 = (float*)alloc((size_t)(NHEAD * FIN + C1) * 4);               // [1536]
    float* bcat2 = (float*)alloc((size_t)(3 * NHEAD * C2 + C2) * 4);            // [6400]
    float* acc1  = (float*)alloc((size_t)NN * C1 * 4);
    _Float16* h1b = (_Float16*)alloc((size_t)NN * C1 * 2);
    float* alpha = (float*)alloc((size_t)NE * NHEAD * 4);
    float* ev    = (float*)alloc((size_t)NE * NHEAD * 4);
    unsigned* amaxU = (unsigned*)alloc((size_t)NN * NHEAD * 4);
    float* denom = (float*)alloc((size_t)NN * NHEAD * 4);
    int* deg    = (int*)alloc((size_t)NN * 4);
    int* rowptr = (int*)alloc((size_t)(NN + 1) * 4);
    int* cursor = (int*)alloc((size_t)NN * 4);
    int* eids   = (int*)alloc((size_t)NE * 4);
    float* bvm1 = (float*)alloc((size_t)C1 * 4);
    _Float16* Tbuf   = (_Float16*)alloc((size_t)NN * NHEAD * FIN * 2);          // 20.5MB
    _Float16* QKVbuf = (_Float16*)alloc((size_t)NN * 3 * NHEAD * C2 * 2);       // 123MB
    _Float16* Zbuf = QKVbuf;     // conv1 z-phase alias
    float* acc2 = acc1;          // conv1 fp32 accum dead once h1b built
    const int LDQKV = 3 * NHEAD * C2;   // 6144

    _Float16* Mst  = wcat1;                                   // first 1024 rows of wcat1
    _Float16* wts1 = wcat1 + (size_t)NHEAD * FIN * FIN;       // last 512 rows
    _Float16* wq2t = wcat2;
    _Float16* wk2t = wcat2 + (size_t)NHEAD * C2 * C1;
    _Float16* wv2t = wcat2 + (size_t)2 * NHEAD * C2 * C1;
    _Float16* ws2t = wcat2 + (size_t)3 * NHEAD * C2 * C1;

    const dim3 blk(256);
    const float sc1 = 1.0f / sqrtf((float)C1);
    const float sc2 = 1.0f / sqrtf((float)C2);
    const int edge_blocks = (NE * 64) / 256;
    const int node_blocks = (NN * 64) / 256;
    const int gy = (NN + 127) / 128;

    // ---- conversions + precompute ----
    cvt_f16<<<((size_t)NN * FIN + 255) / 256, blk, 0, stream>>>(x, xb, NN * FIN);
    {
        dim3 tb(32, 8);
        transpose_cvt<<<dim3(NHEAD * C1 / 32, FIN / 32), tb, 0, stream>>>(Wq1, wtq1, FIN, NHEAD * C1);
        transpose_cvt<<<dim3(NHEAD * C1 / 32, FIN / 32), tb, 0, stream>>>(Wk1, wtk1, FIN, NHEAD * C1);
        transpose_stack<<<dim3(C1 / 32, FIN / 32, NHEAD), tb, 0, stream>>>(Wv1, bvs1, FIN, C1);
        transpose_cvt<<<dim3(C1 / 32, FIN / 32),         tb, 0, stream>>>(Ws1, wts1, FIN, C1);
        transpose_cvt<<<dim3(NHEAD * C2 / 32, C1 / 32),  tb, 0, stream>>>(Wq2, wq2t, C1, NHEAD * C2);
        transpose_cvt<<<dim3(NHEAD * C2 / 32, C1 / 32),  tb, 0, stream>>>(Wk2, wk2t, C1, NHEAD * C2);
        transpose_cvt<<<dim3(NHEAD * C2 / 32, C1 / 32),  tb, 0, stream>>>(Wv2, wv2t, C1, NHEAD * C2);
        transpose_cvt<<<dim3(C2 / 32, C1 / 32),          tb, 0, stream>>>(Ws2, ws2t, C1, C2);
    }
    bvmean_k<<<(C1 + 255) / 256, blk, 0, stream>>>(bv1, bvm1, C1);
    mstack_k<<<dim3(FIN / 16, FIN / 16, NHEAD), dim3(16, 16), 0, stream>>>(wtq1, wtk1, Mst);
    uvprep<<<NHEAD, FIN, 0, stream>>>(Wq1, Wk1, bq1, bk1, uvecs, vvecs, chd);
    udvs_k<<<(NN * NHEAD + 255) / 256, blk, 0, stream>>>(xb, uvecs, vvecs, chd, ud, vs);
    bcat1_k<<<(NHEAD * FIN + C1 + 255) / 256, blk, 0, stream>>>(bs1, bcat1);
    bcat2_k<<<(3 * NHEAD * C2 + C2 + 255) / 256, blk, 0, stream>>>(bq2, bk2, bv2, bs2, bcat2);

    // ---- CSR by dst ----
    zero_i32<<<(NN + 255) / 256, blk, 0, stream>>>(deg, NN);
    hist_dst<<<(NE + 255) / 256, blk, 0, stream>>>(dst, deg);
    scan_deg<<<1, blk, 0, stream>>>(deg, rowptr, cursor, NN);
    scatter_edges<<<(NE + 255) / 256, blk, 0, stream>>>(dst, cursor, eids);

    // ================ conv1: [T | skip] dual GEMM, low-rank QK, z-trick ================
    gemm_dual<<<dim3((NHEAD * FIN + C1) / 128, gy), blk, 0, stream>>>(
        xb, wcat1, bcat1, Tbuf, NHEAD * FIN, acc1, C1, NHEAD * FIN, NN, FIN);
    init_seg<<<(NN * NHEAD + 255) / 256, blk, 0, stream>>>(amaxU, denom, NN * NHEAD);
    edge_alpha_lr<<<edge_blocks, blk, 0, stream>>>(Tbuf, xb, ud, vs, src, dst,
                                                   alpha, amaxU, sc1);
    edge_expsum<<<(NE * NHEAD + 255) / 256, blk, 0, stream>>>(alpha, dst, amaxU, ev, denom);
    zaccum<FIN, NHEAD><<<node_blocks, blk, 0, stream>>>(xb, ev, denom, rowptr, eids, src,
                                                        Zbuf, 0);
    gemm_tn<false, true><<<dim3(C1 / 128, gy), blk, 0, stream>>>(
        Zbuf, bvs1, nullptr, acc1, C1, NN, NHEAD * FIN);                    // acc1 += Z @ Wv
    elu_cvt_bias<<<((size_t)NN * C1 + 255) / 256, blk, 0, stream>>>(
        acc1, h1b, bvm1, deg, NN * C1);

    // ================ conv2: [QKV | skip] dual GEMM, fused edge/aggr ================
    init_seg<<<(NN * NHEAD + 255) / 256, blk, 0, stream>>>(amaxU, denom, NN * NHEAD);
    gemm_dual<<<dim3((LDQKV + C2) / 128, gy), blk, 0, stream>>>(
        h1b, wcat2, bcat2, QKVbuf, LDQKV, acc2, C2, LDQKV, NN, C1);
    edge_alpha_fu<C2, NHEAD><<<edge_blocks, blk, 0, stream>>>(
        QKVbuf, QKVbuf + NHEAD * C2, LDQKV, src, dst, alpha, amaxU, sc2);
    edge_expsum<<<(NE * NHEAD + 255) / 256, blk, 0, stream>>>(alpha, dst, amaxU, ev, denom);
    node_aggr_ilp<C2, NHEAD><<<node_blocks, blk, 0, stream>>>(
        QKVbuf + 2 * NHEAD * C2, LDQKV, ev, denom, rowptr, eids, src, acc2);
    elu_k<<<((size_t)NN * C2 + 255) / 256, blk, 0, stream>>>(acc2, NN * C2);

    // ================ fused pooling + fc ================
    pool_fused<<<NB, blk, 0, stream>>>(acc2, Wg, bg, batch, Wf, bf, alpha, (float*)d_out);
}

// Round 12
// 609.331 us; speedup vs baseline: 2.0263x; 1.0136x over previous
//
#include <hip/hip_runtime.h>
#include <math.h>

#define NN 10000
#define NE 20000
#define FIN 128
#define NHEAD 8
#define C1 512
#define C2 256
#define NB 64
#define NOUT 10

typedef _Float16 half8v __attribute__((ext_vector_type(8)));
typedef _Float16 half4v __attribute__((ext_vector_type(4)));
typedef _Float16 half2v __attribute__((ext_vector_type(2)));
typedef float f32x4 __attribute__((ext_vector_type(4)));

template<int VEC> struct VecT;
template<> struct VecT<2> { using T = half2v; };
template<> struct VecT<4> { using T = half4v; };
template<> struct VecT<8> { using T = half8v; };

__device__ __forceinline__ unsigned enc_f(float f) {
    unsigned u = __float_as_uint(f);
    return (u & 0x80000000u) ? ~u : (u | 0x80000000u);
}
__device__ __forceinline__ float dec_f(unsigned e) {
    return (e & 0x80000000u) ? __uint_as_float(e & 0x7fffffffu) : __uint_as_float(~e);
}

__device__ __forceinline__ void gload16(const _Float16* g, _Float16* l) {
    __builtin_amdgcn_global_load_lds(
        (const __attribute__((address_space(1))) unsigned int*)(const void*)g,
        (__attribute__((address_space(3))) unsigned int*)(void*)l, 16, 0, 0);
}

// XCD-affine swizzle: bijective mod-8 chunk remap (m204) + stripe traversal.
// SW must divide gx. Each XCD gets a contiguous wgid run => contiguous stripe region.
__device__ __forceinline__ void swz_map(int nwg, int gx, int SW, int& bx, int& by) {
    int orig = blockIdx.x;
    int q = nwg >> 3, r = nwg & 7;
    int xcd = orig & 7, lid = orig >> 3;
    int wgid = (xcd < r ? xcd * (q + 1) : r * (q + 1) + (xcd - r) * q) + lid;
    int gy = nwg / gx;
    int sh = SW * gy;
    int stripe = wgid / sh;
    int rem = wgid - stripe * sh;
    int byq = rem / SW;
    by = byq;
    bx = stripe * SW + (rem - byq * SW);
}

// ---------------- conversion / transpose ----------------
__global__ void cvt_f16(const float* __restrict__ in, _Float16* __restrict__ out, int n) {
    int i = blockIdx.x * blockDim.x + threadIdx.x;
    if (i < n) out[i] = (_Float16)in[i];
}

__global__ void transpose_cvt(const float* __restrict__ W, _Float16* __restrict__ Wt,
                              int K, int N) {
    __shared__ float tile[32][33];
    int n0 = blockIdx.x * 32, k0 = blockIdx.y * 32;
    int tx = threadIdx.x, ty = threadIdx.y;
    for (int j = ty; j < 32; j += 8) tile[j][tx] = W[(size_t)(k0 + j) * N + n0 + tx];
    __syncthreads();
    for (int j = ty; j < 32; j += 8)
        Wt[(size_t)(n0 + j) * K + k0 + tx] = (_Float16)tile[tx][j];
}

__global__ void transpose_stack(const float* __restrict__ Wv, _Float16* __restrict__ Bt,
                                int Cin, int Cout) {
    __shared__ float tile[32][33];
    int h = blockIdx.z;
    int c0 = blockIdx.x * 32, k0 = blockIdx.y * 32;
    int tx = threadIdx.x, ty = threadIdx.y;
    for (int j = ty; j < 32; j += 8)
        tile[j][tx] = Wv[(size_t)(k0 + j) * (NHEAD * Cout) + (size_t)h * Cout + c0 + tx];
    __syncthreads();
    for (int j = ty; j < 32; j += 8)
        Bt[(size_t)(c0 + j) * (NHEAD * Cin) + (size_t)h * Cin + k0 + tx] = (_Float16)tile[tx][j];
}

__global__ void bvmean_k(const float* __restrict__ bv, float* __restrict__ bvm, int C) {
    int c = blockIdx.x * blockDim.x + threadIdx.x;
    if (c >= C) return;
    float s = 0.f;
    #pragma unroll
    for (int h = 0; h < NHEAD; ++h) s += bv[h * C + c];
    bvm[c] = s * (1.0f / NHEAD);
}

__global__ void bcat2_k(const float* __restrict__ bq2, const float* __restrict__ bk2,
                        const float* __restrict__ bv2, const float* __restrict__ bs2,
                        float* __restrict__ o) {
    int i = blockIdx.x * blockDim.x + threadIdx.x;
    const int n = NHEAD * C2;
    if (i < n) o[i] = bq2[i];
    else if (i < 2 * n) o[i] = bk2[i - n];
    else if (i < 3 * n) o[i] = bv2[i - 2 * n];
    else if (i < 3 * n + C2) o[i] = bs2[i - 3 * n];
}

// ---------------- conv1 low-rank QK precompute ----------------
__global__ void mstack_k(const _Float16* __restrict__ wtq1, const _Float16* __restrict__ wtk1,
                         _Float16* __restrict__ Mst) {
    int h = blockIdx.z;
    int i = blockIdx.x * 16 + threadIdx.x;
    int j = blockIdx.y * 16 + threadIdx.y;
    float acc = 0.f;
    for (int c = 0; c < C1; ++c)
        acc += (float)wtq1[((size_t)h * C1 + c) * FIN + i] *
               (float)wtk1[((size_t)h * C1 + c) * FIN + j];
    Mst[((size_t)h * FIN + j) * FIN + i] = (_Float16)acc;
}

__global__ void uvprep(const float* __restrict__ Wq1, const float* __restrict__ Wk1,
                       const float* __restrict__ bq1, const float* __restrict__ bk1,
                       float* __restrict__ u, float* __restrict__ v, float* __restrict__ ch) {
    int h = blockIdx.x, i = threadIdx.x;  // block 128
    float su = 0.f, sv = 0.f;
    for (int c = 0; c < C1; ++c) {
        su += Wq1[(size_t)i * (NHEAD * C1) + h * C1 + c] * bk1[h * C1 + c];
        sv += Wk1[(size_t)i * (NHEAD * C1) + h * C1 + c] * bq1[h * C1 + c];
    }
    u[h * FIN + i] = su;
    v[h * FIN + i] = sv;
    if (i == 0) {
        float s = 0.f;
        for (int c = 0; c < C1; ++c) s += bq1[h * C1 + c] * bk1[h * C1 + c];
        ch[h] = s;
    }
}

__global__ void udvs_k(const _Float16* __restrict__ xb, const float* __restrict__ u,
                       const float* __restrict__ v, const float* __restrict__ ch,
                       float* __restrict__ ud, float* __restrict__ vs) {
    int idx = blockIdx.x * blockDim.x + threadIdx.x;
    if (idx >= NN * NHEAD) return;
    int n = idx >> 3, h = idx & 7;
    float su = ch[h], sv = 0.f;
    for (int i = 0; i < FIN; ++i) {
        float xv = (float)xb[(size_t)n * FIN + i];
        su += xv * u[h * FIN + i];
        sv += xv * v[h * FIN + i];
    }
    ud[idx] = su;
    vs[idx] = sv;
}

// ---------------- MFMA GEMM core (m97 structure, XCD-swizzled 1D grid) ----------------
#define GEMM_CORE                                                                   \
    __shared__ _Float16 As[128 * 32];                                               \
    __shared__ _Float16 Bs[128 * 32];                                               \
    const int t = threadIdx.x;                                                      \
    const int w = t >> 6, lane = t & 63;                                            \
    const int wr = w >> 1, wc = w & 1;                                              \
    const int r_lo = lane >> 2, slot = lane & 3;                                    \
    f32x4 acc[4][4];                                                                \
    _Pragma("unroll")                                                               \
    for (int m = 0; m < 4; ++m)                                                     \
        _Pragma("unroll")                                                           \
        for (int n = 0; n < 4; ++n)                                                 \
            _Pragma("unroll")                                                       \
            for (int j = 0; j < 4; ++j) acc[m][n][j] = 0.f;

#define GEMM_STEP(APTR, ALD, AKO, BPTR, BLD, BKO)                                   \
    {                                                                               \
        _Pragma("unroll")                                                           \
        for (int i = 0; i < 2; ++i) {                                               \
            int chunk = 2 * w + i;                                                  \
            int row = chunk * 16 + r_lo;                                            \
            int gr = m0 + row; gr = gr < M ? gr : M - 1;                            \
            gload16(APTR + (size_t)gr * ALD + AKO + slot * 8, &As[chunk * 512]);    \
            gload16(BPTR + (size_t)(n0 + row) * BLD + BKO + slot * 8, &Bs[chunk * 512]); \
        }                                                                           \
        __syncthreads();                                                            \
        half8v af[4], bf[4];                                                        \
        _Pragma("unroll")                                                           \
        for (int m = 0; m < 4; ++m)                                                 \
            af[m] = *(const half8v*)(&As[(wr * 64 + m * 16 + (lane & 15)) * 32 + (lane >> 4) * 8]); \
        _Pragma("unroll")                                                           \
        for (int n = 0; n < 4; ++n)                                                 \
            bf[n] = *(const half8v*)(&Bs[(wc * 64 + n * 16 + (lane & 15)) * 32 + (lane >> 4) * 8]); \
        _Pragma("unroll")                                                           \
        for (int m = 0; m < 4; ++m)                                                 \
            _Pragma("unroll")                                                       \
            for (int n = 0; n < 4; ++n)                                             \
                acc[m][n] = __builtin_amdgcn_mfma_f32_16x16x32_f16(af[m], bf[n], acc[m][n], 0, 0, 0); \
        __syncthreads();                                                            \
    }

// plain GEMM, f16 out (+bias)
__global__ __launch_bounds__(256) void gemm_f16(
    const _Float16* __restrict__ A, const _Float16* __restrict__ Bt,
    const float* __restrict__ bias, _Float16* __restrict__ Cout, int ldc,
    int M, int K, int nwg, int gx, int SW)
{
    int bx, by; swz_map(nwg, gx, SW, bx, by);
    const int m0 = by * 128, n0 = bx * 128;
    GEMM_CORE
    for (int k0 = 0; k0 < K; k0 += 32) GEMM_STEP(A, K, k0, Bt, K, k0)
    #pragma unroll
    for (int m = 0; m < 4; ++m) {
        int r0 = m0 + wr * 64 + m * 16 + (lane >> 4) * 4;
        #pragma unroll
        for (int n = 0; n < 4; ++n) {
            int col = n0 + wc * 64 + n * 16 + (lane & 15);
            float b = bias[col];
            #pragma unroll
            for (int r = 0; r < 4; ++r) {
                int row = r0 + r;
                if (row < M) Cout[(size_t)row * ldc + col] = (_Float16)(acc[m][n][r] + b);
            }
        }
    }
}

// dual-output GEMM: cols < NSPLIT -> f16 (+bias); cols >= NSPLIT -> f32 (+bias)
__global__ __launch_bounds__(256) void gemm_dual(
    const _Float16* __restrict__ A, const _Float16* __restrict__ Bt,
    const float* __restrict__ bias, _Float16* __restrict__ out16, int ld16,
    float* __restrict__ out32, int ld32, int NSPLIT, int M, int K,
    int nwg, int gx, int SW)
{
    int bx, by; swz_map(nwg, gx, SW, bx, by);
    const int m0 = by * 128, n0 = bx * 128;
    GEMM_CORE
    for (int k0 = 0; k0 < K; k0 += 32) GEMM_STEP(A, K, k0, Bt, K, k0)
    #pragma unroll
    for (int m = 0; m < 4; ++m) {
        int r0 = m0 + wr * 64 + m * 16 + (lane >> 4) * 4;
        #pragma unroll
        for (int n = 0; n < 4; ++n) {
            int col = n0 + wc * 64 + n * 16 + (lane & 15);
            float b = bias[col];
            #pragma unroll
            for (int r = 0; r < 4; ++r) {
                int row = r0 + r;
                if (row < M) {
                    float v = acc[m][n][r] + b;
                    if (col < NSPLIT) out16[(size_t)row * ld16 + col] = (_Float16)v;
                    else              out32[(size_t)row * ld32 + (col - NSPLIT)] = v;
                }
            }
        }
    }
}

// K-concat GEMM with fused conv1 epilogue:
// h1b = ELU( [A1|A2] @ [B1|B2]^T + bs1 + (deg>0 ? bvm1 : 0) )   (f16 out)
__global__ __launch_bounds__(256) void gemm_cat2_elu(
    const _Float16* __restrict__ A1, int K1,            // Zbuf [M, 1024]
    const _Float16* __restrict__ A2, int K2,            // xb   [M, 128]
    const _Float16* __restrict__ B1,                    // bvs1 [512, 1024]
    const _Float16* __restrict__ B2,                    // wts1 [512, 128]
    const float* __restrict__ bs1, const float* __restrict__ bvm1,
    const int* __restrict__ deg, _Float16* __restrict__ h1b,
    int M, int nwg, int gx, int SW)
{
    int bx, by; swz_map(nwg, gx, SW, bx, by);
    const int m0 = by * 128, n0 = bx * 128;
    const int K = K1 + K2;
    GEMM_CORE
    for (int k0 = 0; k0 < K; k0 += 32) {
        if (k0 < K1) GEMM_STEP(A1, K1, k0, B1, K1, k0)
        else         GEMM_STEP(A2, K2, (k0 - K1), B2, K2, (k0 - K1))
    }
    #pragma unroll
    for (int m = 0; m < 4; ++m) {
        int r0 = m0 + wr * 64 + m * 16 + (lane >> 4) * 4;
        #pragma unroll
        for (int n = 0; n < 4; ++n) {
            int col = n0 + wc * 64 + n * 16 + (lane & 15);
            float b = bs1[col], bm = bvm1[col];
            #pragma unroll
            for (int r = 0; r < 4; ++r) {
                int row = r0 + r;
                if (row < M) {
                    float v = acc[m][n][r] + b + (deg[row] > 0 ? bm : 0.f);
                    v = v > 0.f ? v : expm1f(v);
                    h1b[(size_t)row * C1 + col] = (_Float16)v;
                }
            }
        }
    }
}

// ---------------- CSR build (by dst) ----------------
__global__ void zero_i32(int* __restrict__ p, int n) {
    int i = blockIdx.x * blockDim.x + threadIdx.x;
    if (i < n) p[i] = 0;
}
__global__ void hist_dst(const int* __restrict__ dst, int* __restrict__ deg) {
    int e = blockIdx.x * blockDim.x + threadIdx.x;
    if (e < NE) atomicAdd(&deg[dst[e]], 1);
}
__global__ void scan_deg(const int* __restrict__ deg, int* __restrict__ rowptr,
                         int* __restrict__ cursor, int n) {
    __shared__ int s[256];
    __shared__ int carry;
    int t = threadIdx.x;
    if (t == 0) carry = 0;
    __syncthreads();
    for (int base = 0; base < n; base += 256) {
        int v = (base + t < n) ? deg[base + t] : 0;
        s[t] = v;
        __syncthreads();
        for (int off = 1; off < 256; off <<= 1) {
            int x = (t >= off) ? s[t - off] : 0;
            __syncthreads();
            s[t] += x;
            __syncthreads();
        }
        int excl = carry + s[t] - v;
        if (base + t < n) { rowptr[base + t] = excl; cursor[base + t] = excl; }
        __syncthreads();
        if (t == 255) carry += s[255];
        __syncthreads();
    }
    if (t == 0) rowptr[n] = carry;
}
__global__ void scatter_edges(const int* __restrict__ dst, int* __restrict__ cursor,
                              int* __restrict__ eids) {
    int e = blockIdx.x * blockDim.x + threadIdx.x;
    if (e < NE) {
        int pos = atomicAdd(&cursor[dst[e]], 1);
        eids[pos] = e;
    }
}

// ---------------- segment softmax pieces ----------------
__global__ void init_seg(unsigned* __restrict__ amax, float* __restrict__ denom, int n) {
    int i = blockIdx.x * blockDim.x + threadIdx.x;
    if (i < n) { amax[i] = 0x007FFFFFu; denom[i] = 0.f; }
}

__global__ void edge_alpha_lr(const _Float16* __restrict__ T, const _Float16* __restrict__ X,
                              const float* __restrict__ ud, const float* __restrict__ vs,
                              const int* __restrict__ src, const int* __restrict__ dst,
                              float* __restrict__ alpha, unsigned* __restrict__ amaxU,
                              float scale)
{
    int gi = blockIdx.x * blockDim.x + threadIdx.x;
    int e = gi >> 6, lane = threadIdx.x & 63;
    if (e >= NE) return;
    int s = src[e], d = dst[e];
    half2v xv = *(const half2v*)(X + (size_t)s * FIN + lane * 2);
    #pragma unroll
    for (int h = 0; h < NHEAD; ++h) {
        half2v tv = *(const half2v*)(T + ((size_t)d * NHEAD + h) * FIN + lane * 2);
        float sum = (float)tv[0] * (float)xv[0] + (float)tv[1] * (float)xv[1];
        #pragma unroll
        for (int off = 32; off; off >>= 1) sum += __shfl_xor(sum, off);
        if (lane == 0) {
            float al = (sum + ud[(size_t)d * NHEAD + h] + vs[(size_t)s * NHEAD + h]) * scale;
            alpha[(size_t)e * NHEAD + h] = al;
            atomicMax(&amaxU[(size_t)d * NHEAD + h], enc_f(al));
        }
    }
}

template<int C, int G>
__global__ void edge_alpha_fu(const _Float16* __restrict__ Q, const _Float16* __restrict__ Kh,
                              int ldq, const int* __restrict__ src, const int* __restrict__ dst,
                              float* __restrict__ alpha, unsigned* __restrict__ amaxU,
                              float scale)
{
    constexpr int VEC = C / 64;
    using vecH = typename VecT<VEC>::T;
    int gi = blockIdx.x * blockDim.x + threadIdx.x;
    int e = gi >> 6, lane = threadIdx.x & 63;
    if (e >= NE) return;
    int s = src[e], d = dst[e];
    const _Float16* qp = Q + (size_t)d * ldq + lane * VEC;
    const _Float16* kp = Kh + (size_t)s * ldq + lane * VEC;
    vecH q[G], k[G];
    #pragma unroll
    for (int h = 0; h < G; ++h) {
        q[h] = *(const vecH*)(qp + h * C);
        k[h] = *(const vecH*)(kp + h * C);
    }
    #pragma unroll
    for (int h = 0; h < G; ++h) {
        float sum = 0.f;
        #pragma unroll
        for (int j = 0; j < VEC; ++j) sum += (float)q[h][j] * (float)k[h][j];
        #pragma unroll
        for (int off = 32; off; off >>= 1) sum += __shfl_xor(sum, off);
        if (lane == 0) {
            float al = sum * scale;
            alpha[(size_t)e * NHEAD + h] = al;
            atomicMax(&amaxU[(size_t)d * NHEAD + h], enc_f(al));
        }
    }
}

__global__ void edge_expsum(const float* __restrict__ alpha, const int* __restrict__ dst,
                            const unsigned* __restrict__ amaxU,
                            float* __restrict__ ev, float* __restrict__ denom)
{
    int i = blockIdx.x * blockDim.x + threadIdx.x;
    if (i >= NE * NHEAD) return;
    int e = i >> 3, h = i & 7;
    int d = dst[e];
    float ex = expf(alpha[i] - dec_f(amaxU[(size_t)d * NHEAD + h]));
    ev[i] = ex;
    atomicAdd(&denom[(size_t)d * NHEAD + h], ex);
}

template<int C, int G>
__global__ void zaccum(const _Float16* __restrict__ X, const float* __restrict__ ev,
                       const float* __restrict__ denom, const int* __restrict__ rowptr,
                       const int* __restrict__ eids, const int* __restrict__ src,
                       _Float16* __restrict__ Z, int hbase)
{
    constexpr int VEC = C / 64;
    using vecH = typename VecT<VEC>::T;
    int gi = blockIdx.x * blockDim.x + threadIdx.x;
    int n = gi >> 6, lane = threadIdx.x & 63;
    if (n >= NN) return;
    int beg = rowptr[n], end = rowptr[n + 1];
    float rd[G];
    #pragma unroll
    for (int h = 0; h < G; ++h)
        rd[h] = (1.0f / NHEAD) / (denom[(size_t)n * NHEAD + hbase + h] + 1e-16f);
    float acc[G][VEC];
    #pragma unroll
    for (int h = 0; h < G; ++h)
        #pragma unroll
        for (int j = 0; j < VEC; ++j) acc[h][j] = 0.f;
    for (int i = beg; i < end; ++i) {
        int e = eids[i];
        int s = src[e];
        vecH xv = *(const vecH*)(X + (size_t)s * C + lane * VEC);
        #pragma unroll
        for (int h = 0; h < G; ++h) {
            float cf = ev[(size_t)e * NHEAD + hbase + h] * rd[h];
            #pragma unroll
            for (int j = 0; j < VEC; ++j) acc[h][j] += cf * (float)xv[j];
        }
    }
    #pragma unroll
    for (int h = 0; h < G; ++h) {
        vecH o;
        #pragma unroll
        for (int j = 0; j < VEC; ++j) o[j] = (_Float16)acc[h][j];
        *(vecH*)(Z + (size_t)n * (G * C) + (size_t)h * C + lane * VEC) = o;
    }
}

template<int C, int G>
__global__ void node_aggr_ilp(const _Float16* __restrict__ V, int ldv,
                              const float* __restrict__ ev, const float* __restrict__ denom,
                              const int* __restrict__ rowptr, const int* __restrict__ eids,
                              const int* __restrict__ src, float* __restrict__ acc)
{
    constexpr int VEC = C / 64;
    using vecH = typename VecT<VEC>::T;
    int gi = blockIdx.x * blockDim.x + threadIdx.x;
    int n = gi >> 6, lane = threadIdx.x & 63;
    if (n >= NN) return;
    int beg = rowptr[n], end = rowptr[n + 1];
    float rd[G];
    #pragma unroll
    for (int h = 0; h < G; ++h)
        rd[h] = (1.0f / NHEAD) / (denom[(size_t)n * NHEAD + h] + 1e-16f);
    float a[VEC];
    #pragma unroll
    for (int j = 0; j < VEC; ++j) a[j] = 0.f;
    for (int i = beg; i < end; ++i) {
        int e = eids[i];
        int s = src[e];
        float cf[G];
        #pragma unroll
        for (int h = 0; h < G; ++h) cf[h] = ev[(size_t)e * NHEAD + h] * rd[h];
        vecH v[G];
        #pragma unroll
        for (int h = 0; h < G; ++h)
            v[h] = *(const vecH*)(V + (size_t)s * ldv + h * C + lane * VEC);
        #pragma unroll
        for (int h = 0; h < G; ++h)
            #pragma unroll
            for (int j = 0; j < VEC; ++j) a[j] += cf[h] * (float)v[h][j];
    }
    float* ap = acc + (size_t)n * C + lane * VEC;
    #pragma unroll
    for (int j = 0; j < VEC; ++j) ap[j] += a[j];
}

__global__ void elu_k(float* __restrict__ x, int n) {
    int i = blockIdx.x * blockDim.x + threadIdx.x;
    if (i < n) { float v = x[i]; x[i] = v > 0.f ? v : expm1f(v); }
}

// ---------------- fused global-attention pooling + final fc ----------------
__global__ __launch_bounds__(256) void pool_fused(
    const float* __restrict__ H2, const float* __restrict__ Wg,
    const float* __restrict__ bg, const int* __restrict__ batch,
    const float* __restrict__ Wf, const float* __restrict__ bf,
    float* __restrict__ glogit, float* __restrict__ out)
{
    const int b = blockIdx.x;
    const int t = threadIdx.x, lane = t & 63, w = t >> 6;
    __shared__ int sbeg, send;
    __shared__ float sred[4];
    if (t == 0) {
        int lo = 0, hi = NN;
        while (lo < hi) { int mid = (lo + hi) >> 1; if (batch[mid] < b) lo = mid + 1; else hi = mid; }
        sbeg = lo;
        hi = NN;
        while (lo < hi) { int mid = (lo + hi) >> 1; if (batch[mid] < b + 1) lo = mid + 1; else hi = mid; }
        send = lo;
    }
    __syncthreads();
    const int beg = sbeg, end = send;
    const float bg0 = bg[0];

    float lmax = -INFINITY;
    for (int n = beg + w; n < end; n += 4) {
        float4 h = ((const float4*)(H2 + (size_t)n * C2))[lane];
        float4 wv = ((const float4*)Wg)[lane];
        float sum = h.x * wv.x + h.y * wv.y + h.z * wv.z + h.w * wv.w;
        #pragma unroll
        for (int off = 32; off; off >>= 1) sum += __shfl_xor(sum, off);
        sum += bg0;
        if (lane == 0) glogit[n] = sum;
        lmax = fmaxf(lmax, sum);
    }
    if (lane == 0) sred[w] = lmax;
    __syncthreads();
    float m = fmaxf(fmaxf(sred[0], sred[1]), fmaxf(sred[2], sred[3]));
    if (!isfinite(m)) m = 0.f;
    __syncthreads();

    float ls = 0.f;
    for (int n = beg + t; n < end; n += 256) {
        float e = expf(glogit[n] - m);
        glogit[n] = e;
        ls += e;
    }
    #pragma unroll
    for (int off = 32; off; off >>= 1) ls += __shfl_xor(ls, off);
    if (lane == 0) sred[w] = ls;
    __syncthreads();
    const float denom = sred[0] + sred[1] + sred[2] + sred[3] + 1e-16f;
    __syncthreads();

    float acc = 0.f;
    for (int n = beg; n < end; ++n)
        acc += glogit[n] * H2[(size_t)n * C2 + t];
    const float gc = acc / denom;

    for (int o = 0; o < NOUT; ++o) {
        float p = gc * Wf[t * NOUT + o];
        #pragma unroll
        for (int off = 32; off; off >>= 1) p += __shfl_xor(p, off);
        __syncthreads();
        if (lane == 0) sred[w] = p;
        __syncthreads();
        if (t == 0) out[b * NOUT + o] = sred[0] + sred[1] + sred[2] + sred[3] + bf[o];
    }
}

extern "C" void kernel_launch(void* const* d_in, const int* in_sizes, int n_in,
                              void* d_out, int out_size, void* d_ws, size_t ws_size,
                              hipStream_t stream) {
    (void)in_sizes; (void)n_in; (void)out_size; (void)ws_size;
    const float* x     = (const float*)d_in[0];
    const int*   ei    = (const int*)  d_in[1];
    const int*   batch = (const int*)  d_in[2];
    const float* Wq1 = (const float*)d_in[3];  const float* bq1 = (const float*)d_in[4];
    const float* Wk1 = (const float*)d_in[5];  const float* bk1 = (const float*)d_in[6];
    const float* Wv1 = (const float*)d_in[7];  const float* bv1 = (const float*)d_in[8];
    const float* Ws1 = (const float*)d_in[9];  const float* bs1 = (const float*)d_in[10];
    const float* Wq2 = (const float*)d_in[11]; const float* bq2 = (const float*)d_in[12];
    const float* Wk2 = (const float*)d_in[13]; const float* bk2 = (const float*)d_in[14];
    const float* Wv2 = (const float*)d_in[15]; const float* bv2 = (const float*)d_in[16];
    const float* Ws2 = (const float*)d_in[17]; const float* bs2 = (const float*)d_in[18];
    const float* Wg  = (const float*)d_in[19]; const float* bg  = (const float*)d_in[20];
    const float* Wf  = (const float*)d_in[21]; const float* bf  = (const float*)d_in[22];

    const int* src = ei;
    const int* dst = ei + NE;

    char* base = (char*)d_ws;
    size_t off = 0;
    auto alloc = [&](size_t bytes) -> char* {
        char* p = base + off;
        off = (off + bytes + 255) & ~(size_t)255;
        return p;
    };
    _Float16* xb    = (_Float16*)alloc((size_t)NN * FIN * 2);
    _Float16* wtq1  = (_Float16*)alloc((size_t)NHEAD * C1 * FIN * 2);
    _Float16* wtk1  = (_Float16*)alloc((size_t)NHEAD * C1 * FIN * 2);
    _Float16* bvs1  = (_Float16*)alloc((size_t)C1 * NHEAD * FIN * 2);   // [512,1024]
    _Float16* wts1  = (_Float16*)alloc((size_t)C1 * FIN * 2);           // [512,128]
    _Float16* Mst   = (_Float16*)alloc((size_t)NHEAD * FIN * FIN * 2);  // [1024,128]
    _Float16* wcat2 = (_Float16*)alloc((size_t)(3 * NHEAD * C2 + C2) * C1 * 2); // [6400,512]
    float* uvecs = (float*)alloc((size_t)NHEAD * FIN * 4);
    float* vvecs = (float*)alloc((size_t)NHEAD * FIN * 4);
    float* chd   = (float*)alloc((size_t)NHEAD * 4);
    float* ud    = (float*)alloc((size_t)NN * NHEAD * 4);
    float* vs    = (float*)alloc((size_t)NN * NHEAD * 4);
    float* zbias = (float*)alloc((size_t)NHEAD * FIN * 4);              // zeros [1024]
    float* bcat2 = (float*)alloc((size_t)(3 * NHEAD * C2 + C2) * 4);    // [6400]
    float* acc2  = (float*)alloc((size_t)NN * C2 * 4);
    _Float16* h1b = (_Float16*)alloc((size_t)NN * C1 * 2);
    float* alpha = (float*)alloc((size_t)NE * NHEAD * 4);
    float* ev    = (float*)alloc((size_t)NE * NHEAD * 4);
    unsigned* amaxU = (unsigned*)alloc((size_t)NN * NHEAD * 4);
    float* denom = (float*)alloc((size_t)NN * NHEAD * 4);
    int* deg    = (int*)alloc((size_t)NN * 4);
    int* rowptr = (int*)alloc((size_t)(NN + 1) * 4);
    int* cursor = (int*)alloc((size_t)NN * 4);
    int* eids   = (int*)alloc((size_t)NE * 4);
    float* bvm1 = (float*)alloc((size_t)C1 * 4);
    _Float16* Tbuf   = (_Float16*)alloc((size_t)NN * NHEAD * FIN * 2);      // 20.5MB
    _Float16* QKVbuf = (_Float16*)alloc((size_t)NN * 3 * NHEAD * C2 * 2);   // 123MB
    _Float16* Zbuf = QKVbuf;    // conv1 z-phase alias
    const int LDQKV = 3 * NHEAD * C2;   // 6144

    _Float16* wq2t = wcat2;
    _Float16* wk2t = wcat2 + (size_t)NHEAD * C2 * C1;
    _Float16* wv2t = wcat2 + (size_t)2 * NHEAD * C2 * C1;
    _Float16* ws2t = wcat2 + (size_t)3 * NHEAD * C2 * C1;

    const dim3 blk(256);
    const float sc1 = 1.0f / sqrtf((float)C1);
    const float sc2 = 1.0f / sqrtf((float)C2);
    const int edge_blocks = (NE * 64) / 256;
    const int node_blocks = (NN * 64) / 256;
    const int gy = (NN + 127) / 128;   // 79

    // ---- conversions + precompute ----
    cvt_f16<<<((size_t)NN * FIN + 255) / 256, blk, 0, stream>>>(x, xb, NN * FIN);
    {
        dim3 tb(32, 8);
        transpose_cvt<<<dim3(NHEAD * C1 / 32, FIN / 32), tb, 0, stream>>>(Wq1, wtq1, FIN, NHEAD * C1);
        transpose_cvt<<<dim3(NHEAD * C1 / 32, FIN / 32), tb, 0, stream>>>(Wk1, wtk1, FIN, NHEAD * C1);
        transpose_stack<<<dim3(C1 / 32, FIN / 32, NHEAD), tb, 0, stream>>>(Wv1, bvs1, FIN, C1);
        transpose_cvt<<<dim3(C1 / 32, FIN / 32),         tb, 0, stream>>>(Ws1, wts1, FIN, C1);
        transpose_cvt<<<dim3(NHEAD * C2 / 32, C1 / 32),  tb, 0, stream>>>(Wq2, wq2t, C1, NHEAD * C2);
        transpose_cvt<<<dim3(NHEAD * C2 / 32, C1 / 32),  tb, 0, stream>>>(Wk2, wk2t, C1, NHEAD * C2);
        transpose_cvt<<<dim3(NHEAD * C2 / 32, C1 / 32),  tb, 0, stream>>>(Wv2, wv2t, C1, NHEAD * C2);
        transpose_cvt<<<dim3(C2 / 32, C1 / 32),          tb, 0, stream>>>(Ws2, ws2t, C1, C2);
    }
    bvmean_k<<<(C1 + 255) / 256, blk, 0, stream>>>(bv1, bvm1, C1);
    mstack_k<<<dim3(FIN / 16, FIN / 16, NHEAD), dim3(16, 16), 0, stream>>>(wtq1, wtk1, Mst);
    uvprep<<<NHEAD, FIN, 0, stream>>>(Wq1, Wk1, bq1, bk1, uvecs, vvecs, chd);
    udvs_k<<<(NN * NHEAD + 255) / 256, blk, 0, stream>>>(xb, uvecs, vvecs, chd, ud, vs);
    zero_i32<<<(NHEAD * FIN + 255) / 256, blk, 0, stream>>>((int*)zbias, NHEAD * FIN);
    bcat2_k<<<(3 * NHEAD * C2 + C2 + 255) / 256, blk, 0, stream>>>(bq2, bk2, bv2, bs2, bcat2);

    // ---- CSR by dst ----
    zero_i32<<<(NN + 255) / 256, blk, 0, stream>>>(deg, NN);
    hist_dst<<<(NE + 255) / 256, blk, 0, stream>>>(dst, deg);
    scan_deg<<<1, blk, 0, stream>>>(deg, rowptr, cursor, NN);
    scatter_edges<<<(NE + 255) / 256, blk, 0, stream>>>(dst, cursor, eids);

    // ================ conv1: low-rank QK, z-trick, fused cat2+ELU ================
    {   // T = X @ M   [10000,1024] K=128; gx=8, SW=8
        int nwg = 8 * gy;
        gemm_f16<<<nwg, blk, 0, stream>>>(xb, Mst, zbias, Tbuf, NHEAD * FIN, NN, FIN,
                                          nwg, 8, 8);
    }
    init_seg<<<(NN * NHEAD + 255) / 256, blk, 0, stream>>>(amaxU, denom, NN * NHEAD);
    edge_alpha_lr<<<edge_blocks, blk, 0, stream>>>(Tbuf, xb, ud, vs, src, dst,
                                                   alpha, amaxU, sc1);
    edge_expsum<<<(NE * NHEAD + 255) / 256, blk, 0, stream>>>(alpha, dst, amaxU, ev, denom);
    zaccum<FIN, NHEAD><<<node_blocks, blk, 0, stream>>>(xb, ev, denom, rowptr, eids, src,
                                                        Zbuf, 0);
    {   // h1b = ELU([Z|xb] @ [bvs1|wts1]^T + bs1 + gated bvm1)  [10000,512] K=1152; gx=4, SW=4
        int nwg = 4 * gy;
        gemm_cat2_elu<<<nwg, blk, 0, stream>>>(Zbuf, NHEAD * FIN, xb, FIN,
                                               bvs1, wts1, bs1, bvm1, deg, h1b,
                                               NN, nwg, 4, 4);
    }

    // ================ conv2: [QKV | skip] dual GEMM (XCD-swizzled), fused edge/aggr ================
    init_seg<<<(NN * NHEAD + 255) / 256, blk, 0, stream>>>(amaxU, denom, NN * NHEAD);
    {   // [10000, 6400] K=512; gx=50, SW=25
        int nwg = 50 * gy;
        gemm_dual<<<nwg, blk, 0, stream>>>(h1b, wcat2, bcat2, QKVbuf, LDQKV,
                                           acc2, C2, LDQKV, NN, C1, nwg, 50, 25);
    }
    edge_alpha_fu<C2, NHEAD><<<edge_blocks, blk, 0, stream>>>(
        QKVbuf, QKVbuf + NHEAD * C2, LDQKV, src, dst, alpha, amaxU, sc2);
    edge_expsum<<<(NE * NHEAD + 255) / 256, blk, 0, stream>>>(alpha, dst, amaxU, ev, denom);
    node_aggr_ilp<C2, NHEAD><<<node_blocks, blk, 0, stream>>>(
        QKVbuf + 2 * NHEAD * C2, LDQKV, ev, denom, rowptr, eids, src, acc2);
    elu_k<<<((size_t)NN * C2 + 255) / 256, blk, 0, stream>>>(acc2, NN * C2);

    // ================ fused pooling + fc ================
    pool_fused<<<NB, blk, 0, stream>>>(acc2, Wg, bg, batch, Wf, bf, alpha, (float*)d_out);
}

// Round 13
// 585.585 us; speedup vs baseline: 2.1085x; 1.0406x over previous
//
#include <hip/hip_runtime.h>
#include <math.h>

#define NN 10000
#define NE 20000
#define FIN 128
#define NHEAD 8
#define C1 512
#define C2 256
#define NB 64
#define NOUT 10

typedef _Float16 half8v __attribute__((ext_vector_type(8)));
typedef _Float16 half4v __attribute__((ext_vector_type(4)));
typedef _Float16 half2v __attribute__((ext_vector_type(2)));
typedef float f32x4 __attribute__((ext_vector_type(4)));

template<int VEC> struct VecT;
template<> struct VecT<2> { using T = half2v; };
template<> struct VecT<4> { using T = half4v; };
template<> struct VecT<8> { using T = half8v; };

__device__ __forceinline__ unsigned enc_f(float f) {
    unsigned u = __float_as_uint(f);
    return (u & 0x80000000u) ? ~u : (u | 0x80000000u);
}
__device__ __forceinline__ float dec_f(unsigned e) {
    return (e & 0x80000000u) ? __uint_as_float(e & 0x7fffffffu) : __uint_as_float(~e);
}

__device__ __forceinline__ void gload16(const _Float16* g, _Float16* l) {
    __builtin_amdgcn_global_load_lds(
        (const __attribute__((address_space(1))) unsigned int*)(const void*)g,
        (__attribute__((address_space(3))) unsigned int*)(void*)l, 16, 0, 0);
}

// XCD-affine swizzle: bijective mod-8 chunk remap (m204) + stripe traversal.
__device__ __forceinline__ void swz_map(int nwg, int gx, int SW, int& bx, int& by) {
    int orig = blockIdx.x;
    int q = nwg >> 3, r = nwg & 7;
    int xcd = orig & 7, lid = orig >> 3;
    int wgid = (xcd < r ? xcd * (q + 1) : r * (q + 1) + (xcd - r) * q) + lid;
    int gy = nwg / gx;
    int sh = SW * gy;
    int stripe = wgid / sh;
    int rem = wgid - stripe * sh;
    int byq = rem / SW;
    by = byq;
    bx = stripe * SW + (rem - byq * SW);
}

// ---------------- conversion / transpose ----------------
__global__ void cvt_f16(const float* __restrict__ in, _Float16* __restrict__ out, int n) {
    int i = blockIdx.x * blockDim.x + threadIdx.x;
    if (i < n) out[i] = (_Float16)in[i];
}

__global__ void transpose_cvt(const float* __restrict__ W, _Float16* __restrict__ Wt,
                              int K, int N) {
    __shared__ float tile[32][33];
    int n0 = blockIdx.x * 32, k0 = blockIdx.y * 32;
    int tx = threadIdx.x, ty = threadIdx.y;
    for (int j = ty; j < 32; j += 8) tile[j][tx] = W[(size_t)(k0 + j) * N + n0 + tx];
    __syncthreads();
    for (int j = ty; j < 32; j += 8)
        Wt[(size_t)(n0 + j) * K + k0 + tx] = (_Float16)tile[tx][j];
}

__global__ void transpose_stack(const float* __restrict__ Wv, _Float16* __restrict__ Bt,
                                int Cin, int Cout) {
    __shared__ float tile[32][33];
    int h = blockIdx.z;
    int c0 = blockIdx.x * 32, k0 = blockIdx.y * 32;
    int tx = threadIdx.x, ty = threadIdx.y;
    for (int j = ty; j < 32; j += 8)
        tile[j][tx] = Wv[(size_t)(k0 + j) * (NHEAD * Cout) + (size_t)h * Cout + c0 + tx];
    __syncthreads();
    for (int j = ty; j < 32; j += 8)
        Bt[(size_t)(c0 + j) * (NHEAD * Cin) + (size_t)h * Cin + k0 + tx] = (_Float16)tile[tx][j];
}

__global__ void bvmean_k(const float* __restrict__ bv, float* __restrict__ bvm, int C) {
    int c = blockIdx.x * blockDim.x + threadIdx.x;
    if (c >= C) return;
    float s = 0.f;
    #pragma unroll
    for (int h = 0; h < NHEAD; ++h) s += bv[h * C + c];
    bvm[c] = s * (1.0f / NHEAD);
}

__global__ void bcat2_k(const float* __restrict__ bq2, const float* __restrict__ bk2,
                        const float* __restrict__ bv2, const float* __restrict__ bs2,
                        float* __restrict__ o) {
    int i = blockIdx.x * blockDim.x + threadIdx.x;
    const int n = NHEAD * C2;
    if (i < n) o[i] = bq2[i];
    else if (i < 2 * n) o[i] = bk2[i - n];
    else if (i < 3 * n) o[i] = bv2[i - 2 * n];
    else if (i < 3 * n + C2) o[i] = bs2[i - 3 * n];
}

// ---------------- conv1 low-rank QK precompute ----------------
__global__ void mstack_k(const _Float16* __restrict__ wtq1, const _Float16* __restrict__ wtk1,
                         _Float16* __restrict__ Mst) {
    int h = blockIdx.z;
    int i = blockIdx.x * 16 + threadIdx.x;
    int j = blockIdx.y * 16 + threadIdx.y;
    float acc = 0.f;
    for (int c = 0; c < C1; ++c)
        acc += (float)wtq1[((size_t)h * C1 + c) * FIN + i] *
               (float)wtk1[((size_t)h * C1 + c) * FIN + j];
    Mst[((size_t)h * FIN + j) * FIN + i] = (_Float16)acc;
}

// wave-parallel u/v: one wave per (h,i)
__global__ void uvprep_w(const float* __restrict__ Wq1, const float* __restrict__ Wk1,
                         const float* __restrict__ bq1, const float* __restrict__ bk1,
                         float* __restrict__ u, float* __restrict__ v) {
    int wid = (blockIdx.x * blockDim.x + threadIdx.x) >> 6;
    int lane = threadIdx.x & 63;
    if (wid >= NHEAD * FIN) return;
    int h = wid >> 7, i = wid & 127;
    const float* wq = Wq1 + (size_t)i * (NHEAD * C1) + h * C1;
    const float* wk = Wk1 + (size_t)i * (NHEAD * C1) + h * C1;
    const float* bk = bk1 + h * C1;
    const float* bq = bq1 + h * C1;
    int c = lane * 8;
    float4 a0 = *(const float4*)(wq + c),  a1 = *(const float4*)(wq + c + 4);
    float4 p0 = *(const float4*)(bk + c),  p1 = *(const float4*)(bk + c + 4);
    float4 b0 = *(const float4*)(wk + c),  b1 = *(const float4*)(wk + c + 4);
    float4 q0 = *(const float4*)(bq + c),  q1 = *(const float4*)(bq + c + 4);
    float su = a0.x*p0.x + a0.y*p0.y + a0.z*p0.z + a0.w*p0.w
             + a1.x*p1.x + a1.y*p1.y + a1.z*p1.z + a1.w*p1.w;
    float sv = b0.x*q0.x + b0.y*q0.y + b0.z*q0.z + b0.w*q0.w
             + b1.x*q1.x + b1.y*q1.y + b1.z*q1.z + b1.w*q1.w;
    #pragma unroll
    for (int off = 32; off; off >>= 1) {
        su += __shfl_xor(su, off);
        sv += __shfl_xor(sv, off);
    }
    if (lane == 0) { u[h * FIN + i] = su; v[h * FIN + i] = sv; }
}

// ch[h] = bq1_h . bk1_h  (one wave per head, 1 block of 512)
__global__ void chd_k(const float* __restrict__ bq1, const float* __restrict__ bk1,
                      float* __restrict__ ch) {
    int h = threadIdx.x >> 6, lane = threadIdx.x & 63;
    int c = lane * 8;
    const float* bq = bq1 + h * C1;
    const float* bk = bk1 + h * C1;
    float4 a0 = *(const float4*)(bq + c), a1 = *(const float4*)(bq + c + 4);
    float4 b0 = *(const float4*)(bk + c), b1 = *(const float4*)(bk + c + 4);
    float s = a0.x*b0.x + a0.y*b0.y + a0.z*b0.z + a0.w*b0.w
            + a1.x*b1.x + a1.y*b1.y + a1.z*b1.z + a1.w*b1.w;
    #pragma unroll
    for (int off = 32; off; off >>= 1) s += __shfl_xor(s, off);
    if (lane == 0) ch[h] = s;
}

// wave-parallel ud/vs: one wave per node
__global__ void udvs_w(const _Float16* __restrict__ xb, const float* __restrict__ u,
                       const float* __restrict__ v, const float* __restrict__ ch,
                       float* __restrict__ ud, float* __restrict__ vs) {
    int n = (blockIdx.x * blockDim.x + threadIdx.x) >> 6;
    int lane = threadIdx.x & 63;
    if (n >= NN) return;
    half2v xv = *(const half2v*)(xb + (size_t)n * FIN + lane * 2);
    float x0 = (float)xv[0], x1 = (float)xv[1];
    #pragma unroll
    for (int h = 0; h < NHEAD; ++h) {
        float2 uu = *(const float2*)(u + h * FIN + lane * 2);
        float2 vv = *(const float2*)(v + h * FIN + lane * 2);
        float su = x0 * uu.x + x1 * uu.y;
        float sv = x0 * vv.x + x1 * vv.y;
        #pragma unroll
        for (int off = 32; off; off >>= 1) {
            su += __shfl_xor(su, off);
            sv += __shfl_xor(sv, off);
        }
        if (lane == 0) {
            ud[(size_t)n * NHEAD + h] = su + ch[h];
            vs[(size_t)n * NHEAD + h] = sv;
        }
    }
}

// ---------------- MFMA GEMM core (m97 structure, XCD-swizzled 1D grid) ----------------
#define GEMM_CORE                                                                   \
    __shared__ _Float16 As[128 * 32];                                               \
    __shared__ _Float16 Bs[128 * 32];                                               \
    __shared__ _Float16 Ct[64 * 136];                                               \
    const int t = threadIdx.x;                                                      \
    const int w = t >> 6, lane = t & 63;                                            \
    const int wr = w >> 1, wc = w & 1;                                              \
    const int r_lo = lane >> 2, slot = lane & 3;                                    \
    f32x4 acc[4][4];                                                                \
    _Pragma("unroll")                                                               \
    for (int m = 0; m < 4; ++m)                                                     \
        _Pragma("unroll")                                                           \
        for (int n = 0; n < 4; ++n)                                                 \
            _Pragma("unroll")                                                       \
            for (int j = 0; j < 4; ++j) acc[m][n][j] = 0.f;

#define GEMM_STEP(APTR, ALD, AKO, BPTR, BLD, BKO)                                   \
    {                                                                               \
        _Pragma("unroll")                                                           \
        for (int i = 0; i < 2; ++i) {                                               \
            int chunk = 2 * w + i;                                                  \
            int row = chunk * 16 + r_lo;                                            \
            int gr = m0 + row; gr = gr < M ? gr : M - 1;                            \
            gload16(APTR + (size_t)gr * ALD + AKO + slot * 8, &As[chunk * 512]);    \
            gload16(BPTR + (size_t)(n0 + row) * BLD + BKO + slot * 8, &Bs[chunk * 512]); \
        }                                                                           \
        __syncthreads();                                                            \
        half8v af[4], bf[4];                                                        \
        _Pragma("unroll")                                                           \
        for (int m = 0; m < 4; ++m)                                                 \
            af[m] = *(const half8v*)(&As[(wr * 64 + m * 16 + (lane & 15)) * 32 + (lane >> 4) * 8]); \
        _Pragma("unroll")                                                           \
        for (int n = 0; n < 4; ++n)                                                 \
            bf[n] = *(const half8v*)(&Bs[(wc * 64 + n * 16 + (lane & 15)) * 32 + (lane >> 4) * 8]); \
        _Pragma("unroll")                                                           \
        for (int m = 0; m < 4; ++m)                                                 \
            _Pragma("unroll")                                                       \
            for (int n = 0; n < 4; ++n)                                             \
                acc[m][n] = __builtin_amdgcn_mfma_f32_16x16x32_f16(af[m], bf[n], acc[m][n], 0, 0, 0); \
        __syncthreads();                                                            \
    }

// LDS-staged coalesced f16 epilogue. STAGE_EXPR computes float v from (acc val, grow, gcol).
#define EPI_F16(OUTPTR, LDC, STAGE_EXPR)                                            \
    _Pragma("unroll")                                                               \
    for (int half = 0; half < 2; ++half) {                                          \
        __syncthreads();                                                            \
        if (wr == half) {                                                           \
            _Pragma("unroll")                                                       \
            for (int m = 0; m < 4; ++m)                                             \
                _Pragma("unroll")                                                   \
                for (int n = 0; n < 4; ++n) {                                       \
                    int lcol = wc * 64 + n * 16 + (lane & 15);                      \
                    int gcol = n0 + lcol;                                           \
                    _Pragma("unroll")                                               \
                    for (int r = 0; r < 4; ++r) {                                   \
                        int lrow = m * 16 + (lane >> 4) * 4 + r;                    \
                        int grow = m0 + half * 64 + lrow;                           \
                        float av = acc[m][n][r];                                    \
                        Ct[lrow * 136 + lcol] = (_Float16)(STAGE_EXPR);             \
                    }                                                               \
                }                                                                   \
        }                                                                           \
        __syncthreads();                                                            \
        _Pragma("unroll")                                                           \
        for (int g = 0; g < 4; ++g) {                                               \
            int lrow = g * 16 + (t >> 4);                                           \
            int grow = m0 + half * 64 + lrow;                                       \
            if (grow < M) {                                                         \
                int seg = (t & 15) * 8;                                             \
                *(float4*)(OUTPTR + (size_t)grow * LDC + n0 + seg) =                \
                    *(const float4*)(&Ct[lrow * 136 + seg]);                        \
            }                                                                       \
        }                                                                           \
    }

// plain GEMM, f16 out (+bias), coalesced epilogue
__global__ __launch_bounds__(256) void gemm_f16(
    const _Float16* __restrict__ A, const _Float16* __restrict__ Bt,
    const float* __restrict__ bias, _Float16* __restrict__ Cout, int ldc,
    int M, int K, int nwg, int gx, int SW)
{
    int bx, by; swz_map(nwg, gx, SW, bx, by);
    const int m0 = by * 128, n0 = bx * 128;
    GEMM_CORE
    for (int k0 = 0; k0 < K; k0 += 32) GEMM_STEP(A, K, k0, Bt, K, k0)
    EPI_F16(Cout, ldc, av + bias[gcol])
}

// dual-output GEMM: blocks with n0<NSPLIT are all-f16 (staged); others f32 scalar
__global__ __launch_bounds__(256) void gemm_dual(
    const _Float16* __restrict__ A, const _Float16* __restrict__ Bt,
    const float* __restrict__ bias, _Float16* __restrict__ out16, int ld16,
    float* __restrict__ out32, int ld32, int NSPLIT, int M, int K,
    int nwg, int gx, int SW)
{
    int bx, by; swz_map(nwg, gx, SW, bx, by);
    const int m0 = by * 128, n0 = bx * 128;
    GEMM_CORE
    for (int k0 = 0; k0 < K; k0 += 32) GEMM_STEP(A, K, k0, Bt, K, k0)
    if (n0 < NSPLIT) {
        EPI_F16(out16, ld16, av + bias[gcol])
    } else {
        #pragma unroll
        for (int m = 0; m < 4; ++m) {
            int r0 = m0 + wr * 64 + m * 16 + (lane >> 4) * 4;
            #pragma unroll
            for (int n = 0; n < 4; ++n) {
                int col = n0 + wc * 64 + n * 16 + (lane & 15);
                float b = bias[col];
                #pragma unroll
                for (int r = 0; r < 4; ++r) {
                    int row = r0 + r;
                    if (row < M)
                        out32[(size_t)row * ld32 + (col - NSPLIT)] = acc[m][n][r] + b;
                }
            }
        }
    }
}

// K-concat GEMM + fused conv1 epilogue: h1b = ELU([Z|xb]@[B1|B2]^T + bs1 + gated bvm1)
__global__ __launch_bounds__(256) void gemm_cat2_elu(
    const _Float16* __restrict__ A1, int K1, const _Float16* __restrict__ A2, int K2,
    const _Float16* __restrict__ B1, const _Float16* __restrict__ B2,
    const float* __restrict__ bs1, const float* __restrict__ bvm1,
    const int* __restrict__ deg, _Float16* __restrict__ h1b,
    int M, int nwg, int gx, int SW)
{
    int bx, by; swz_map(nwg, gx, SW, bx, by);
    const int m0 = by * 128, n0 = bx * 128;
    const int K = K1 + K2;
    GEMM_CORE
    for (int k0 = 0; k0 < K; k0 += 32) {
        if (k0 < K1) GEMM_STEP(A1, K1, k0, B1, K1, k0)
        else         GEMM_STEP(A2, K2, (k0 - K1), B2, K2, (k0 - K1))
    }
    EPI_F16(h1b, C1,
        ({ int dr = grow < M ? grow : M - 1;
           float vv = av + bs1[gcol] + (deg[dr] > 0 ? bvm1[gcol] : 0.f);
           vv > 0.f ? vv : expm1f(vv); }))
}

// ---------------- CSR build (by dst) ----------------
__global__ void zero_i32(int* __restrict__ p, int n) {
    int i = blockIdx.x * blockDim.x + threadIdx.x;
    if (i < n) p[i] = 0;
}
__global__ void hist_dst(const int* __restrict__ dst, int* __restrict__ deg) {
    int e = blockIdx.x * blockDim.x + threadIdx.x;
    if (e < NE) atomicAdd(&deg[dst[e]], 1);
}
__global__ void scan_deg(const int* __restrict__ deg, int* __restrict__ rowptr,
                         int* __restrict__ cursor, int n) {
    __shared__ int s[256];
    __shared__ int carry;
    int t = threadIdx.x;
    if (t == 0) carry = 0;
    __syncthreads();
    for (int base = 0; base < n; base += 256) {
        int v = (base + t < n) ? deg[base + t] : 0;
        s[t] = v;
        __syncthreads();
        for (int off = 1; off < 256; off <<= 1) {
            int x = (t >= off) ? s[t - off] : 0;
            __syncthreads();
            s[t] += x;
            __syncthreads();
        }
        int excl = carry + s[t] - v;
        if (base + t < n) { rowptr[base + t] = excl; cursor[base + t] = excl; }
        __syncthreads();
        if (t == 255) carry += s[255];
        __syncthreads();
    }
    if (t == 0) rowptr[n] = carry;
}
__global__ void scatter_edges(const int* __restrict__ dst, int* __restrict__ cursor,
                              int* __restrict__ eids) {
    int e = blockIdx.x * blockDim.x + threadIdx.x;
    if (e < NE) {
        int pos = atomicAdd(&cursor[dst[e]], 1);
        eids[pos] = e;
    }
}

// ---------------- segment softmax pieces ----------------
__global__ void init_seg(unsigned* __restrict__ amax, float* __restrict__ denom, int n) {
    int i = blockIdx.x * blockDim.x + threadIdx.x;
    if (i < n) { amax[i] = 0x007FFFFFu; denom[i] = 0.f; }
}

__global__ void edge_alpha_lr(const _Float16* __restrict__ T, const _Float16* __restrict__ X,
                              const float* __restrict__ ud, const float* __restrict__ vs,
                              const int* __restrict__ src, const int* __restrict__ dst,
                              float* __restrict__ alpha, unsigned* __restrict__ amaxU,
                              float scale)
{
    int gi = blockIdx.x * blockDim.x + threadIdx.x;
    int e = gi >> 6, lane = threadIdx.x & 63;
    if (e >= NE) return;
    int s = src[e], d = dst[e];
    half2v xv = *(const half2v*)(X + (size_t)s * FIN + lane * 2);
    #pragma unroll
    for (int h = 0; h < NHEAD; ++h) {
        half2v tv = *(const half2v*)(T + ((size_t)d * NHEAD + h) * FIN + lane * 2);
        float sum = (float)tv[0] * (float)xv[0] + (float)tv[1] * (float)xv[1];
        #pragma unroll
        for (int off = 32; off; off >>= 1) sum += __shfl_xor(sum, off);
        if (lane == 0) {
            float al = (sum + ud[(size_t)d * NHEAD + h] + vs[(size_t)s * NHEAD + h]) * scale;
            alpha[(size_t)e * NHEAD + h] = al;
            atomicMax(&amaxU[(size_t)d * NHEAD + h], enc_f(al));
        }
    }
}

template<int C, int G>
__global__ void edge_alpha_fu(const _Float16* __restrict__ Q, const _Float16* __restrict__ Kh,
                              int ldq, const int* __restrict__ src, const int* __restrict__ dst,
                              float* __restrict__ alpha, unsigned* __restrict__ amaxU,
                              float scale)
{
    constexpr int VEC = C / 64;
    using vecH = typename VecT<VEC>::T;
    int gi = blockIdx.x * blockDim.x + threadIdx.x;
    int e = gi >> 6, lane = threadIdx.x & 63;
    if (e >= NE) return;
    int s = src[e], d = dst[e];
    const _Float16* qp = Q + (size_t)d * ldq + lane * VEC;
    const _Float16* kp = Kh + (size_t)s * ldq + lane * VEC;
    vecH q[G], k[G];
    #pragma unroll
    for (int h = 0; h < G; ++h) {
        q[h] = *(const vecH*)(qp + h * C);
        k[h] = *(const vecH*)(kp + h * C);
    }
    #pragma unroll
    for (int h = 0; h < G; ++h) {
        float sum = 0.f;
        #pragma unroll
        for (int j = 0; j < VEC; ++j) sum += (float)q[h][j] * (float)k[h][j];
        #pragma unroll
        for (int off = 32; off; off >>= 1) sum += __shfl_xor(sum, off);
        if (lane == 0) {
            float al = sum * scale;
            alpha[(size_t)e * NHEAD + h] = al;
            atomicMax(&amaxU[(size_t)d * NHEAD + h], enc_f(al));
        }
    }
}

__global__ void edge_expsum(const float* __restrict__ alpha, const int* __restrict__ dst,
                            const unsigned* __restrict__ amaxU,
                            float* __restrict__ ev, float* __restrict__ denom)
{
    int i = blockIdx.x * blockDim.x + threadIdx.x;
    if (i >= NE * NHEAD) return;
    int e = i >> 3, h = i & 7;
    int d = dst[e];
    float ex = expf(alpha[i] - dec_f(amaxU[(size_t)d * NHEAD + h]));
    ev[i] = ex;
    atomicAdd(&denom[(size_t)d * NHEAD + h], ex);
}

template<int C, int G>
__global__ void zaccum(const _Float16* __restrict__ X, const float* __restrict__ ev,
                       const float* __restrict__ denom, const int* __restrict__ rowptr,
                       const int* __restrict__ eids, const int* __restrict__ src,
                       _Float16* __restrict__ Z, int hbase)
{
    constexpr int VEC = C / 64;
    using vecH = typename VecT<VEC>::T;
    int gi = blockIdx.x * blockDim.x + threadIdx.x;
    int n = gi >> 6, lane = threadIdx.x & 63;
    if (n >= NN) return;
    int beg = rowptr[n], end = rowptr[n + 1];
    float rd[G];
    #pragma unroll
    for (int h = 0; h < G; ++h)
        rd[h] = (1.0f / NHEAD) / (denom[(size_t)n * NHEAD + hbase + h] + 1e-16f);
    float acc[G][VEC];
    #pragma unroll
    for (int h = 0; h < G; ++h)
        #pragma unroll
        for (int j = 0; j < VEC; ++j) acc[h][j] = 0.f;
    for (int i = beg; i < end; ++i) {
        int e = eids[i];
        int s = src[e];
        vecH xv = *(const vecH*)(X + (size_t)s * C + lane * VEC);
        #pragma unroll
        for (int h = 0; h < G; ++h) {
            float cf = ev[(size_t)e * NHEAD + hbase + h] * rd[h];
            #pragma unroll
            for (int j = 0; j < VEC; ++j) acc[h][j] += cf * (float)xv[j];
        }
    }
    #pragma unroll
    for (int h = 0; h < G; ++h) {
        vecH o;
        #pragma unroll
        for (int j = 0; j < VEC; ++j) o[j] = (_Float16)acc[h][j];
        *(vecH*)(Z + (size_t)n * (G * C) + (size_t)h * C + lane * VEC) = o;
    }
}

template<int C, int G>
__global__ void node_aggr_ilp(const _Float16* __restrict__ V, int ldv,
                              const float* __restrict__ ev, const float* __restrict__ denom,
                              const int* __restrict__ rowptr, const int* __restrict__ eids,
                              const int* __restrict__ src, float* __restrict__ acc)
{
    constexpr int VEC = C / 64;
    using vecH = typename VecT<VEC>::T;
    int gi = blockIdx.x * blockDim.x + threadIdx.x;
    int n = gi >> 6, lane = threadIdx.x & 63;
    if (n >= NN) return;
    int beg = rowptr[n], end = rowptr[n + 1];
    float rd[G];
    #pragma unroll
    for (int h = 0; h < G; ++h)
        rd[h] = (1.0f / NHEAD) / (denom[(size_t)n * NHEAD + h] + 1e-16f);
    float a[VEC];
    #pragma unroll
    for (int j = 0; j < VEC; ++j) a[j] = 0.f;
    for (int i = beg; i < end; ++i) {
        int e = eids[i];
        int s = src[e];
        float cf[G];
        #pragma unroll
        for (int h = 0; h < G; ++h) cf[h] = ev[(size_t)e * NHEAD + h] * rd[h];
        vecH v[G];
        #pragma unroll
        for (int h = 0; h < G; ++h)
            v[h] = *(const vecH*)(V + (size_t)s * ldv + h * C + lane * VEC);
        #pragma unroll
        for (int h = 0; h < G; ++h)
            #pragma unroll
            for (int j = 0; j < VEC; ++j) a[j] += cf[h] * (float)v[h][j];
    }
    float* ap = acc + (size_t)n * C + lane * VEC;
    #pragma unroll
    for (int j = 0; j < VEC; ++j) ap[j] += a[j];
}

__global__ void elu_k(float* __restrict__ x, int n) {
    int i = blockIdx.x * blockDim.x + threadIdx.x;
    if (i < n) { float v = x[i]; x[i] = v > 0.f ? v : expm1f(v); }
}

// ---------------- fused global-attention pooling + final fc ----------------
__global__ __launch_bounds__(256) void pool_fused(
    const float* __restrict__ H2, const float* __restrict__ Wg,
    const float* __restrict__ bg, const int* __restrict__ batch,
    const float* __restrict__ Wf, const float* __restrict__ bf,
    float* __restrict__ glogit, float* __restrict__ out)
{
    const int b = blockIdx.x;
    const int t = threadIdx.x, lane = t & 63, w = t >> 6;
    __shared__ int sbeg, send;
    __shared__ float sred[4];
    if (t == 0) {
        int lo = 0, hi = NN;
        while (lo < hi) { int mid = (lo + hi) >> 1; if (batch[mid] < b) lo = mid + 1; else hi = mid; }
        sbeg = lo;
        hi = NN;
        while (lo < hi) { int mid = (lo + hi) >> 1; if (batch[mid] < b + 1) lo = mid + 1; else hi = mid; }
        send = lo;
    }
    __syncthreads();
    const int beg = sbeg, end = send;
    const float bg0 = bg[0];

    float lmax = -INFINITY;
    for (int n = beg + w; n < end; n += 4) {
        float4 h = ((const float4*)(H2 + (size_t)n * C2))[lane];
        float4 wv = ((const float4*)Wg)[lane];
        float sum = h.x * wv.x + h.y * wv.y + h.z * wv.z + h.w * wv.w;
        #pragma unroll
        for (int off = 32; off; off >>= 1) sum += __shfl_xor(sum, off);
        sum += bg0;
        if (lane == 0) glogit[n] = sum;
        lmax = fmaxf(lmax, sum);
    }
    if (lane == 0) sred[w] = lmax;
    __syncthreads();
    float m = fmaxf(fmaxf(sred[0], sred[1]), fmaxf(sred[2], sred[3]));
    if (!isfinite(m)) m = 0.f;
    __syncthreads();

    float ls = 0.f;
    for (int n = beg + t; n < end; n += 256) {
        float e = expf(glogit[n] - m);
        glogit[n] = e;
        ls += e;
    }
    #pragma unroll
    for (int off = 32; off; off >>= 1) ls += __shfl_xor(ls, off);
    if (lane == 0) sred[w] = ls;
    __syncthreads();
    const float denom = sred[0] + sred[1] + sred[2] + sred[3] + 1e-16f;
    __syncthreads();

    float acc = 0.f;
    for (int n = beg; n < end; ++n)
        acc += glogit[n] * H2[(size_t)n * C2 + t];
    const float gc = acc / denom;

    for (int o = 0; o < NOUT; ++o) {
        float p = gc * Wf[t * NOUT + o];
        #pragma unroll
        for (int off = 32; off; off >>= 1) p += __shfl_xor(p, off);
        __syncthreads();
        if (lane == 0) sred[w] = p;
        __syncthreads();
        if (t == 0) out[b * NOUT + o] = sred[0] + sred[1] + sred[2] + sred[3] + bf[o];
    }
}

extern "C" void kernel_launch(void* const* d_in, const int* in_sizes, int n_in,
                              void* d_out, int out_size, void* d_ws, size_t ws_size,
                              hipStream_t stream) {
    (void)in_sizes; (void)n_in; (void)out_size; (void)ws_size;
    const float* x     = (const float*)d_in[0];
    const int*   ei    = (const int*)  d_in[1];
    const int*   batch = (const int*)  d_in[2];
    const float* Wq1 = (const float*)d_in[3];  const float* bq1 = (const float*)d_in[4];
    const float* Wk1 = (const float*)d_in[5];  const float* bk1 = (const float*)d_in[6];
    const float* Wv1 = (const float*)d_in[7];  const float* bv1 = (const float*)d_in[8];
    const float* Ws1 = (const float*)d_in[9];  const float* bs1 = (const float*)d_in[10];
    const float* Wq2 = (const float*)d_in[11]; const float* bq2 = (const float*)d_in[12];
    const float* Wk2 = (const float*)d_in[13]; const float* bk2 = (const float*)d_in[14];
    const float* Wv2 = (const float*)d_in[15]; const float* bv2 = (const float*)d_in[16];
    const float* Ws2 = (const float*)d_in[17]; const float* bs2 = (const float*)d_in[18];
    const float* Wg  = (const float*)d_in[19]; const float* bg  = (const float*)d_in[20];
    const float* Wf  = (const float*)d_in[21]; const float* bf  = (const float*)d_in[22];

    const int* src = ei;
    const int* dst = ei + NE;

    char* base = (char*)d_ws;
    size_t off = 0;
    auto alloc = [&](size_t bytes) -> char* {
        char* p = base + off;
        off = (off + bytes + 255) & ~(size_t)255;
        return p;
    };
    _Float16* xb    = (_Float16*)alloc((size_t)NN * FIN * 2);
    _Float16* wtq1  = (_Float16*)alloc((size_t)NHEAD * C1 * FIN * 2);
    _Float16* wtk1  = (_Float16*)alloc((size_t)NHEAD * C1 * FIN * 2);
    _Float16* bvs1  = (_Float16*)alloc((size_t)C1 * NHEAD * FIN * 2);   // [512,1024]
    _Float16* wts1  = (_Float16*)alloc((size_t)C1 * FIN * 2);           // [512,128]
    _Float16* Mst   = (_Float16*)alloc((size_t)NHEAD * FIN * FIN * 2);  // [1024,128]
    _Float16* wcat2 = (_Float16*)alloc((size_t)(3 * NHEAD * C2 + C2) * C1 * 2); // [6400,512]
    float* uvecs = (float*)alloc((size_t)NHEAD * FIN * 4);
    float* vvecs = (float*)alloc((size_t)NHEAD * FIN * 4);
    float* chd   = (float*)alloc((size_t)NHEAD * 4);
    float* ud    = (float*)alloc((size_t)NN * NHEAD * 4);
    float* vs    = (float*)alloc((size_t)NN * NHEAD * 4);
    float* zbias = (float*)alloc((size_t)NHEAD * FIN * 4);              // zeros [1024]
    float* bcat2 = (float*)alloc((size_t)(3 * NHEAD * C2 + C2) * 4);    // [6400]
    float* acc2  = (float*)alloc((size_t)NN * C2 * 4);
    _Float16* h1b = (_Float16*)alloc((size_t)NN * C1 * 2);
    float* alpha = (float*)alloc((size_t)NE * NHEAD * 4);
    float* ev    = (float*)alloc((size_t)NE * NHEAD * 4);
    unsigned* amaxU = (unsigned*)alloc((size_t)NN * NHEAD * 4);
    float* denom = (float*)alloc((size_t)NN * NHEAD * 4);
    int* deg    = (int*)alloc((size_t)NN * 4);
    int* rowptr = (int*)alloc((size_t)(NN + 1) * 4);
    int* cursor = (int*)alloc((size_t)NN * 4);
    int* eids   = (int*)alloc((size_t)NE * 4);
    float* bvm1 = (float*)alloc((size_t)C1 * 4);
    _Float16* Tbuf   = (_Float16*)alloc((size_t)NN * NHEAD * FIN * 2);      // 20.5MB
    _Float16* QKVbuf = (_Float16*)alloc((size_t)NN * 3 * NHEAD * C2 * 2);   // 123MB
    _Float16* Zbuf = QKVbuf;    // conv1 z-phase alias
    const int LDQKV = 3 * NHEAD * C2;   // 6144

    _Float16* wq2t = wcat2;
    _Float16* wk2t = wcat2 + (size_t)NHEAD * C2 * C1;
    _Float16* wv2t = wcat2 + (size_t)2 * NHEAD * C2 * C1;
    _Float16* ws2t = wcat2 + (size_t)3 * NHEAD * C2 * C1;

    const dim3 blk(256);
    const float sc1 = 1.0f / sqrtf((float)C1);
    const float sc2 = 1.0f / sqrtf((float)C2);
    const int edge_blocks = (NE * 64) / 256;
    const int node_blocks = (NN * 64) / 256;
    const int gy = (NN + 127) / 128;   // 79

    // ---- conversions + precompute ----
    cvt_f16<<<((size_t)NN * FIN + 255) / 256, blk, 0, stream>>>(x, xb, NN * FIN);
    {
        dim3 tb(32, 8);
        transpose_cvt<<<dim3(NHEAD * C1 / 32, FIN / 32), tb, 0, stream>>>(Wq1, wtq1, FIN, NHEAD * C1);
        transpose_cvt<<<dim3(NHEAD * C1 / 32, FIN / 32), tb, 0, stream>>>(Wk1, wtk1, FIN, NHEAD * C1);
        transpose_stack<<<dim3(C1 / 32, FIN / 32, NHEAD), tb, 0, stream>>>(Wv1, bvs1, FIN, C1);
        transpose_cvt<<<dim3(C1 / 32, FIN / 32),         tb, 0, stream>>>(Ws1, wts1, FIN, C1);
        transpose_cvt<<<dim3(NHEAD * C2 / 32, C1 / 32),  tb, 0, stream>>>(Wq2, wq2t, C1, NHEAD * C2);
        transpose_cvt<<<dim3(NHEAD * C2 / 32, C1 / 32),  tb, 0, stream>>>(Wk2, wk2t, C1, NHEAD * C2);
        transpose_cvt<<<dim3(NHEAD * C2 / 32, C1 / 32),  tb, 0, stream>>>(Wv2, wv2t, C1, NHEAD * C2);
        transpose_cvt<<<dim3(C2 / 32, C1 / 32),          tb, 0, stream>>>(Ws2, ws2t, C1, C2);
    }
    bvmean_k<<<(C1 + 255) / 256, blk, 0, stream>>>(bv1, bvm1, C1);
    mstack_k<<<dim3(FIN / 16, FIN / 16, NHEAD), dim3(16, 16), 0, stream>>>(wtq1, wtk1, Mst);
    uvprep_w<<<(NHEAD * FIN * 64) / 256, blk, 0, stream>>>(Wq1, Wk1, bq1, bk1, uvecs, vvecs);
    chd_k<<<1, 512, 0, stream>>>(bq1, bk1, chd);
    udvs_w<<<node_blocks, blk, 0, stream>>>(xb, uvecs, vvecs, chd, ud, vs);
    zero_i32<<<(NHEAD * FIN + 255) / 256, blk, 0, stream>>>((int*)zbias, NHEAD * FIN);
    bcat2_k<<<(3 * NHEAD * C2 + C2 + 255) / 256, blk, 0, stream>>>(bq2, bk2, bv2, bs2, bcat2);

    // ---- CSR by dst ----
    zero_i32<<<(NN + 255) / 256, blk, 0, stream>>>(deg, NN);
    hist_dst<<<(NE + 255) / 256, blk, 0, stream>>>(dst, deg);
    scan_deg<<<1, blk, 0, stream>>>(deg, rowptr, cursor, NN);
    scatter_edges<<<(NE + 255) / 256, blk, 0, stream>>>(dst, cursor, eids);

    // ================ conv1: low-rank QK, z-trick, fused cat2+ELU ================
    {   // T = X @ M   [10000,1024] K=128; gx=8, SW=8
        int nwg = 8 * gy;
        gemm_f16<<<nwg, blk, 0, stream>>>(xb, Mst, zbias, Tbuf, NHEAD * FIN, NN, FIN,
                                          nwg, 8, 8);
    }
    init_seg<<<(NN * NHEAD + 255) / 256, blk, 0, stream>>>(amaxU, denom, NN * NHEAD);
    edge_alpha_lr<<<edge_blocks, blk, 0, stream>>>(Tbuf, xb, ud, vs, src, dst,
                                                   alpha, amaxU, sc1);
    edge_expsum<<<(NE * NHEAD + 255) / 256, blk, 0, stream>>>(alpha, dst, amaxU, ev, denom);
    zaccum<FIN, NHEAD><<<node_blocks, blk, 0, stream>>>(xb, ev, denom, rowptr, eids, src,
                                                        Zbuf, 0);
    {   // h1b = ELU([Z|xb] @ [bvs1|wts1]^T + bs1 + gated bvm1)  [10000,512] K=1152
        int nwg = 4 * gy;
        gemm_cat2_elu<<<nwg, blk, 0, stream>>>(Zbuf, NHEAD * FIN, xb, FIN,
                                               bvs1, wts1, bs1, bvm1, deg, h1b,
                                               NN, nwg, 4, 4);
    }

    // ================ conv2: [QKV | skip] dual GEMM (XCD-swizzled), fused edge/aggr ================
    init_seg<<<(NN * NHEAD + 255) / 256, blk, 0, stream>>>(amaxU, denom, NN * NHEAD);
    {   // [10000, 6400] K=512; gx=50, SW=25
        int nwg = 50 * gy;
        gemm_dual<<<nwg, blk, 0, stream>>>(h1b, wcat2, bcat2, QKVbuf, LDQKV,
                                           acc2, C2, LDQKV, NN, C1, nwg, 50, 25);
    }
    edge_alpha_fu<C2, NHEAD><<<edge_blocks, blk, 0, stream>>>(
        QKVbuf, QKVbuf + NHEAD * C2, LDQKV, src, dst, alpha, amaxU, sc2);
    edge_expsum<<<(NE * NHEAD + 255) / 256, blk, 0, stream>>>(alpha, dst, amaxU, ev, denom);
    node_aggr_ilp<C2, NHEAD><<<node_blocks, blk, 0, stream>>>(
        QKVbuf + 2 * NHEAD * C2, LDQKV, ev, denom, rowptr, eids, src, acc2);
    elu_k<<<((size_t)NN * C2 + 255) / 256, blk, 0, stream>>>(acc2, NN * C2);

    // ================ fused pooling + fc ================
    pool_fused<<<NB, blk, 0, stream>>>(acc2, Wg, bg, batch, Wf, bf, alpha, (float*)d_out);
}

// Round 14
// 552.329 us; speedup vs baseline: 2.2355x; 1.0602x over previous
//
#include <hip/hip_runtime.h>
#include <math.h>

#define NN 10000
#define NE 20000
#define FIN 128
#define NHEAD 8
#define C1 512
#define C2 256
#define NB 64
#define NOUT 10

typedef _Float16 half8v __attribute__((ext_vector_type(8)));
typedef _Float16 half4v __attribute__((ext_vector_type(4)));
typedef _Float16 half2v __attribute__((ext_vector_type(2)));
typedef float f32x4 __attribute__((ext_vector_type(4)));

template<int VEC> struct VecT;
template<> struct VecT<2> { using T = half2v; };
template<> struct VecT<4> { using T = half4v; };
template<> struct VecT<8> { using T = half8v; };

__device__ __forceinline__ unsigned enc_f(float f) {
    unsigned u = __float_as_uint(f);
    return (u & 0x80000000u) ? ~u : (u | 0x80000000u);
}
__device__ __forceinline__ float dec_f(unsigned e) {
    return (e & 0x80000000u) ? __uint_as_float(e & 0x7fffffffu) : __uint_as_float(~e);
}

__device__ __forceinline__ void gload16(const _Float16* g, _Float16* l) {
    __builtin_amdgcn_global_load_lds(
        (const __attribute__((address_space(1))) unsigned int*)(const void*)g,
        (__attribute__((address_space(3))) unsigned int*)(void*)l, 16, 0, 0);
}

// XCD-affine swizzle: bijective mod-8 chunk remap (m204) + stripe traversal.
__device__ __forceinline__ void swz_map(int nwg, int gx, int SW, int& bx, int& by) {
    int orig = blockIdx.x;
    int q = nwg >> 3, r = nwg & 7;
    int xcd = orig & 7, lid = orig >> 3;
    int wgid = (xcd < r ? xcd * (q + 1) : r * (q + 1) + (xcd - r) * q) + lid;
    int gy = nwg / gx;
    int sh = SW * gy;
    int stripe = wgid / sh;
    int rem = wgid - stripe * sh;
    int byq = rem / SW;
    by = byq;
    bx = stripe * SW + (rem - byq * SW);
}

// ---------------- conversion / transpose ----------------
__global__ void cvt_f16(const float* __restrict__ in, _Float16* __restrict__ out, int n) {
    int i = blockIdx.x * blockDim.x + threadIdx.x;
    if (i < n) out[i] = (_Float16)in[i];
}

__global__ void transpose_cvt(const float* __restrict__ W, _Float16* __restrict__ Wt,
                              int K, int N) {
    __shared__ float tile[32][33];
    int n0 = blockIdx.x * 32, k0 = blockIdx.y * 32;
    int tx = threadIdx.x, ty = threadIdx.y;
    for (int j = ty; j < 32; j += 8) tile[j][tx] = W[(size_t)(k0 + j) * N + n0 + tx];
    __syncthreads();
    for (int j = ty; j < 32; j += 8)
        Wt[(size_t)(n0 + j) * K + k0 + tx] = (_Float16)tile[tx][j];
}

__global__ void transpose_stack(const float* __restrict__ Wv, _Float16* __restrict__ Bt,
                                int Cin, int Cout) {
    __shared__ float tile[32][33];
    int h = blockIdx.z;
    int c0 = blockIdx.x * 32, k0 = blockIdx.y * 32;
    int tx = threadIdx.x, ty = threadIdx.y;
    for (int j = ty; j < 32; j += 8)
        tile[j][tx] = Wv[(size_t)(k0 + j) * (NHEAD * Cout) + (size_t)h * Cout + c0 + tx];
    __syncthreads();
    for (int j = ty; j < 32; j += 8)
        Bt[(size_t)(c0 + j) * (NHEAD * Cin) + (size_t)h * Cin + k0 + tx] = (_Float16)tile[tx][j];
}

__global__ void bvmean_k(const float* __restrict__ bv, float* __restrict__ bvm, int C) {
    int c = blockIdx.x * blockDim.x + threadIdx.x;
    if (c >= C) return;
    float s = 0.f;
    #pragma unroll
    for (int h = 0; h < NHEAD; ++h) s += bv[h * C + c];
    bvm[c] = s * (1.0f / NHEAD);
}

__global__ void bcat2_k(const float* __restrict__ bq2, const float* __restrict__ bk2,
                        const float* __restrict__ bv2, const float* __restrict__ bs2,
                        float* __restrict__ o) {
    int i = blockIdx.x * blockDim.x + threadIdx.x;
    const int n = NHEAD * C2;
    if (i < n) o[i] = bq2[i];
    else if (i < 2 * n) o[i] = bk2[i - n];
    else if (i < 3 * n) o[i] = bv2[i - 2 * n];
    else if (i < 3 * n + C2) o[i] = bs2[i - 3 * n];
}

// ---------------- conv1 low-rank QK precompute ----------------
__global__ void mstack_k(const _Float16* __restrict__ wtq1, const _Float16* __restrict__ wtk1,
                         _Float16* __restrict__ Mst) {
    int h = blockIdx.z;
    int i = blockIdx.x * 16 + threadIdx.x;
    int j = blockIdx.y * 16 + threadIdx.y;
    float acc = 0.f;
    for (int c = 0; c < C1; ++c)
        acc += (float)wtq1[((size_t)h * C1 + c) * FIN + i] *
               (float)wtk1[((size_t)h * C1 + c) * FIN + j];
    Mst[((size_t)h * FIN + j) * FIN + i] = (_Float16)acc;
}

__global__ void uvprep_w(const float* __restrict__ Wq1, const float* __restrict__ Wk1,
                         const float* __restrict__ bq1, const float* __restrict__ bk1,
                         float* __restrict__ u, float* __restrict__ v) {
    int wid = (blockIdx.x * blockDim.x + threadIdx.x) >> 6;
    int lane = threadIdx.x & 63;
    if (wid >= NHEAD * FIN) return;
    int h = wid >> 7, i = wid & 127;
    const float* wq = Wq1 + (size_t)i * (NHEAD * C1) + h * C1;
    const float* wk = Wk1 + (size_t)i * (NHEAD * C1) + h * C1;
    const float* bk = bk1 + h * C1;
    const float* bq = bq1 + h * C1;
    int c = lane * 8;
    float4 a0 = *(const float4*)(wq + c),  a1 = *(const float4*)(wq + c + 4);
    float4 p0 = *(const float4*)(bk + c),  p1 = *(const float4*)(bk + c + 4);
    float4 b0 = *(const float4*)(wk + c),  b1 = *(const float4*)(wk + c + 4);
    float4 q0 = *(const float4*)(bq + c),  q1 = *(const float4*)(bq + c + 4);
    float su = a0.x*p0.x + a0.y*p0.y + a0.z*p0.z + a0.w*p0.w
             + a1.x*p1.x + a1.y*p1.y + a1.z*p1.z + a1.w*p1.w;
    float sv = b0.x*q0.x + b0.y*q0.y + b0.z*q0.z + b0.w*q0.w
             + b1.x*q1.x + b1.y*q1.y + b1.z*q1.z + b1.w*q1.w;
    #pragma unroll
    for (int off = 32; off; off >>= 1) {
        su += __shfl_xor(su, off);
        sv += __shfl_xor(sv, off);
    }
    if (lane == 0) { u[h * FIN + i] = su; v[h * FIN + i] = sv; }
}

__global__ void chd_k(const float* __restrict__ bq1, const float* __restrict__ bk1,
                      float* __restrict__ ch) {
    int h = threadIdx.x >> 6, lane = threadIdx.x & 63;
    int c = lane * 8;
    const float* bq = bq1 + h * C1;
    const float* bk = bk1 + h * C1;
    float4 a0 = *(const float4*)(bq + c), a1 = *(const float4*)(bq + c + 4);
    float4 b0 = *(const float4*)(bk + c), b1 = *(const float4*)(bk + c + 4);
    float s = a0.x*b0.x + a0.y*b0.y + a0.z*b0.z + a0.w*b0.w
            + a1.x*b1.x + a1.y*b1.y + a1.z*b1.z + a1.w*b1.w;
    #pragma unroll
    for (int off = 32; off; off >>= 1) s += __shfl_xor(s, off);
    if (lane == 0) ch[h] = s;
}

__global__ void udvs_w(const _Float16* __restrict__ xb, const float* __restrict__ u,
                       const float* __restrict__ v, const float* __restrict__ ch,
                       float* __restrict__ ud, float* __restrict__ vs) {
    int n = (blockIdx.x * blockDim.x + threadIdx.x) >> 6;
    int lane = threadIdx.x & 63;
    if (n >= NN) return;
    half2v xv = *(const half2v*)(xb + (size_t)n * FIN + lane * 2);
    float x0 = (float)xv[0], x1 = (float)xv[1];
    #pragma unroll
    for (int h = 0; h < NHEAD; ++h) {
        float2 uu = *(const float2*)(u + h * FIN + lane * 2);
        float2 vv = *(const float2*)(v + h * FIN + lane * 2);
        float su = x0 * uu.x + x1 * uu.y;
        float sv = x0 * vv.x + x1 * vv.y;
        #pragma unroll
        for (int off = 32; off; off >>= 1) {
            su += __shfl_xor(su, off);
            sv += __shfl_xor(sv, off);
        }
        if (lane == 0) {
            ud[(size_t)n * NHEAD + h] = su + ch[h];
            vs[(size_t)n * NHEAD + h] = sv;
        }
    }
}

// ---------------- MFMA GEMM core: double-buffered LDS + counted vmcnt pipeline ----------------
// SM layout: [buf*2 + (0=A,1=B)][128*32]; Ct epilogue aliases SM (post K-loop).
#define GEMM_CORE                                                                   \
    __shared__ _Float16 SM[4][128 * 32];                                            \
    _Float16* Ct = &SM[0][0];  /* 64*136 f16 = 17.4KB < 32KB */                     \
    const int t = threadIdx.x;                                                      \
    const int w = t >> 6, lane = t & 63;                                            \
    const int wr = w >> 1, wc = w & 1;                                              \
    const int r_lo = lane >> 2, slot = lane & 3;                                    \
    f32x4 acc[4][4];                                                                \
    _Pragma("unroll")                                                               \
    for (int m = 0; m < 4; ++m)                                                     \
        _Pragma("unroll")                                                           \
        for (int n = 0; n < 4; ++n)                                                 \
            _Pragma("unroll")                                                       \
            for (int j = 0; j < 4; ++j) acc[m][n][j] = 0.f;

// stage one 128x32 A-tile + B-tile into buffer BUF (4 gload_lds per thread)
#define GEMM_STAGE(BUF, APTR, ALD, AKO, BPTR, BLD, BKO)                             \
    {                                                                               \
        _Pragma("unroll")                                                           \
        for (int i = 0; i < 2; ++i) {                                               \
            int chunk = 2 * w + i;                                                  \
            int row = chunk * 16 + r_lo;                                            \
            int gr = m0 + row; gr = gr < M ? gr : M - 1;                            \
            gload16(APTR + (size_t)gr * ALD + (AKO) + slot * 8, &SM[(BUF)*2+0][chunk * 512]); \
            gload16(BPTR + (size_t)(n0 + row) * BLD + (BKO) + slot * 8, &SM[(BUF)*2+1][chunk * 512]); \
        }                                                                           \
    }

#define GEMM_COMPUTE(BUF)                                                           \
    {                                                                               \
        half8v af[4], bf[4];                                                        \
        _Pragma("unroll")                                                           \
        for (int m = 0; m < 4; ++m)                                                 \
            af[m] = *(const half8v*)(&SM[(BUF)*2+0][(wr * 64 + m * 16 + (lane & 15)) * 32 + (lane >> 4) * 8]); \
        _Pragma("unroll")                                                           \
        for (int n = 0; n < 4; ++n)                                                 \
            bf[n] = *(const half8v*)(&SM[(BUF)*2+1][(wc * 64 + n * 16 + (lane & 15)) * 32 + (lane >> 4) * 8]); \
        _Pragma("unroll")                                                           \
        for (int m = 0; m < 4; ++m)                                                 \
            _Pragma("unroll")                                                       \
            for (int n = 0; n < 4; ++n)                                             \
                acc[m][n] = __builtin_amdgcn_mfma_f32_16x16x32_f16(af[m], bf[n], acc[m][n], 0, 0, 0); \
    }

// pipeline sync helpers: counted vmcnt keeps next-tile loads in flight across barrier
#define PIPE_WAIT_PREV                                                              \
    asm volatile("s_waitcnt vmcnt(4)" ::: "memory");                                \
    __builtin_amdgcn_sched_barrier(0);                                              \
    __builtin_amdgcn_s_barrier();                                                   \
    __builtin_amdgcn_sched_barrier(0);
#define PIPE_WAIT_ALL                                                               \
    asm volatile("s_waitcnt vmcnt(0)" ::: "memory");                                \
    __builtin_amdgcn_sched_barrier(0);                                              \
    __builtin_amdgcn_s_barrier();                                                   \
    __builtin_amdgcn_sched_barrier(0);
#define PIPE_END                                                                    \
    __builtin_amdgcn_sched_barrier(0);                                              \
    __builtin_amdgcn_s_barrier();                                                   \
    __builtin_amdgcn_sched_barrier(0);

// LDS-staged coalesced f16 epilogue (Ct aliases SM; safe after final PIPE_END barrier)
#define EPI_F16(OUTPTR, LDC, STAGE_EXPR)                                            \
    _Pragma("unroll")                                                               \
    for (int half = 0; half < 2; ++half) {                                          \
        __syncthreads();                                                            \
        if (wr == half) {                                                           \
            _Pragma("unroll")                                                       \
            for (int m = 0; m < 4; ++m)                                             \
                _Pragma("unroll")                                                   \
                for (int n = 0; n < 4; ++n) {                                       \
                    int lcol = wc * 64 + n * 16 + (lane & 15);                      \
                    int gcol = n0 + lcol;                                           \
                    _Pragma("unroll")                                               \
                    for (int r = 0; r < 4; ++r) {                                   \
                        int lrow = m * 16 + (lane >> 4) * 4 + r;                    \
                        int grow = m0 + half * 64 + lrow;                           \
                        float av = acc[m][n][r];                                    \
                        Ct[lrow * 136 + lcol] = (_Float16)(STAGE_EXPR);             \
                    }                                                               \
                }                                                                   \
        }                                                                           \
        __syncthreads();                                                            \
        _Pragma("unroll")                                                           \
        for (int g = 0; g < 4; ++g) {                                               \
            int lrow = g * 16 + (t >> 4);                                           \
            int grow = m0 + half * 64 + lrow;                                       \
            if (grow < M) {                                                         \
                int seg = (t & 15) * 8;                                             \
                *(float4*)(OUTPTR + (size_t)grow * LDC + n0 + seg) =                \
                    *(const float4*)(&Ct[lrow * 136 + seg]);                        \
            }                                                                       \
        }                                                                           \
    }

// plain GEMM, f16 out (+bias)
__global__ __launch_bounds__(256) void gemm_f16(
    const _Float16* __restrict__ A, const _Float16* __restrict__ Bt,
    const float* __restrict__ bias, _Float16* __restrict__ Cout, int ldc,
    int M, int K, int nwg, int gx, int SW)
{
    int bx, by; swz_map(nwg, gx, SW, bx, by);
    const int m0 = by * 128, n0 = bx * 128;
    GEMM_CORE
    GEMM_STAGE(0, A, K, 0, Bt, K, 0)
    int cur = 0;
    const int nsteps = K >> 5;
    for (int s = 0; s < nsteps; ++s) {
        if (s + 1 < nsteps) {
            int ko = (s + 1) << 5;
            GEMM_STAGE(cur ^ 1, A, K, ko, Bt, K, ko)
            PIPE_WAIT_PREV
        } else {
            PIPE_WAIT_ALL
        }
        GEMM_COMPUTE(cur)
        PIPE_END
        cur ^= 1;
    }
    EPI_F16(Cout, ldc, av + bias[gcol])
}

// dual-output GEMM: blocks with n0<NSPLIT all-f16 (staged); others f32 scalar
__global__ __launch_bounds__(256) void gemm_dual(
    const _Float16* __restrict__ A, const _Float16* __restrict__ Bt,
    const float* __restrict__ bias, _Float16* __restrict__ out16, int ld16,
    float* __restrict__ out32, int ld32, int NSPLIT, int M, int K,
    int nwg, int gx, int SW)
{
    int bx, by; swz_map(nwg, gx, SW, bx, by);
    const int m0 = by * 128, n0 = bx * 128;
    GEMM_CORE
    GEMM_STAGE(0, A, K, 0, Bt, K, 0)
    int cur = 0;
    const int nsteps = K >> 5;
    for (int s = 0; s < nsteps; ++s) {
        if (s + 1 < nsteps) {
            int ko = (s + 1) << 5;
            GEMM_STAGE(cur ^ 1, A, K, ko, Bt, K, ko)
            PIPE_WAIT_PREV
        } else {
            PIPE_WAIT_ALL
        }
        GEMM_COMPUTE(cur)
        PIPE_END
        cur ^= 1;
    }
    if (n0 < NSPLIT) {
        EPI_F16(out16, ld16, av + bias[gcol])
    } else {
        #pragma unroll
        for (int m = 0; m < 4; ++m) {
            int r0 = m0 + wr * 64 + m * 16 + (lane >> 4) * 4;
            #pragma unroll
            for (int n = 0; n < 4; ++n) {
                int col = n0 + wc * 64 + n * 16 + (lane & 15);
                float b = bias[col];
                #pragma unroll
                for (int r = 0; r < 4; ++r) {
                    int row = r0 + r;
                    if (row < M)
                        out32[(size_t)row * ld32 + (col - NSPLIT)] = acc[m][n][r] + b;
                }
            }
        }
    }
}

// K-concat GEMM + fused conv1 epilogue: h1b = ELU([Z|xb]@[B1|B2]^T + bs1 + gated bvm1)
__global__ __launch_bounds__(256) void gemm_cat2_elu(
    const _Float16* __restrict__ A1, int K1, const _Float16* __restrict__ A2, int K2,
    const _Float16* __restrict__ B1, const _Float16* __restrict__ B2,
    const float* __restrict__ bs1, const float* __restrict__ bvm1,
    const int* __restrict__ deg, _Float16* __restrict__ h1b,
    int M, int nwg, int gx, int SW)
{
    int bx, by; swz_map(nwg, gx, SW, bx, by);
    const int m0 = by * 128, n0 = bx * 128;
    GEMM_CORE
    GEMM_STAGE(0, A1, K1, 0, B1, K1, 0)
    int cur = 0;
    const int nsteps = (K1 + K2) >> 5;
    const int split = K1 >> 5;
    for (int s = 0; s < nsteps; ++s) {
        if (s + 1 < nsteps) {
            int sn = s + 1;
            if (sn < split) {
                int ko = sn << 5;
                GEMM_STAGE(cur ^ 1, A1, K1, ko, B1, K1, ko)
            } else {
                int ko = (sn - split) << 5;
                GEMM_STAGE(cur ^ 1, A2, K2, ko, B2, K2, ko)
            }
            PIPE_WAIT_PREV
        } else {
            PIPE_WAIT_ALL
        }
        GEMM_COMPUTE(cur)
        PIPE_END
        cur ^= 1;
    }
    EPI_F16(h1b, C1,
        ({ int dr = grow < M ? grow : M - 1;
           float vv = av + bs1[gcol] + (deg[dr] > 0 ? bvm1[gcol] : 0.f);
           vv > 0.f ? vv : expm1f(vv); }))
}

// ---------------- CSR build (by dst) ----------------
__global__ void zero_i32(int* __restrict__ p, int n) {
    int i = blockIdx.x * blockDim.x + threadIdx.x;
    if (i < n) p[i] = 0;
}
__global__ void hist_dst(const int* __restrict__ dst, int* __restrict__ deg) {
    int e = blockIdx.x * blockDim.x + threadIdx.x;
    if (e < NE) atomicAdd(&deg[dst[e]], 1);
}
__global__ void scan_deg(const int* __restrict__ deg, int* __restrict__ rowptr,
                         int* __restrict__ cursor, int n) {
    __shared__ int s[256];
    __shared__ int carry;
    int t = threadIdx.x;
    if (t == 0) carry = 0;
    __syncthreads();
    for (int base = 0; base < n; base += 256) {
        int v = (base + t < n) ? deg[base + t] : 0;
        s[t] = v;
        __syncthreads();
        for (int off = 1; off < 256; off <<= 1) {
            int x = (t >= off) ? s[t - off] : 0;
            __syncthreads();
            s[t] += x;
            __syncthreads();
        }
        int excl = carry + s[t] - v;
        if (base + t < n) { rowptr[base + t] = excl; cursor[base + t] = excl; }
        __syncthreads();
        if (t == 255) carry += s[255];
        __syncthreads();
    }
    if (t == 0) rowptr[n] = carry;
}
__global__ void scatter_edges(const int* __restrict__ dst, int* __restrict__ cursor,
                              int* __restrict__ eids) {
    int e = blockIdx.x * blockDim.x + threadIdx.x;
    if (e < NE) {
        int pos = atomicAdd(&cursor[dst[e]], 1);
        eids[pos] = e;
    }
}

// ---------------- segment softmax pieces ----------------
__global__ void init_seg(unsigned* __restrict__ amax, float* __restrict__ denom, int n) {
    int i = blockIdx.x * blockDim.x + threadIdx.x;
    if (i < n) { amax[i] = 0x007FFFFFu; denom[i] = 0.f; }
}

__global__ void edge_alpha_lr(const _Float16* __restrict__ T, const _Float16* __restrict__ X,
                              const float* __restrict__ ud, const float* __restrict__ vs,
                              const int* __restrict__ src, const int* __restrict__ dst,
                              float* __restrict__ alpha, unsigned* __restrict__ amaxU,
                              float scale)
{
    int gi = blockIdx.x * blockDim.x + threadIdx.x;
    int e = gi >> 6, lane = threadIdx.x & 63;
    if (e >= NE) return;
    int s = src[e], d = dst[e];
    half2v xv = *(const half2v*)(X + (size_t)s * FIN + lane * 2);
    #pragma unroll
    for (int h = 0; h < NHEAD; ++h) {
        half2v tv = *(const half2v*)(T + ((size_t)d * NHEAD + h) * FIN + lane * 2);
        float sum = (float)tv[0] * (float)xv[0] + (float)tv[1] * (float)xv[1];
        #pragma unroll
        for (int off = 32; off; off >>= 1) sum += __shfl_xor(sum, off);
        if (lane == 0) {
            float al = (sum + ud[(size_t)d * NHEAD + h] + vs[(size_t)s * NHEAD + h]) * scale;
            alpha[(size_t)e * NHEAD + h] = al;
            atomicMax(&amaxU[(size_t)d * NHEAD + h], enc_f(al));
        }
    }
}

template<int C, int G>
__global__ void edge_alpha_fu(const _Float16* __restrict__ Q, const _Float16* __restrict__ Kh,
                              int ldq, const int* __restrict__ src, const int* __restrict__ dst,
                              float* __restrict__ alpha, unsigned* __restrict__ amaxU,
                              float scale)
{
    constexpr int VEC = C / 64;
    using vecH = typename VecT<VEC>::T;
    int gi = blockIdx.x * blockDim.x + threadIdx.x;
    int e = gi >> 6, lane = threadIdx.x & 63;
    if (e >= NE) return;
    int s = src[e], d = dst[e];
    const _Float16* qp = Q + (size_t)d * ldq + lane * VEC;
    const _Float16* kp = Kh + (size_t)s * ldq + lane * VEC;
    vecH q[G], k[G];
    #pragma unroll
    for (int h = 0; h < G; ++h) {
        q[h] = *(const vecH*)(qp + h * C);
        k[h] = *(const vecH*)(kp + h * C);
    }
    #pragma unroll
    for (int h = 0; h < G; ++h) {
        float sum = 0.f;
        #pragma unroll
        for (int j = 0; j < VEC; ++j) sum += (float)q[h][j] * (float)k[h][j];
        #pragma unroll
        for (int off = 32; off; off >>= 1) sum += __shfl_xor(sum, off);
        if (lane == 0) {
            float al = sum * scale;
            alpha[(size_t)e * NHEAD + h] = al;
            atomicMax(&amaxU[(size_t)d * NHEAD + h], enc_f(al));
        }
    }
}

__global__ void edge_expsum(const float* __restrict__ alpha, const int* __restrict__ dst,
                            const unsigned* __restrict__ amaxU,
                            float* __restrict__ ev, float* __restrict__ denom)
{
    int i = blockIdx.x * blockDim.x + threadIdx.x;
    if (i >= NE * NHEAD) return;
    int e = i >> 3, h = i & 7;
    int d = dst[e];
    float ex = expf(alpha[i] - dec_f(amaxU[(size_t)d * NHEAD + h]));
    ev[i] = ex;
    atomicAdd(&denom[(size_t)d * NHEAD + h], ex);
}

template<int C, int G>
__global__ void zaccum(const _Float16* __restrict__ X, const float* __restrict__ ev,
                       const float* __restrict__ denom, const int* __restrict__ rowptr,
                       const int* __restrict__ eids, const int* __restrict__ src,
                       _Float16* __restrict__ Z, int hbase)
{
    constexpr int VEC = C / 64;
    using vecH = typename VecT<VEC>::T;
    int gi = blockIdx.x * blockDim.x + threadIdx.x;
    int n = gi >> 6, lane = threadIdx.x & 63;
    if (n >= NN) return;
    int beg = rowptr[n], end = rowptr[n + 1];
    float rd[G];
    #pragma unroll
    for (int h = 0; h < G; ++h)
        rd[h] = (1.0f / NHEAD) / (denom[(size_t)n * NHEAD + hbase + h] + 1e-16f);
    float acc[G][VEC];
    #pragma unroll
    for (int h = 0; h < G; ++h)
        #pragma unroll
        for (int j = 0; j < VEC; ++j) acc[h][j] = 0.f;
    for (int i = beg; i < end; ++i) {
        int e = eids[i];
        int s = src[e];
        vecH xv = *(const vecH*)(X + (size_t)s * C + lane * VEC);
        #pragma unroll
        for (int h = 0; h < G; ++h) {
            float cf = ev[(size_t)e * NHEAD + hbase + h] * rd[h];
            #pragma unroll
            for (int j = 0; j < VEC; ++j) acc[h][j] += cf * (float)xv[j];
        }
    }
    #pragma unroll
    for (int h = 0; h < G; ++h) {
        vecH o;
        #pragma unroll
        for (int j = 0; j < VEC; ++j) o[j] = (_Float16)acc[h][j];
        *(vecH*)(Z + (size_t)n * (G * C) + (size_t)h * C + lane * VEC) = o;
    }
}

template<int C, int G>
__global__ void node_aggr_ilp(const _Float16* __restrict__ V, int ldv,
                              const float* __restrict__ ev, const float* __restrict__ denom,
                              const int* __restrict__ rowptr, const int* __restrict__ eids,
                              const int* __restrict__ src, float* __restrict__ acc)
{
    constexpr int VEC = C / 64;
    using vecH = typename VecT<VEC>::T;
    int gi = blockIdx.x * blockDim.x + threadIdx.x;
    int n = gi >> 6, lane = threadIdx.x & 63;
    if (n >= NN) return;
    int beg = rowptr[n], end = rowptr[n + 1];
    float rd[G];
    #pragma unroll
    for (int h = 0; h < G; ++h)
        rd[h] = (1.0f / NHEAD) / (denom[(size_t)n * NHEAD + h] + 1e-16f);
    float a[VEC];
    #pragma unroll
    for (int j = 0; j < VEC; ++j) a[j] = 0.f;
    for (int i = beg; i < end; ++i) {
        int e = eids[i];
        int s = src[e];
        float cf[G];
        #pragma unroll
        for (int h = 0; h < G; ++h) cf[h] = ev[(size_t)e * NHEAD + h] * rd[h];
        vecH v[G];
        #pragma unroll
        for (int h = 0; h < G; ++h)
            v[h] = *(const vecH*)(V + (size_t)s * ldv + h * C + lane * VEC);
        #pragma unroll
        for (int h = 0; h < G; ++h)
            #pragma unroll
            for (int j = 0; j < VEC; ++j) a[j] += cf[h] * (float)v[h][j];
    }
    float* ap = acc + (size_t)n * C + lane * VEC;
    #pragma unroll
    for (int j = 0; j < VEC; ++j) ap[j] += a[j];
}

__global__ void elu_k(float* __restrict__ x, int n) {
    int i = blockIdx.x * blockDim.x + threadIdx.x;
    if (i < n) { float v = x[i]; x[i] = v > 0.f ? v : expm1f(v); }
}

// ---------------- fused global-attention pooling + final fc ----------------
__global__ __launch_bounds__(256) void pool_fused(
    const float* __restrict__ H2, const float* __restrict__ Wg,
    const float* __restrict__ bg, const int* __restrict__ batch,
    const float* __restrict__ Wf, const float* __restrict__ bf,
    float* __restrict__ glogit, float* __restrict__ out)
{
    const int b = blockIdx.x;
    const int t = threadIdx.x, lane = t & 63, w = t >> 6;
    __shared__ int sbeg, send;
    __shared__ float sred[4];
    if (t == 0) {
        int lo = 0, hi = NN;
        while (lo < hi) { int mid = (lo + hi) >> 1; if (batch[mid] < b) lo = mid + 1; else hi = mid; }
        sbeg = lo;
        hi = NN;
        while (lo < hi) { int mid = (lo + hi) >> 1; if (batch[mid] < b + 1) lo = mid + 1; else hi = mid; }
        send = lo;
    }
    __syncthreads();
    const int beg = sbeg, end = send;
    const float bg0 = bg[0];

    float lmax = -INFINITY;
    for (int n = beg + w; n < end; n += 4) {
        float4 h = ((const float4*)(H2 + (size_t)n * C2))[lane];
        float4 wv = ((const float4*)Wg)[lane];
        float sum = h.x * wv.x + h.y * wv.y + h.z * wv.z + h.w * wv.w;
        #pragma unroll
        for (int off = 32; off; off >>= 1) sum += __shfl_xor(sum, off);
        sum += bg0;
        if (lane == 0) glogit[n] = sum;
        lmax = fmaxf(lmax, sum);
    }
    if (lane == 0) sred[w] = lmax;
    __syncthreads();
    float m = fmaxf(fmaxf(sred[0], sred[1]), fmaxf(sred[2], sred[3]));
    if (!isfinite(m)) m = 0.f;
    __syncthreads();

    float ls = 0.f;
    for (int n = beg + t; n < end; n += 256) {
        float e = expf(glogit[n] - m);
        glogit[n] = e;
        ls += e;
    }
    #pragma unroll
    for (int off = 32; off; off >>= 1) ls += __shfl_xor(ls, off);
    if (lane == 0) sred[w] = ls;
    __syncthreads();
    const float denom = sred[0] + sred[1] + sred[2] + sred[3] + 1e-16f;
    __syncthreads();

    float acc = 0.f;
    for (int n = beg; n < end; ++n)
        acc += glogit[n] * H2[(size_t)n * C2 + t];
    const float gc = acc / denom;

    for (int o = 0; o < NOUT; ++o) {
        float p = gc * Wf[t * NOUT + o];
        #pragma unroll
        for (int off = 32; off; off >>= 1) p += __shfl_xor(p, off);
        __syncthreads();
        if (lane == 0) sred[w] = p;
        __syncthreads();
        if (t == 0) out[b * NOUT + o] = sred[0] + sred[1] + sred[2] + sred[3] + bf[o];
    }
}

extern "C" void kernel_launch(void* const* d_in, const int* in_sizes, int n_in,
                              void* d_out, int out_size, void* d_ws, size_t ws_size,
                              hipStream_t stream) {
    (void)in_sizes; (void)n_in; (void)out_size; (void)ws_size;
    const float* x     = (const float*)d_in[0];
    const int*   ei    = (const int*)  d_in[1];
    const int*   batch = (const int*)  d_in[2];
    const float* Wq1 = (const float*)d_in[3];  const float* bq1 = (const float*)d_in[4];
    const float* Wk1 = (const float*)d_in[5];  const float* bk1 = (const float*)d_in[6];
    const float* Wv1 = (const float*)d_in[7];  const float* bv1 = (const float*)d_in[8];
    const float* Ws1 = (const float*)d_in[9];  const float* bs1 = (const float*)d_in[10];
    const float* Wq2 = (const float*)d_in[11]; const float* bq2 = (const float*)d_in[12];
    const float* Wk2 = (const float*)d_in[13]; const float* bk2 = (const float*)d_in[14];
    const float* Wv2 = (const float*)d_in[15]; const float* bv2 = (const float*)d_in[16];
    const float* Ws2 = (const float*)d_in[17]; const float* bs2 = (const float*)d_in[18];
    const float* Wg  = (const float*)d_in[19]; const float* bg  = (const float*)d_in[20];
    const float* Wf  = (const float*)d_in[21]; const float* bf  = (const float*)d_in[22];

    const int* src = ei;
    const int* dst = ei + NE;

    char* base = (char*)d_ws;
    size_t off = 0;
    auto alloc = [&](size_t bytes) -> char* {
        char* p = base + off;
        off = (off + bytes + 255) & ~(size_t)255;
        return p;
    };
    _Float16* xb    = (_Float16*)alloc((size_t)NN * FIN * 2);
    _Float16* wtq1  = (_Float16*)alloc((size_t)NHEAD * C1 * FIN * 2);
    _Float16* wtk1  = (_Float16*)alloc((size_t)NHEAD * C1 * FIN * 2);
    _Float16* bvs1  = (_Float16*)alloc((size_t)C1 * NHEAD * FIN * 2);   // [512,1024]
    _Float16* wts1  = (_Float16*)alloc((size_t)C1 * FIN * 2);           // [512,128]
    _Float16* Mst   = (_Float16*)alloc((size_t)NHEAD * FIN * FIN * 2);  // [1024,128]
    _Float16* wcat2 = (_Float16*)alloc((size_t)(3 * NHEAD * C2 + C2) * C1 * 2); // [6400,512]
    float* uvecs = (float*)alloc((size_t)NHEAD * FIN * 4);
    float* vvecs = (float*)alloc((size_t)NHEAD * FIN * 4);
    float* chd   = (float*)alloc((size_t)NHEAD * 4);
    float* ud    = (float*)alloc((size_t)NN * NHEAD * 4);
    float* vs    = (float*)alloc((size_t)NN * NHEAD * 4);
    float* zbias = (float*)alloc((size_t)NHEAD * FIN * 4);              // zeros [1024]
    float* bcat2 = (float*)alloc((size_t)(3 * NHEAD * C2 + C2) * 4);    // [6400]
    float* acc2  = (float*)alloc((size_t)NN * C2 * 4);
    _Float16* h1b = (_Float16*)alloc((size_t)NN * C1 * 2);
    float* alpha = (float*)alloc((size_t)NE * NHEAD * 4);
    float* ev    = (float*)alloc((size_t)NE * NHEAD * 4);
    unsigned* amaxU = (unsigned*)alloc((size_t)NN * NHEAD * 4);
    float* denom = (float*)alloc((size_t)NN * NHEAD * 4);
    int* deg    = (int*)alloc((size_t)NN * 4);
    int* rowptr = (int*)alloc((size_t)(NN + 1) * 4);
    int* cursor = (int*)alloc((size_t)NN * 4);
    int* eids   = (int*)alloc((size_t)NE * 4);
    float* bvm1 = (float*)alloc((size_t)C1 * 4);
    _Float16* Tbuf   = (_Float16*)alloc((size_t)NN * NHEAD * FIN * 2);      // 20.5MB
    _Float16* QKVbuf = (_Float16*)alloc((size_t)NN * 3 * NHEAD * C2 * 2);   // 123MB
    _Float16* Zbuf = QKVbuf;    // conv1 z-phase alias
    const int LDQKV = 3 * NHEAD * C2;   // 6144

    _Float16* wq2t = wcat2;
    _Float16* wk2t = wcat2 + (size_t)NHEAD * C2 * C1;
    _Float16* wv2t = wcat2 + (size_t)2 * NHEAD * C2 * C1;
    _Float16* ws2t = wcat2 + (size_t)3 * NHEAD * C2 * C1;

    const dim3 blk(256);
    const float sc1 = 1.0f / sqrtf((float)C1);
    const float sc2 = 1.0f / sqrtf((float)C2);
    const int edge_blocks = (NE * 64) / 256;
    const int node_blocks = (NN * 64) / 256;
    const int gy = (NN + 127) / 128;   // 79

    // ---- conversions + precompute ----
    cvt_f16<<<((size_t)NN * FIN + 255) / 256, blk, 0, stream>>>(x, xb, NN * FIN);
    {
        dim3 tb(32, 8);
        transpose_cvt<<<dim3(NHEAD * C1 / 32, FIN / 32), tb, 0, stream>>>(Wq1, wtq1, FIN, NHEAD * C1);
        transpose_cvt<<<dim3(NHEAD * C1 / 32, FIN / 32), tb, 0, stream>>>(Wk1, wtk1, FIN, NHEAD * C1);
        transpose_stack<<<dim3(C1 / 32, FIN / 32, NHEAD), tb, 0, stream>>>(Wv1, bvs1, FIN, C1);
        transpose_cvt<<<dim3(C1 / 32, FIN / 32),         tb, 0, stream>>>(Ws1, wts1, FIN, C1);
        transpose_cvt<<<dim3(NHEAD * C2 / 32, C1 / 32),  tb, 0, stream>>>(Wq2, wq2t, C1, NHEAD * C2);
        transpose_cvt<<<dim3(NHEAD * C2 / 32, C1 / 32),  tb, 0, stream>>>(Wk2, wk2t, C1, NHEAD * C2);
        transpose_cvt<<<dim3(NHEAD * C2 / 32, C1 / 32),  tb, 0, stream>>>(Wv2, wv2t, C1, NHEAD * C2);
        transpose_cvt<<<dim3(C2 / 32, C1 / 32),          tb, 0, stream>>>(Ws2, ws2t, C1, C2);
    }
    bvmean_k<<<(C1 + 255) / 256, blk, 0, stream>>>(bv1, bvm1, C1);
    mstack_k<<<dim3(FIN / 16, FIN / 16, NHEAD), dim3(16, 16), 0, stream>>>(wtq1, wtk1, Mst);
    uvprep_w<<<(NHEAD * FIN * 64) / 256, blk, 0, stream>>>(Wq1, Wk1, bq1, bk1, uvecs, vvecs);
    chd_k<<<1, 512, 0, stream>>>(bq1, bk1, chd);
    udvs_w<<<node_blocks, blk, 0, stream>>>(xb, uvecs, vvecs, chd, ud, vs);
    zero_i32<<<(NHEAD * FIN + 255) / 256, blk, 0, stream>>>((int*)zbias, NHEAD * FIN);
    bcat2_k<<<(3 * NHEAD * C2 + C2 + 255) / 256, blk, 0, stream>>>(bq2, bk2, bv2, bs2, bcat2);

    // ---- CSR by dst ----
    zero_i32<<<(NN + 255) / 256, blk, 0, stream>>>(deg, NN);
    hist_dst<<<(NE + 255) / 256, blk, 0, stream>>>(dst, deg);
    scan_deg<<<1, blk, 0, stream>>>(deg, rowptr, cursor, NN);
    scatter_edges<<<(NE + 255) / 256, blk, 0, stream>>>(dst, cursor, eids);

    // ================ conv1: low-rank QK, z-trick, fused cat2+ELU ================
    {   // T = X @ M   [10000,1024] K=128; gx=8, SW=8
        int nwg = 8 * gy;
        gemm_f16<<<nwg, blk, 0, stream>>>(xb, Mst, zbias, Tbuf, NHEAD * FIN, NN, FIN,
                                          nwg, 8, 8);
    }
    init_seg<<<(NN * NHEAD + 255) / 256, blk, 0, stream>>>(amaxU, denom, NN * NHEAD);
    edge_alpha_lr<<<edge_blocks, blk, 0, stream>>>(Tbuf, xb, ud, vs, src, dst,
                                                   alpha, amaxU, sc1);
    edge_expsum<<<(NE * NHEAD + 255) / 256, blk, 0, stream>>>(alpha, dst, amaxU, ev, denom);
    zaccum<FIN, NHEAD><<<node_blocks, blk, 0, stream>>>(xb, ev, denom, rowptr, eids, src,
                                                        Zbuf, 0);
    {   // h1b = ELU([Z|xb] @ [bvs1|wts1]^T + bs1 + gated bvm1)  [10000,512] K=1152
        int nwg = 4 * gy;
        gemm_cat2_elu<<<nwg, blk, 0, stream>>>(Zbuf, NHEAD * FIN, xb, FIN,
                                               bvs1, wts1, bs1, bvm1, deg, h1b,
                                               NN, nwg, 4, 4);
    }

    // ================ conv2: [QKV | skip] dual GEMM (XCD-swizzled), fused edge/aggr ================
    init_seg<<<(NN * NHEAD + 255) / 256, blk, 0, stream>>>(amaxU, denom, NN * NHEAD);
    {   // [10000, 6400] K=512; gx=50, SW=25
        int nwg = 50 * gy;
        gemm_dual<<<nwg, blk, 0, stream>>>(h1b, wcat2, bcat2, QKVbuf, LDQKV,
                                           acc2, C2, LDQKV, NN, C1, nwg, 50, 25);
    }
    edge_alpha_fu<C2, NHEAD><<<edge_blocks, blk, 0, stream>>>(
        QKVbuf, QKVbuf + NHEAD * C2, LDQKV, src, dst, alpha, amaxU, sc2);
    edge_expsum<<<(NE * NHEAD + 255) / 256, blk, 0, stream>>>(alpha, dst, amaxU, ev, denom);
    node_aggr_ilp<C2, NHEAD><<<node_blocks, blk, 0, stream>>>(
        QKVbuf + 2 * NHEAD * C2, LDQKV, ev, denom, rowptr, eids, src, acc2);
    elu_k<<<((size_t)NN * C2 + 255) / 256, blk, 0, stream>>>(acc2, NN * C2);

    // ================ fused pooling + fc ================
    pool_fused<<<NB, blk, 0, stream>>>(acc2, Wg, bg, batch, Wf, bf, alpha, (float*)d_out);
}